// Round 6
// baseline (1165.937 us; speedup 1.0000x reference)
//
// MongeGapTransport: KNN gather + 5-layer MLP pushforward.
// R6: R2 skeleton (only build that produced finite output) verbatim +
//   - top-32 fp32 screen (R5's crash-clean topk32) + fp64 refine on condF
//     (scalar 4B float loads only; exact reference ordering)
//   - NaN stage tracer: condF/A0/A1/out scans -> stamp 333/555/777/999
#include <hip/hip_runtime.h>
#include <stdint.h>

typedef unsigned short u16;
typedef unsigned long long u64;
typedef short v8bf __attribute__((ext_vector_type(8)));
typedef float v4f  __attribute__((ext_vector_type(4)));

#define NPTS 4096
#define DF   128
#define DR   64
#define HID  1024
#define KNN  10
#define SCR  32
#define MROWS (NPTS*KNN)   // 40960
#define DIN  192

__device__ __forceinline__ float bf2f(u16 b){ return __uint_as_float(((unsigned)b)<<16); }
__device__ __forceinline__ u16 f2bf(float f){
  unsigned u = __float_as_uint(f);
  unsigned r = 0x7fffu + ((u>>16)&1u);
  return (u16)((u + r)>>16);
}
__device__ __forceinline__ float softplus_f(float x){ return x>15.f ? x : log1pf(expf(x)); }
__device__ __forceinline__ float rdv(const void* p, long j, int fl){
  return fl ? bf2f(((const u16*)p)[j]) : ((const float*)p)[j];
}

// ---------- dtype detection (R2-proven) ----------
__global__ void detect_k(const u16* __restrict__ c, int* __restrict__ flag){
  __shared__ int cnt[256];
  int t = threadIdx.x, n = 0;
  for(int i=t; i<8192; i+=256){
    u16 v = c[2*i];
    int e = (v>>7)&0xff;
    n += (e>=96 && e<=158);
  }
  cnt[t] = n; __syncthreads();
  for(int s=128; s>0; s>>=1){ if(t<s) cnt[t]+=cnt[t+s]; __syncthreads(); }
  if(t==0) *flag = (cnt[0] > 4915) ? 1 : 0;
}

// ---------- canonicalize to fp32 (R2-proven) ----------
__global__ void cvt_all_k(const void* c, const void* t, const void* bi, const void* b1,
                          const void* b2, const void* b3, const void* bo,
                          float* __restrict__ condF, float* __restrict__ tensF,
                          float* __restrict__ biasF, const int* __restrict__ flag){
  const int fl = *flag;
  int i = blockIdx.x*256 + threadIdx.x;
  if(i < 524288){ condF[i] = rdv(c, i, fl); }
  else if(i < 786432){ tensF[i-524288] = rdv(t, i-524288, fl); }
  else{
    int j = i - 786432;
    if(j < 1024)      biasF[j] = rdv(bi, j, fl);
    else if(j < 2048) biasF[j] = rdv(b1, j-1024, fl);
    else if(j < 3072) biasF[j] = rdv(b2, j-2048, fl);
    else if(j < 4096) biasF[j] = rdv(b3, j-3072, fl);
    else if(j < 4160) biasF[j] = rdv(bo, j-4096, fl);
  }
}

// ---------- flag-aware transpose -> bf16 Bt (R2-proven) ----------
__global__ void transpose_flag_k(const void* __restrict__ in, u16* __restrict__ out,
                                 int R, int C, const int* __restrict__ flag){
  __shared__ u16 tile[32][33];
  const int fl = *flag;
  int bx = blockIdx.x*32, by = blockIdx.y*32;
  int tx = threadIdx.x, ty = threadIdx.y;
  #pragma unroll
  for(int r=ty; r<32; r+=8){
    size_t idx = (size_t)(by+r)*C + bx + tx;
    tile[r][tx] = fl ? ((const u16*)in)[idx] : f2bf(((const float*)in)[idx]);
  }
  __syncthreads();
  #pragma unroll
  for(int r=ty; r<32; r+=8) out[(size_t)(bx+r)*R + by + tx] = tile[tx][r];
}

// ---------- squared norms (R2-proven) ----------
__global__ void sqnorm_k(const float* __restrict__ condF, float* __restrict__ sq){
  int row  = blockIdx.x*4 + (threadIdx.x>>6);
  int lane = threadIdx.x&63;
  const float* r = condF + (size_t)row*DF;
  float a = r[lane], b = r[lane+64];
  double s = (double)a*a + (double)b*b;
  #pragma unroll
  for(int off=32; off>0; off>>=1) s += __shfl_down(s, off, 64);
  if(lane==0) sq[row] = (float)s;
}

// ---------- gram -> dist via hi/lo bf16 split MFMA (R2-proven) ----------
__global__ __launch_bounds__(256) void gram_dist_k(const float* __restrict__ condF,
    const float* __restrict__ sq, float* __restrict__ dist){
  __shared__ u16 Ahi[128*40], Alo[128*40], Bhi[128*40], Blo[128*40];
  const int bm = blockIdx.x*128, bn = blockIdx.y*128;
  const int tid = threadIdx.x, lane = tid&63, wave = tid>>6;
  const int wm = (wave&1)*64, wn = (wave>>1)*64;
  v4f acc[4][4] = {};
  for(int kb=0; kb<DF; kb+=32){
    #pragma unroll
    for(int t=0;t<4;t++){
      int ch = tid + t*256;
      int r = ch>>3, c = (ch&7)*4;
      float4 av = *(const float4*)&condF[(size_t)(bm+r)*DF + kb + c];
      float4 bv = *(const float4*)&condF[(size_t)(bn+r)*DF + kb + c];
      ushort4 ah, al, bh, bl;
      ah.x=f2bf(av.x); ah.y=f2bf(av.y); ah.z=f2bf(av.z); ah.w=f2bf(av.w);
      al.x=f2bf(av.x-bf2f(ah.x)); al.y=f2bf(av.y-bf2f(ah.y));
      al.z=f2bf(av.z-bf2f(ah.z)); al.w=f2bf(av.w-bf2f(ah.w));
      bh.x=f2bf(bv.x); bh.y=f2bf(bv.y); bh.z=f2bf(bv.z); bh.w=f2bf(bv.w);
      bl.x=f2bf(bv.x-bf2f(bh.x)); bl.y=f2bf(bv.y-bf2f(bh.y));
      bl.z=f2bf(bv.z-bf2f(bh.z)); bl.w=f2bf(bv.w-bf2f(bh.w));
      *(ushort4*)&Ahi[r*40+c] = ah; *(ushort4*)&Alo[r*40+c] = al;
      *(ushort4*)&Bhi[r*40+c] = bh; *(ushort4*)&Blo[r*40+c] = bl;
    }
    __syncthreads();
    const int m16 = lane&15, q = lane>>4;
    v8bf ahf[4], alf[4], bhf[4], blf[4];
    #pragma unroll
    for(int x=0;x<4;x++){
      ahf[x] = *(const v8bf*)&Ahi[(wm + x*16 + m16)*40 + q*8];
      alf[x] = *(const v8bf*)&Alo[(wm + x*16 + m16)*40 + q*8];
      bhf[x] = *(const v8bf*)&Bhi[(wn + x*16 + m16)*40 + q*8];
      blf[x] = *(const v8bf*)&Blo[(wn + x*16 + m16)*40 + q*8];
    }
    #pragma unroll
    for(int mi=0;mi<4;mi++)
      #pragma unroll
      for(int ni=0;ni<4;ni++){
        acc[mi][ni] = __builtin_amdgcn_mfma_f32_16x16x32_bf16(alf[mi], bhf[ni], acc[mi][ni], 0,0,0);
        acc[mi][ni] = __builtin_amdgcn_mfma_f32_16x16x32_bf16(ahf[mi], blf[ni], acc[mi][ni], 0,0,0);
        acc[mi][ni] = __builtin_amdgcn_mfma_f32_16x16x32_bf16(ahf[mi], bhf[ni], acc[mi][ni], 0,0,0);
      }
    __syncthreads();
  }
  const int col16 = lane&15, rowq = lane>>4;
  #pragma unroll
  for(int mi=0;mi<4;mi++){
    #pragma unroll
    for(int ni=0;ni<4;ni++){
      int cj = bn + wn + ni*16 + col16;
      float sqj = sq[cj];
      #pragma unroll
      for(int r=0;r<4;r++){
        int ri = bm + wm + mi*16 + rowq*4 + r;
        float d2 = (sq[ri] + sqj) - 2.0f*acc[mi][ni][r];
        dist[(size_t)ri*NPTS + cj] = sqrtf(fmaxf(d2, 0.f));
      }
    }
  }
}

// ---------- screen: top-32 per row (R5 ran this without fault) ----------
__global__ __launch_bounds__(256) void topk32_k(const float* __restrict__ dist,
                                                int* __restrict__ cand){
  const int i = blockIdx.x, tid = threadIdx.x;
  __shared__ u64 lst[256*16];
  __shared__ u64 red[256];
  u64 best[16];
  const float* drow = dist + (size_t)i*NPTS;
  #pragma unroll
  for(int t=0;t<16;t++){
    int j = tid + t*256;
    float d = drow[j];
    u64 key = ((u64)__float_as_uint(d)<<32) | (unsigned)j;
    best[t] = key;
    #pragma unroll
    for(int s=15; s>0; --s){
      if(s<=t && best[s] < best[s-1]){ u64 tmp=best[s]; best[s]=best[s-1]; best[s-1]=tmp; }
    }
  }
  #pragma unroll
  for(int t=0;t<16;t++) lst[tid*16+t] = best[t];
  __syncthreads();
  int pos = 0;
  for(int r=0;r<SCR;r++){
    u64 h = (pos<16) ? lst[tid*16+pos] : ~0ULL;
    red[tid] = h;
    __syncthreads();
    for(int s=128; s>0; s>>=1){
      if(tid<s){ u64 o = red[tid+s]; if(o<red[tid]) red[tid]=o; }
      __syncthreads();
    }
    u64 win = red[0];
    __syncthreads();
    if(h==win) pos++;
    if(tid==0) cand[i*SCR+r] = (int)(win & 0xffffffffu);
  }
}

// ---------- refine: fp64 exact distances from fp32 condF (scalar loads) ----------
__global__ __launch_bounds__(64) void refine_k(const float* __restrict__ condF,
    const int* __restrict__ cand, int* __restrict__ nidx){
  const int i = blockIdx.x, t = threadIdx.x;
  __shared__ float  af[DF];
  __shared__ double ds[SCR];
  __shared__ int    idxs[SCR];
  af[t]    = condF[(size_t)i*DF + t];
  af[t+64] = condF[(size_t)i*DF + t + 64];
  __syncthreads();
  if(t < SCR){
    int j = cand[i*SCR + t] & (NPTS-1);
    const float* bp = condF + (size_t)j*DF;
    double s = 0.0;
    for(int e=0; e<DF; ++e){
      double d = (double)af[e] - (double)bp[e];
      s += d*d;
    }
    ds[t]   = sqrt(s);
    idxs[t] = j;
  }
  __syncthreads();
  if(t==0){
    unsigned used = 0;
    for(int r=0;r<KNN;r++){
      int bm=0, bi=0x7fffffff; double bd=1e300;
      for(int c=0;c<SCR;c++){
        if(used & (1u<<c)) continue;
        if(ds[c]<bd || (ds[c]==bd && idxs[c]<bi)){ bd=ds[c]; bi=idxs[c]; bm=c; }
      }
      used |= (1u<<bm);
      nidx[i*KNN+r] = bi;
    }
  }
}

// ---------- X = concat(cond[j], tens[j]) rows, bf16 (R2-proven + clamp) ----------
__global__ void buildx_k(const float* __restrict__ condF, const float* __restrict__ tensF,
                         const int* __restrict__ nidx, u16* __restrict__ X){
  int c = blockIdx.x*256 + threadIdx.x;
  int m = c/48;
  int off = (c - m*48)*4;
  int j = nidx[m] & (NPTS-1);
  float4 v = (off < DF) ? *(const float4*)&condF[(size_t)j*DF + off]
                        : *(const float4*)&tensF[(size_t)j*DR + (off-DF)];
  ushort4 o; o.x=f2bf(v.x); o.y=f2bf(v.y); o.z=f2bf(v.z); o.w=f2bf(v.w);
  *(ushort4*)&X[(size_t)m*DIN + off] = o;
}

// ---------- GEMM (R2-proven) ----------
template<int ACT>
__global__ __launch_bounds__(256,2) void gemm_bt_k(const u16* __restrict__ A,
    const u16* __restrict__ Bt, const float* __restrict__ bias, u16* __restrict__ C,
    int M, int Nc, int Kc){
  __shared__ u16 As[128*40];
  __shared__ u16 Bs[128*40];
  const int bm = blockIdx.x*128, bn = blockIdx.y*128;
  const int tid = threadIdx.x, lane = tid&63, wave = tid>>6;
  const int wm = (wave&1)*64, wn = (wave>>1)*64;
  v4f acc[4][4] = {};
  for(int kb=0; kb<Kc; kb+=32){
    #pragma unroll
    for(int t=0;t<2;t++){
      int c = tid + t*256;
      int r = c>>2, col = (c&3)*8;
      *(uint4*)&As[r*40+col] = *(const uint4*)&A[(size_t)(bm+r)*Kc + kb + col];
      *(uint4*)&Bs[r*40+col] = *(const uint4*)&Bt[(size_t)(bn+r)*Kc + kb + col];
    }
    __syncthreads();
    const int m16 = lane&15, q = lane>>4;
    v8bf a[4], b[4];
    #pragma unroll
    for(int x=0;x<4;x++){
      a[x] = *(const v8bf*)&As[(wm + x*16 + m16)*40 + q*8];
      b[x] = *(const v8bf*)&Bs[(wn + x*16 + m16)*40 + q*8];
    }
    #pragma unroll
    for(int mi=0;mi<4;mi++)
      #pragma unroll
      for(int ni=0;ni<4;ni++)
        acc[mi][ni] = __builtin_amdgcn_mfma_f32_16x16x32_bf16(a[mi], b[ni], acc[mi][ni], 0,0,0);
    __syncthreads();
  }
  const int col16 = lane&15, rowq = lane>>4;
  #pragma unroll
  for(int mi=0;mi<4;mi++){
    #pragma unroll
    for(int ni=0;ni<4;ni++){
      int cn = bn + wn + ni*16 + col16;
      float bi = bias[cn];
      #pragma unroll
      for(int r=0;r<4;r++){
        int rw = bm + wm + mi*16 + rowq*4 + r;
        float v = acc[mi][ni][r] + bi;
        if(ACT) v = softplus_f(v);
        C[(size_t)rw*Nc + cn] = f2bf(v);
      }
    }
  }
}

// ---------- final layer (R2-proven + clamp) ----------
__global__ __launch_bounds__(256,2) void gemm_out_k(const u16* __restrict__ A,
    const u16* __restrict__ Bt, const float* __restrict__ bias,
    const float* __restrict__ tensF, const int* __restrict__ nidx,
    void* __restrict__ outv, const int* __restrict__ flag){
  __shared__ u16 As[128*40];
  __shared__ u16 Bs[64*40];
  const int fl = *flag;
  const int bm = blockIdx.x*128;
  const int tid = threadIdx.x, lane = tid&63, wave = tid>>6;
  const int wm = wave*32;
  v4f acc[2][4] = {};
  for(int kb=0; kb<HID; kb+=32){
    #pragma unroll
    for(int t=0;t<2;t++){
      int c = tid + t*256;
      int r = c>>2, col = (c&3)*8;
      *(uint4*)&As[r*40+col] = *(const uint4*)&A[(size_t)(bm+r)*HID + kb + col];
    }
    { int r = tid>>2, col = (tid&3)*8;
      *(uint4*)&Bs[r*40+col] = *(const uint4*)&Bt[(size_t)r*HID + kb + col];
    }
    __syncthreads();
    const int m16 = lane&15, q = lane>>4;
    v8bf a[2], b[4];
    a[0] = *(const v8bf*)&As[(wm + m16)*40 + q*8];
    a[1] = *(const v8bf*)&As[(wm + 16 + m16)*40 + q*8];
    #pragma unroll
    for(int x=0;x<4;x++) b[x] = *(const v8bf*)&Bs[(x*16 + m16)*40 + q*8];
    #pragma unroll
    for(int mi=0;mi<2;mi++)
      #pragma unroll
      for(int ni=0;ni<4;ni++)
        acc[mi][ni] = __builtin_amdgcn_mfma_f32_16x16x32_bf16(a[mi], b[ni], acc[mi][ni], 0,0,0);
    __syncthreads();
  }
  const int col16 = lane&15, rowq = lane>>4;
  #pragma unroll
  for(int mi=0;mi<2;mi++){
    #pragma unroll
    for(int ni=0;ni<4;ni++){
      int cn = ni*16 + col16;
      float bi = bias[cn];
      #pragma unroll
      for(int r=0;r<4;r++){
        int rw = bm + wm + mi*16 + rowq*4 + r;
        int j = nidx[rw] & (NPTS-1);
        float y = tensF[(size_t)j*DR + cn] - (acc[mi][ni][r] + bi);
        if(fl) ((u16*)outv)[(size_t)rw*DR + cn] = f2bf(y);
        else   ((float*)outv)[(size_t)rw*DR + cn] = y;
      }
    }
  }
}

// ---------- diagnostics: NaN/Inf stage tracer ----------
__global__ void zdiag_k(int* diag){ if(threadIdx.x==0) *diag = 0; }

__global__ void scan_f32_k(const float* __restrict__ a, long n, int* diag, int bit){
  long idx = (long)blockIdx.x*256 + threadIdx.x;
  int bad = 0;
  for(long i=idx; i<n; i += (long)gridDim.x*256){
    unsigned e = (__float_as_uint(a[i])>>23)&0xffu;
    if(e==0xffu) bad = 1;
  }
  if(bad) atomicOr(diag, 1<<bit);
}
__global__ void scan_bf16_k(const u16* __restrict__ a, long n, int* diag, int bit){
  long idx = (long)blockIdx.x*256 + threadIdx.x;
  int bad = 0;
  for(long i=idx; i<n; i += (long)gridDim.x*256){
    if(((a[i]>>7)&0xffu)==0xffu) bad = 1;
  }
  if(bad) atomicOr(diag, 1<<bit);
}
__global__ void scan_out_k(const void* __restrict__ outv, const int* flag, int* diag, int bit){
  const int fl = *flag;
  long n = (long)MROWS*DR;
  long idx = (long)blockIdx.x*256 + threadIdx.x;
  int bad = 0;
  for(long i=idx; i<n; i += (long)gridDim.x*256){
    if(fl){ if(((((const u16*)outv)[i]>>7)&0xffu)==0xffu) bad = 1; }
    else{ unsigned e=(__float_as_uint(((const float*)outv)[i])>>23)&0xffu; if(e==0xffu) bad=1; }
  }
  if(bad) atomicOr(diag, 1<<bit);
}
__global__ void stamp_k(void* __restrict__ outv, const int* flag, const int* diag){
  int d = *diag;
  if(!d) return;
  float m = (d&1)?333.f : (d&2)?555.f : (d&4)?777.f : 999.f;
  const int fl = *flag;
  long n = (long)MROWS*DR;
  for(long i=(long)blockIdx.x*256+threadIdx.x; i<n; i += (long)gridDim.x*256){
    if(fl) ((u16*)outv)[i] = f2bf(m); else ((float*)outv)[i] = m;
  }
}

// ---------- workspace layout (R2's + cand; ~178.5 MB; R1 proved >=190 mapped) ----------
constexpr size_t OFF_FLAG  = 0;                      // flag@0, diag@64
constexpr size_t OFF_SQ    = 256;
constexpr size_t OFF_NIDX  = OFF_SQ    + 16384;
constexpr size_t OFF_BIAS  = OFF_NIDX  + 163840;
constexpr size_t OFF_CONDF = OFF_BIAS  + 16640;
constexpr size_t OFF_TENSF = OFF_CONDF + 2097152;
constexpr size_t OFF_WTIN  = OFF_TENSF + 1048576;
constexpr size_t OFF_WT1   = OFF_WTIN  + 393216;
constexpr size_t OFF_WT2   = OFF_WT1   + 2097152;
constexpr size_t OFF_WT3   = OFF_WT2   + 2097152;
constexpr size_t OFF_WTO   = OFF_WT3   + 2097152;
constexpr size_t OFF_RA    = OFF_WTO   + 131072;     // dist (67MB) then A0 (84MB)
constexpr size_t OFF_RB    = OFF_RA    + 83886080;   // X (15.7MB) then A1 (84MB)
constexpr size_t OFF_CAND  = OFF_RB    + 83886080;   // 512 KB

extern "C" void kernel_launch(void* const* d_in, const int* in_sizes, int n_in,
                              void* d_out, int out_size, void* d_ws, size_t ws_size,
                              hipStream_t stream){
  char* ws = (char*)d_ws;
  int*   flag  = (int*)  (ws + OFF_FLAG);
  int*   diag  = (int*)  (ws + OFF_FLAG + 64);
  float* sqv   = (float*)(ws + OFF_SQ);
  int*   nidx  = (int*)  (ws + OFF_NIDX);
  float* biasF = (float*)(ws + OFF_BIAS);
  float* condF = (float*)(ws + OFF_CONDF);
  float* tensF = (float*)(ws + OFF_TENSF);
  u16*   Wt_in = (u16*)  (ws + OFF_WTIN);
  u16*   Wt1   = (u16*)  (ws + OFF_WT1);
  u16*   Wt2   = (u16*)  (ws + OFF_WT2);
  u16*   Wt3   = (u16*)  (ws + OFF_WT3);
  u16*   Wt_o  = (u16*)  (ws + OFF_WTO);
  float* dist  = (float*)(ws + OFF_RA);
  u16*   A0    = (u16*)  (ws + OFF_RA);
  u16*   X     = (u16*)  (ws + OFF_RB);
  u16*   A1    = (u16*)  (ws + OFF_RB);
  int*   cand  = (int*)  (ws + OFF_CAND);

  zdiag_k  <<<1, 64, 0, stream>>>(diag);
  detect_k <<<1, 256, 0, stream>>>((const u16*)d_in[0], flag);
  cvt_all_k<<<3089, 256, 0, stream>>>(d_in[0], d_in[1], d_in[3], d_in[5], d_in[7],
                                      d_in[9], d_in[11], condF, tensF, biasF, flag);
  transpose_flag_k<<<dim3(32, 6), dim3(32,8), 0, stream>>>(d_in[2],  Wt_in, 192, 1024, flag);
  transpose_flag_k<<<dim3(32,32), dim3(32,8), 0, stream>>>(d_in[4],  Wt1, 1024, 1024, flag);
  transpose_flag_k<<<dim3(32,32), dim3(32,8), 0, stream>>>(d_in[6],  Wt2, 1024, 1024, flag);
  transpose_flag_k<<<dim3(32,32), dim3(32,8), 0, stream>>>(d_in[8],  Wt3, 1024, 1024, flag);
  transpose_flag_k<<<dim3( 2,32), dim3(32,8), 0, stream>>>(d_in[10], Wt_o, 1024,  64, flag);
  sqnorm_k   <<<1024, 256, 0, stream>>>(condF, sqv);
  gram_dist_k<<<dim3(32,32), 256, 0, stream>>>(condF, sqv, dist);
  topk32_k   <<<NPTS, 256, 0, stream>>>(dist, cand);
  refine_k   <<<NPTS, 64, 0, stream>>>(condF, cand, nidx);
  buildx_k   <<<7680, 256, 0, stream>>>(condF, tensF, nidx, X);
  gemm_bt_k<1><<<dim3(320,8), 256, 0, stream>>>(X,  Wt_in, biasF,      A0, MROWS, HID, DIN);
  gemm_bt_k<1><<<dim3(320,8), 256, 0, stream>>>(A0, Wt1,   biasF+1024, A1, MROWS, HID, HID);
  gemm_bt_k<1><<<dim3(320,8), 256, 0, stream>>>(A1, Wt2,   biasF+2048, A0, MROWS, HID, HID);
  gemm_bt_k<1><<<dim3(320,8), 256, 0, stream>>>(A0, Wt3,   biasF+3072, A1, MROWS, HID, HID);
  gemm_out_k  <<<320, 256, 0, stream>>>(A1, Wt_o, biasF+4096, tensF, nidx, d_out, flag);
  // ---- stage tracer (remove once passing) ----
  scan_f32_k <<<1024, 256, 0, stream>>>(condF, 524288L, diag, 0);
  scan_bf16_k<<<2048, 256, 0, stream>>>(A0, (long)MROWS*HID, diag, 1);
  scan_bf16_k<<<2048, 256, 0, stream>>>(A1, (long)MROWS*HID, diag, 2);
  scan_out_k <<<1024, 256, 0, stream>>>(d_out, flag, diag, 3);
  stamp_k    <<<1024, 256, 0, stream>>>(d_out, flag, diag);
}

// Round 7
// 1029.277 us; speedup vs baseline: 1.1328x; 1.1328x over previous
//
// MongeGapTransport: KNN gather + 5-layer MLP pushforward, bf16 I/O (confirmed).
// R7: R6 (passing) + perf: global_load_lds width=16 staging in all GEMMs
// (m93->m97 ladder step), unpadded chunk-linear LDS tiles, tracer removed,
// screen top-32 -> top-16.
#include <hip/hip_runtime.h>
#include <stdint.h>

typedef unsigned short u16;
typedef unsigned long long u64;
typedef short v8bf __attribute__((ext_vector_type(8)));
typedef float v4f  __attribute__((ext_vector_type(4)));

#define NPTS 4096
#define DF   128
#define DR   64
#define HID  1024
#define KNN  10
#define SCR  16
#define MROWS (NPTS*KNN)   // 40960
#define DIN  192

#define AS1 __attribute__((address_space(1)))
#define AS3 __attribute__((address_space(3)))

__device__ __forceinline__ float bf2f(u16 b){ return __uint_as_float(((unsigned)b)<<16); }
__device__ __forceinline__ u16 f2bf(float f){
  unsigned u = __float_as_uint(f);
  unsigned r = 0x7fffu + ((u>>16)&1u);
  return (u16)((u + r)>>16);
}
__device__ __forceinline__ float softplus_f(float x){ return x>15.f ? x : log1pf(expf(x)); }
__device__ __forceinline__ float rdv(const void* p, long j, int fl){
  return fl ? bf2f(((const u16*)p)[j]) : ((const float*)p)[j];
}
// async global->LDS, 16B per lane; lds dest = wave-uniform base + lane*16
__device__ __forceinline__ void gl2lds16(const u16* g, u16* l){
  __builtin_amdgcn_global_load_lds((const AS1 unsigned int*)g, (AS3 unsigned int*)l, 16, 0, 0);
}

// ---------- dtype detection (R2-proven) ----------
__global__ void detect_k(const u16* __restrict__ c, int* __restrict__ flag){
  __shared__ int cnt[256];
  int t = threadIdx.x, n = 0;
  for(int i=t; i<8192; i+=256){
    u16 v = c[2*i];
    int e = (v>>7)&0xff;
    n += (e>=96 && e<=158);
  }
  cnt[t] = n; __syncthreads();
  for(int s=128; s>0; s>>=1){ if(t<s) cnt[t]+=cnt[t+s]; __syncthreads(); }
  if(t==0) *flag = (cnt[0] > 4915) ? 1 : 0;
}

// ---------- canonicalize to fp32 (R2-proven) ----------
__global__ void cvt_all_k(const void* c, const void* t, const void* bi, const void* b1,
                          const void* b2, const void* b3, const void* bo,
                          float* __restrict__ condF, float* __restrict__ tensF,
                          float* __restrict__ biasF, const int* __restrict__ flag){
  const int fl = *flag;
  int i = blockIdx.x*256 + threadIdx.x;
  if(i < 524288){ condF[i] = rdv(c, i, fl); }
  else if(i < 786432){ tensF[i-524288] = rdv(t, i-524288, fl); }
  else{
    int j = i - 786432;
    if(j < 1024)      biasF[j] = rdv(bi, j, fl);
    else if(j < 2048) biasF[j] = rdv(b1, j-1024, fl);
    else if(j < 3072) biasF[j] = rdv(b2, j-2048, fl);
    else if(j < 4096) biasF[j] = rdv(b3, j-3072, fl);
    else if(j < 4160) biasF[j] = rdv(bo, j-4096, fl);
  }
}

// ---------- flag-aware transpose -> bf16 Bt (R2-proven) ----------
__global__ void transpose_flag_k(const void* __restrict__ in, u16* __restrict__ out,
                                 int R, int C, const int* __restrict__ flag){
  __shared__ u16 tile[32][33];
  const int fl = *flag;
  int bx = blockIdx.x*32, by = blockIdx.y*32;
  int tx = threadIdx.x, ty = threadIdx.y;
  #pragma unroll
  for(int r=ty; r<32; r+=8){
    size_t idx = (size_t)(by+r)*C + bx + tx;
    tile[r][tx] = fl ? ((const u16*)in)[idx] : f2bf(((const float*)in)[idx]);
  }
  __syncthreads();
  #pragma unroll
  for(int r=ty; r<32; r+=8) out[(size_t)(bx+r)*R + by + tx] = tile[tx][r];
}

// ---------- squared norms (R2-proven) ----------
__global__ void sqnorm_k(const float* __restrict__ condF, float* __restrict__ sq){
  int row  = blockIdx.x*4 + (threadIdx.x>>6);
  int lane = threadIdx.x&63;
  const float* r = condF + (size_t)row*DF;
  float a = r[lane], b = r[lane+64];
  double s = (double)a*a + (double)b*b;
  #pragma unroll
  for(int off=32; off>0; off>>=1) s += __shfl_down(s, off, 64);
  if(lane==0) sq[row] = (float)s;
}

// ---------- gram -> dist via hi/lo bf16 split MFMA (R6-proven) ----------
__global__ __launch_bounds__(256) void gram_dist_k(const float* __restrict__ condF,
    const float* __restrict__ sq, float* __restrict__ dist){
  __shared__ u16 Ahi[128*40], Alo[128*40], Bhi[128*40], Blo[128*40];
  const int bm = blockIdx.x*128, bn = blockIdx.y*128;
  const int tid = threadIdx.x, lane = tid&63, wave = tid>>6;
  const int wm = (wave&1)*64, wn = (wave>>1)*64;
  v4f acc[4][4] = {};
  for(int kb=0; kb<DF; kb+=32){
    #pragma unroll
    for(int t=0;t<4;t++){
      int ch = tid + t*256;
      int r = ch>>3, c = (ch&7)*4;
      float4 av = *(const float4*)&condF[(size_t)(bm+r)*DF + kb + c];
      float4 bv = *(const float4*)&condF[(size_t)(bn+r)*DF + kb + c];
      ushort4 ah, al, bh, bl;
      ah.x=f2bf(av.x); ah.y=f2bf(av.y); ah.z=f2bf(av.z); ah.w=f2bf(av.w);
      al.x=f2bf(av.x-bf2f(ah.x)); al.y=f2bf(av.y-bf2f(ah.y));
      al.z=f2bf(av.z-bf2f(ah.z)); al.w=f2bf(av.w-bf2f(ah.w));
      bh.x=f2bf(bv.x); bh.y=f2bf(bv.y); bh.z=f2bf(bv.z); bh.w=f2bf(bv.w);
      bl.x=f2bf(bv.x-bf2f(bh.x)); bl.y=f2bf(bv.y-bf2f(bh.y));
      bl.z=f2bf(bv.z-bf2f(bh.z)); bl.w=f2bf(bv.w-bf2f(bh.w));
      *(ushort4*)&Ahi[r*40+c] = ah; *(ushort4*)&Alo[r*40+c] = al;
      *(ushort4*)&Bhi[r*40+c] = bh; *(ushort4*)&Blo[r*40+c] = bl;
    }
    __syncthreads();
    const int m16 = lane&15, q = lane>>4;
    v8bf ahf[4], alf[4], bhf[4], blf[4];
    #pragma unroll
    for(int x=0;x<4;x++){
      ahf[x] = *(const v8bf*)&Ahi[(wm + x*16 + m16)*40 + q*8];
      alf[x] = *(const v8bf*)&Alo[(wm + x*16 + m16)*40 + q*8];
      bhf[x] = *(const v8bf*)&Bhi[(wn + x*16 + m16)*40 + q*8];
      blf[x] = *(const v8bf*)&Blo[(wn + x*16 + m16)*40 + q*8];
    }
    #pragma unroll
    for(int mi=0;mi<4;mi++)
      #pragma unroll
      for(int ni=0;ni<4;ni++){
        acc[mi][ni] = __builtin_amdgcn_mfma_f32_16x16x32_bf16(alf[mi], bhf[ni], acc[mi][ni], 0,0,0);
        acc[mi][ni] = __builtin_amdgcn_mfma_f32_16x16x32_bf16(ahf[mi], blf[ni], acc[mi][ni], 0,0,0);
        acc[mi][ni] = __builtin_amdgcn_mfma_f32_16x16x32_bf16(ahf[mi], bhf[ni], acc[mi][ni], 0,0,0);
      }
    __syncthreads();
  }
  const int col16 = lane&15, rowq = lane>>4;
  #pragma unroll
  for(int mi=0;mi<4;mi++){
    #pragma unroll
    for(int ni=0;ni<4;ni++){
      int cj = bn + wn + ni*16 + col16;
      float sqj = sq[cj];
      #pragma unroll
      for(int r=0;r<4;r++){
        int ri = bm + wm + mi*16 + rowq*4 + r;
        float d2 = (sq[ri] + sqj) - 2.0f*acc[mi][ni][r];
        dist[(size_t)ri*NPTS + cj] = sqrtf(fmaxf(d2, 0.f));
      }
    }
  }
}

// ---------- screen: top-16 per row (R6-proven structure) ----------
__global__ __launch_bounds__(256) void topk_scr_k(const float* __restrict__ dist,
                                                  int* __restrict__ cand){
  const int i = blockIdx.x, tid = threadIdx.x;
  __shared__ u64 lst[256*16];
  __shared__ u64 red[256];
  u64 best[16];
  const float* drow = dist + (size_t)i*NPTS;
  #pragma unroll
  for(int t=0;t<16;t++){
    int j = tid + t*256;
    float d = drow[j];
    u64 key = ((u64)__float_as_uint(d)<<32) | (unsigned)j;
    best[t] = key;
    #pragma unroll
    for(int s=15; s>0; --s){
      if(s<=t && best[s] < best[s-1]){ u64 tmp=best[s]; best[s]=best[s-1]; best[s-1]=tmp; }
    }
  }
  #pragma unroll
  for(int t=0;t<16;t++) lst[tid*16+t] = best[t];
  __syncthreads();
  int pos = 0;
  for(int r=0;r<SCR;r++){
    u64 h = (pos<16) ? lst[tid*16+pos] : ~0ULL;
    red[tid] = h;
    __syncthreads();
    for(int s=128; s>0; s>>=1){
      if(tid<s){ u64 o = red[tid+s]; if(o<red[tid]) red[tid]=o; }
      __syncthreads();
    }
    u64 win = red[0];
    __syncthreads();
    if(h==win) pos++;
    if(tid==0) cand[i*SCR+r] = (int)(win & 0xffffffffu);
  }
}

// ---------- refine: fp64 exact distances for 16 candidates -> top-10 ----------
__global__ __launch_bounds__(64) void refine_k(const float* __restrict__ condF,
    const int* __restrict__ cand, int* __restrict__ nidx){
  const int i = blockIdx.x, t = threadIdx.x;
  __shared__ float  af[DF];
  __shared__ double ds[SCR];
  __shared__ int    idxs[SCR];
  af[t]    = condF[(size_t)i*DF + t];
  af[t+64] = condF[(size_t)i*DF + t + 64];
  __syncthreads();
  if(t < SCR){
    int j = cand[i*SCR + t] & (NPTS-1);
    const float* bp = condF + (size_t)j*DF;
    double s = 0.0;
    for(int e=0; e<DF; ++e){
      double d = (double)af[e] - (double)bp[e];
      s += d*d;
    }
    ds[t]   = sqrt(s);
    idxs[t] = j;
  }
  __syncthreads();
  if(t==0){
    unsigned used = 0;
    for(int r=0;r<KNN;r++){
      int bm=0, bi=0x7fffffff; double bd=1e300;
      for(int c=0;c<SCR;c++){
        if(used & (1u<<c)) continue;
        if(ds[c]<bd || (ds[c]==bd && idxs[c]<bi)){ bd=ds[c]; bi=idxs[c]; bm=c; }
      }
      used |= (1u<<bm);
      nidx[i*KNN+r] = bi;
    }
  }
}

// ---------- X = concat(cond[j], tens[j]) rows, bf16 ----------
__global__ void buildx_k(const float* __restrict__ condF, const float* __restrict__ tensF,
                         const int* __restrict__ nidx, u16* __restrict__ X){
  int c = blockIdx.x*256 + threadIdx.x;
  int m = c/48;
  int off = (c - m*48)*4;
  int j = nidx[m] & (NPTS-1);
  float4 v = (off < DF) ? *(const float4*)&condF[(size_t)j*DF + off]
                        : *(const float4*)&tensF[(size_t)j*DR + (off-DF)];
  ushort4 o; o.x=f2bf(v.x); o.y=f2bf(v.y); o.z=f2bf(v.z); o.w=f2bf(v.w);
  *(ushort4*)&X[(size_t)m*DIN + off] = o;
}

// ---------- GEMM: C = act(A @ Bt^T + bias), global_load_lds staging ----------
// LDS tiles 128x32 bf16, chunk-linear (chunk = 16B = 8 elems; chunk c = r*4+q).
template<int ACT>
__global__ __launch_bounds__(256,2) void gemm_bt_k(const u16* __restrict__ A,
    const u16* __restrict__ Bt, const float* __restrict__ bias, u16* __restrict__ C,
    int M, int Nc, int Kc){
  __shared__ u16 As[128*32];
  __shared__ u16 Bs[128*32];
  const int bm = blockIdx.x*128, bn = blockIdx.y*128;
  const int tid = threadIdx.x, lane = tid&63, wave = tid>>6;
  const int wm = (wave&1)*64, wn = (wave>>1)*64;
  // staging: wave w, inst i covers chunks c = w*128 + i*64 + lane
  int c0 = wave*128 + lane, c1 = c0 + 64;
  int r0 = c0>>2, q0 = c0&3, r1 = c1>>2, q1 = c1&3;
  const u16* pA0 = A  + (size_t)(bm+r0)*Kc + q0*8;
  const u16* pA1 = A  + (size_t)(bm+r1)*Kc + q1*8;
  const u16* pB0 = Bt + (size_t)(bn+r0)*Kc + q0*8;
  const u16* pB1 = Bt + (size_t)(bn+r1)*Kc + q1*8;
  u16* lA0 = &As[(wave*128      )*8];
  u16* lA1 = &As[(wave*128 + 64 )*8];
  u16* lB0 = &Bs[(wave*128      )*8];
  u16* lB1 = &Bs[(wave*128 + 64 )*8];
  const int m16 = lane&15, q = lane>>4;
  v4f acc[4][4] = {};
  for(int kb=0; kb<Kc; kb+=32){
    gl2lds16(pA0 + kb, lA0);
    gl2lds16(pA1 + kb, lA1);
    gl2lds16(pB0 + kb, lB0);
    gl2lds16(pB1 + kb, lB1);
    __syncthreads();           // drains vmcnt -> DMA data visible
    v8bf a[4], b[4];
    #pragma unroll
    for(int x=0;x<4;x++){
      a[x] = *(const v8bf*)&As[(wm + x*16 + m16)*32 + q*8];
      b[x] = *(const v8bf*)&Bs[(wn + x*16 + m16)*32 + q*8];
    }
    #pragma unroll
    for(int mi=0;mi<4;mi++)
      #pragma unroll
      for(int ni=0;ni<4;ni++)
        acc[mi][ni] = __builtin_amdgcn_mfma_f32_16x16x32_bf16(a[mi], b[ni], acc[mi][ni], 0,0,0);
    __syncthreads();
  }
  const int col16 = lane&15, rowq = lane>>4;
  #pragma unroll
  for(int mi=0;mi<4;mi++){
    #pragma unroll
    for(int ni=0;ni<4;ni++){
      int cn = bn + wn + ni*16 + col16;
      float bi = bias[cn];
      #pragma unroll
      for(int r=0;r<4;r++){
        int rw = bm + wm + mi*16 + rowq*4 + r;
        float v = acc[mi][ni][r] + bi;
        if(ACT) v = softplus_f(v);
        C[(size_t)rw*Nc + cn] = f2bf(v);
      }
    }
  }
}

// ---------- final layer, global_load_lds staging ----------
__global__ __launch_bounds__(256,2) void gemm_out_k(const u16* __restrict__ A,
    const u16* __restrict__ Bt, const float* __restrict__ bias,
    const float* __restrict__ tensF, const int* __restrict__ nidx,
    void* __restrict__ outv, const int* __restrict__ flag){
  __shared__ u16 As[128*32];
  __shared__ u16 Bs[64*32];
  const int fl = *flag;
  const int bm = blockIdx.x*128;
  const int tid = threadIdx.x, lane = tid&63, wave = tid>>6;
  const int wm = wave*32;
  int c0 = wave*128 + lane, c1 = c0 + 64;
  int ra0 = c0>>2, qa0 = c0&3, ra1 = c1>>2, qa1 = c1&3;
  int cb = wave*64 + lane;                 // B tile: 64x32 = 256 chunks
  int rb = cb>>2, qb = cb&3;
  const u16* pA0 = A  + (size_t)(bm+ra0)*HID + qa0*8;
  const u16* pA1 = A  + (size_t)(bm+ra1)*HID + qa1*8;
  const u16* pB  = Bt + (size_t)rb*HID + qb*8;
  u16* lA0 = &As[(wave*128     )*8];
  u16* lA1 = &As[(wave*128 + 64)*8];
  u16* lB  = &Bs[(wave*64      )*8];
  const int m16 = lane&15, q = lane>>4;
  v4f acc[2][4] = {};
  for(int kb=0; kb<HID; kb+=32){
    gl2lds16(pA0 + kb, lA0);
    gl2lds16(pA1 + kb, lA1);
    gl2lds16(pB  + kb, lB);
    __syncthreads();
    v8bf a[2], b[4];
    a[0] = *(const v8bf*)&As[(wm + m16)*32 + q*8];
    a[1] = *(const v8bf*)&As[(wm + 16 + m16)*32 + q*8];
    #pragma unroll
    for(int x=0;x<4;x++) b[x] = *(const v8bf*)&Bs[(x*16 + m16)*32 + q*8];
    #pragma unroll
    for(int mi=0;mi<2;mi++)
      #pragma unroll
      for(int ni=0;ni<4;ni++)
        acc[mi][ni] = __builtin_amdgcn_mfma_f32_16x16x32_bf16(a[mi], b[ni], acc[mi][ni], 0,0,0);
    __syncthreads();
  }
  const int col16 = lane&15, rowq = lane>>4;
  #pragma unroll
  for(int mi=0;mi<2;mi++){
    #pragma unroll
    for(int ni=0;ni<4;ni++){
      int cn = ni*16 + col16;
      float bi = bias[cn];
      #pragma unroll
      for(int r=0;r<4;r++){
        int rw = bm + wm + mi*16 + rowq*4 + r;
        int j = nidx[rw] & (NPTS-1);
        float y = tensF[(size_t)j*DR + cn] - (acc[mi][ni][r] + bi);
        if(fl) ((u16*)outv)[(size_t)rw*DR + cn] = f2bf(y);
        else   ((float*)outv)[(size_t)rw*DR + cn] = y;
      }
    }
  }
}

// ---------- workspace layout (~178.5 MB) ----------
constexpr size_t OFF_FLAG  = 0;
constexpr size_t OFF_SQ    = 256;
constexpr size_t OFF_NIDX  = OFF_SQ    + 16384;
constexpr size_t OFF_BIAS  = OFF_NIDX  + 163840;
constexpr size_t OFF_CONDF = OFF_BIAS  + 16640;
constexpr size_t OFF_TENSF = OFF_CONDF + 2097152;
constexpr size_t OFF_WTIN  = OFF_TENSF + 1048576;
constexpr size_t OFF_WT1   = OFF_WTIN  + 393216;
constexpr size_t OFF_WT2   = OFF_WT1   + 2097152;
constexpr size_t OFF_WT3   = OFF_WT2   + 2097152;
constexpr size_t OFF_WTO   = OFF_WT3   + 2097152;
constexpr size_t OFF_RA    = OFF_WTO   + 131072;     // dist (67MB) then A0 (84MB)
constexpr size_t OFF_RB    = OFF_RA    + 83886080;   // X (15.7MB) then A1 (84MB)
constexpr size_t OFF_CAND  = OFF_RB    + 83886080;   // 256 KB

extern "C" void kernel_launch(void* const* d_in, const int* in_sizes, int n_in,
                              void* d_out, int out_size, void* d_ws, size_t ws_size,
                              hipStream_t stream){
  char* ws = (char*)d_ws;
  int*   flag  = (int*)  (ws + OFF_FLAG);
  float* sqv   = (float*)(ws + OFF_SQ);
  int*   nidx  = (int*)  (ws + OFF_NIDX);
  float* biasF = (float*)(ws + OFF_BIAS);
  float* condF = (float*)(ws + OFF_CONDF);
  float* tensF = (float*)(ws + OFF_TENSF);
  u16*   Wt_in = (u16*)  (ws + OFF_WTIN);
  u16*   Wt1   = (u16*)  (ws + OFF_WT1);
  u16*   Wt2   = (u16*)  (ws + OFF_WT2);
  u16*   Wt3   = (u16*)  (ws + OFF_WT3);
  u16*   Wt_o  = (u16*)  (ws + OFF_WTO);
  float* dist  = (float*)(ws + OFF_RA);
  u16*   A0    = (u16*)  (ws + OFF_RA);
  u16*   X     = (u16*)  (ws + OFF_RB);
  u16*   A1    = (u16*)  (ws + OFF_RB);
  int*   cand  = (int*)  (ws + OFF_CAND);

  detect_k <<<1, 256, 0, stream>>>((const u16*)d_in[0], flag);
  cvt_all_k<<<3089, 256, 0, stream>>>(d_in[0], d_in[1], d_in[3], d_in[5], d_in[7],
                                      d_in[9], d_in[11], condF, tensF, biasF, flag);
  transpose_flag_k<<<dim3(32, 6), dim3(32,8), 0, stream>>>(d_in[2],  Wt_in, 192, 1024, flag);
  transpose_flag_k<<<dim3(32,32), dim3(32,8), 0, stream>>>(d_in[4],  Wt1, 1024, 1024, flag);
  transpose_flag_k<<<dim3(32,32), dim3(32,8), 0, stream>>>(d_in[6],  Wt2, 1024, 1024, flag);
  transpose_flag_k<<<dim3(32,32), dim3(32,8), 0, stream>>>(d_in[8],  Wt3, 1024, 1024, flag);
  transpose_flag_k<<<dim3( 2,32), dim3(32,8), 0, stream>>>(d_in[10], Wt_o, 1024,  64, flag);
  sqnorm_k   <<<1024, 256, 0, stream>>>(condF, sqv);
  gram_dist_k<<<dim3(32,32), 256, 0, stream>>>(condF, sqv, dist);
  topk_scr_k <<<NPTS, 256, 0, stream>>>(dist, cand);
  refine_k   <<<NPTS, 64, 0, stream>>>(condF, cand, nidx);
  buildx_k   <<<7680, 256, 0, stream>>>(condF, tensF, nidx, X);
  gemm_bt_k<1><<<dim3(320,8), 256, 0, stream>>>(X,  Wt_in, biasF,      A0, MROWS, HID, DIN);
  gemm_bt_k<1><<<dim3(320,8), 256, 0, stream>>>(A0, Wt1,   biasF+1024, A1, MROWS, HID, HID);
  gemm_bt_k<1><<<dim3(320,8), 256, 0, stream>>>(A1, Wt2,   biasF+2048, A0, MROWS, HID, HID);
  gemm_bt_k<1><<<dim3(320,8), 256, 0, stream>>>(A0, Wt3,   biasF+3072, A1, MROWS, HID, HID);
  gemm_out_k  <<<320, 256, 0, stream>>>(A1, Wt_o, biasF+4096, tensF, nidx, d_out, flag);
}

// Round 8
// 655.433 us; speedup vs baseline: 1.7789x; 1.5704x over previous
//
// MongeGapTransport: KNN gather + 5-layer MLP pushforward, bf16 I/O (confirmed).
// R8: R7 + XCD-aware block swizzle in GEMMs (A-tile reuse within one XCD L2:
// bid -> xcd=bid&7, bm=xcd+8*(bid>>6), bn=(bid>>3)&7) + fast softplus
// (__expf/__logf hw intrinsics). Theory: R7 was L2/L3-delivery-bound
// (65 FLOP/B * 5.8 TB/s = 377 TF == measured 381 TF).
#include <hip/hip_runtime.h>
#include <stdint.h>

typedef unsigned short u16;
typedef unsigned long long u64;
typedef short v8bf __attribute__((ext_vector_type(8)));
typedef float v4f  __attribute__((ext_vector_type(4)));

#define NPTS 4096
#define DF   128
#define DR   64
#define HID  1024
#define KNN  10
#define SCR  16
#define MROWS (NPTS*KNN)   // 40960
#define DIN  192

#define AS1 __attribute__((address_space(1)))
#define AS3 __attribute__((address_space(3)))

__device__ __forceinline__ float bf2f(u16 b){ return __uint_as_float(((unsigned)b)<<16); }
__device__ __forceinline__ u16 f2bf(float f){
  unsigned u = __float_as_uint(f);
  unsigned r = 0x7fffu + ((u>>16)&1u);
  return (u16)((u + r)>>16);
}
// fast softplus: hw v_exp/v_log; for x<=-15 exp underflows -> 0 (fine at bf16 out)
__device__ __forceinline__ float softplus_f(float x){
  return x>15.f ? x : __logf(1.f + __expf(x));
}
__device__ __forceinline__ float rdv(const void* p, long j, int fl){
  return fl ? bf2f(((const u16*)p)[j]) : ((const float*)p)[j];
}
// async global->LDS, 16B per lane; lds dest = wave-uniform base + lane*16
__device__ __forceinline__ void gl2lds16(const u16* g, u16* l){
  __builtin_amdgcn_global_load_lds((const AS1 unsigned int*)g, (AS3 unsigned int*)l, 16, 0, 0);
}

// ---------- dtype detection (R2-proven) ----------
__global__ void detect_k(const u16* __restrict__ c, int* __restrict__ flag){
  __shared__ int cnt[256];
  int t = threadIdx.x, n = 0;
  for(int i=t; i<8192; i+=256){
    u16 v = c[2*i];
    int e = (v>>7)&0xff;
    n += (e>=96 && e<=158);
  }
  cnt[t] = n; __syncthreads();
  for(int s=128; s>0; s>>=1){ if(t<s) cnt[t]+=cnt[t+s]; __syncthreads(); }
  if(t==0) *flag = (cnt[0] > 4915) ? 1 : 0;
}

// ---------- canonicalize to fp32 (R2-proven) ----------
__global__ void cvt_all_k(const void* c, const void* t, const void* bi, const void* b1,
                          const void* b2, const void* b3, const void* bo,
                          float* __restrict__ condF, float* __restrict__ tensF,
                          float* __restrict__ biasF, const int* __restrict__ flag){
  const int fl = *flag;
  int i = blockIdx.x*256 + threadIdx.x;
  if(i < 524288){ condF[i] = rdv(c, i, fl); }
  else if(i < 786432){ tensF[i-524288] = rdv(t, i-524288, fl); }
  else{
    int j = i - 786432;
    if(j < 1024)      biasF[j] = rdv(bi, j, fl);
    else if(j < 2048) biasF[j] = rdv(b1, j-1024, fl);
    else if(j < 3072) biasF[j] = rdv(b2, j-2048, fl);
    else if(j < 4096) biasF[j] = rdv(b3, j-3072, fl);
    else if(j < 4160) biasF[j] = rdv(bo, j-4096, fl);
  }
}

// ---------- flag-aware transpose -> bf16 Bt (R2-proven) ----------
__global__ void transpose_flag_k(const void* __restrict__ in, u16* __restrict__ out,
                                 int R, int C, const int* __restrict__ flag){
  __shared__ u16 tile[32][33];
  const int fl = *flag;
  int bx = blockIdx.x*32, by = blockIdx.y*32;
  int tx = threadIdx.x, ty = threadIdx.y;
  #pragma unroll
  for(int r=ty; r<32; r+=8){
    size_t idx = (size_t)(by+r)*C + bx + tx;
    tile[r][tx] = fl ? ((const u16*)in)[idx] : f2bf(((const float*)in)[idx]);
  }
  __syncthreads();
  #pragma unroll
  for(int r=ty; r<32; r+=8) out[(size_t)(bx+r)*R + by + tx] = tile[tx][r];
}

// ---------- squared norms (R2-proven) ----------
__global__ void sqnorm_k(const float* __restrict__ condF, float* __restrict__ sq){
  int row  = blockIdx.x*4 + (threadIdx.x>>6);
  int lane = threadIdx.x&63;
  const float* r = condF + (size_t)row*DF;
  float a = r[lane], b = r[lane+64];
  double s = (double)a*a + (double)b*b;
  #pragma unroll
  for(int off=32; off>0; off>>=1) s += __shfl_down(s, off, 64);
  if(lane==0) sq[row] = (float)s;
}

// ---------- gram -> dist via hi/lo bf16 split MFMA (R6-proven) ----------
__global__ __launch_bounds__(256) void gram_dist_k(const float* __restrict__ condF,
    const float* __restrict__ sq, float* __restrict__ dist){
  __shared__ u16 Ahi[128*40], Alo[128*40], Bhi[128*40], Blo[128*40];
  const int bm = blockIdx.x*128, bn = blockIdx.y*128;
  const int tid = threadIdx.x, lane = tid&63, wave = tid>>6;
  const int wm = (wave&1)*64, wn = (wave>>1)*64;
  v4f acc[4][4] = {};
  for(int kb=0; kb<DF; kb+=32){
    #pragma unroll
    for(int t=0;t<4;t++){
      int ch = tid + t*256;
      int r = ch>>3, c = (ch&7)*4;
      float4 av = *(const float4*)&condF[(size_t)(bm+r)*DF + kb + c];
      float4 bv = *(const float4*)&condF[(size_t)(bn+r)*DF + kb + c];
      ushort4 ah, al, bh, bl;
      ah.x=f2bf(av.x); ah.y=f2bf(av.y); ah.z=f2bf(av.z); ah.w=f2bf(av.w);
      al.x=f2bf(av.x-bf2f(ah.x)); al.y=f2bf(av.y-bf2f(ah.y));
      al.z=f2bf(av.z-bf2f(ah.z)); al.w=f2bf(av.w-bf2f(ah.w));
      bh.x=f2bf(bv.x); bh.y=f2bf(bv.y); bh.z=f2bf(bv.z); bh.w=f2bf(bv.w);
      bl.x=f2bf(bv.x-bf2f(bh.x)); bl.y=f2bf(bv.y-bf2f(bh.y));
      bl.z=f2bf(bv.z-bf2f(bh.z)); bl.w=f2bf(bv.w-bf2f(bh.w));
      *(ushort4*)&Ahi[r*40+c] = ah; *(ushort4*)&Alo[r*40+c] = al;
      *(ushort4*)&Bhi[r*40+c] = bh; *(ushort4*)&Blo[r*40+c] = bl;
    }
    __syncthreads();
    const int m16 = lane&15, q = lane>>4;
    v8bf ahf[4], alf[4], bhf[4], blf[4];
    #pragma unroll
    for(int x=0;x<4;x++){
      ahf[x] = *(const v8bf*)&Ahi[(wm + x*16 + m16)*40 + q*8];
      alf[x] = *(const v8bf*)&Alo[(wm + x*16 + m16)*40 + q*8];
      bhf[x] = *(const v8bf*)&Bhi[(wn + x*16 + m16)*40 + q*8];
      blf[x] = *(const v8bf*)&Blo[(wn + x*16 + m16)*40 + q*8];
    }
    #pragma unroll
    for(int mi=0;mi<4;mi++)
      #pragma unroll
      for(int ni=0;ni<4;ni++){
        acc[mi][ni] = __builtin_amdgcn_mfma_f32_16x16x32_bf16(alf[mi], bhf[ni], acc[mi][ni], 0,0,0);
        acc[mi][ni] = __builtin_amdgcn_mfma_f32_16x16x32_bf16(ahf[mi], blf[ni], acc[mi][ni], 0,0,0);
        acc[mi][ni] = __builtin_amdgcn_mfma_f32_16x16x32_bf16(ahf[mi], bhf[ni], acc[mi][ni], 0,0,0);
      }
    __syncthreads();
  }
  const int col16 = lane&15, rowq = lane>>4;
  #pragma unroll
  for(int mi=0;mi<4;mi++){
    #pragma unroll
    for(int ni=0;ni<4;ni++){
      int cj = bn + wn + ni*16 + col16;
      float sqj = sq[cj];
      #pragma unroll
      for(int r=0;r<4;r++){
        int ri = bm + wm + mi*16 + rowq*4 + r;
        float d2 = (sq[ri] + sqj) - 2.0f*acc[mi][ni][r];
        dist[(size_t)ri*NPTS + cj] = sqrtf(fmaxf(d2, 0.f));
      }
    }
  }
}

// ---------- screen: top-16 per row (R6-proven structure) ----------
__global__ __launch_bounds__(256) void topk_scr_k(const float* __restrict__ dist,
                                                  int* __restrict__ cand){
  const int i = blockIdx.x, tid = threadIdx.x;
  __shared__ u64 lst[256*16];
  __shared__ u64 red[256];
  u64 best[16];
  const float* drow = dist + (size_t)i*NPTS;
  #pragma unroll
  for(int t=0;t<16;t++){
    int j = tid + t*256;
    float d = drow[j];
    u64 key = ((u64)__float_as_uint(d)<<32) | (unsigned)j;
    best[t] = key;
    #pragma unroll
    for(int s=15; s>0; --s){
      if(s<=t && best[s] < best[s-1]){ u64 tmp=best[s]; best[s]=best[s-1]; best[s-1]=tmp; }
    }
  }
  #pragma unroll
  for(int t=0;t<16;t++) lst[tid*16+t] = best[t];
  __syncthreads();
  int pos = 0;
  for(int r=0;r<SCR;r++){
    u64 h = (pos<16) ? lst[tid*16+pos] : ~0ULL;
    red[tid] = h;
    __syncthreads();
    for(int s=128; s>0; s>>=1){
      if(tid<s){ u64 o = red[tid+s]; if(o<red[tid]) red[tid]=o; }
      __syncthreads();
    }
    u64 win = red[0];
    __syncthreads();
    if(h==win) pos++;
    if(tid==0) cand[i*SCR+r] = (int)(win & 0xffffffffu);
  }
}

// ---------- refine: fp64 exact distances for 16 candidates -> top-10 ----------
__global__ __launch_bounds__(64) void refine_k(const float* __restrict__ condF,
    const int* __restrict__ cand, int* __restrict__ nidx){
  const int i = blockIdx.x, t = threadIdx.x;
  __shared__ float  af[DF];
  __shared__ double ds[SCR];
  __shared__ int    idxs[SCR];
  af[t]    = condF[(size_t)i*DF + t];
  af[t+64] = condF[(size_t)i*DF + t + 64];
  __syncthreads();
  if(t < SCR){
    int j = cand[i*SCR + t] & (NPTS-1);
    const float* bp = condF + (size_t)j*DF;
    double s = 0.0;
    for(int e=0; e<DF; ++e){
      double d = (double)af[e] - (double)bp[e];
      s += d*d;
    }
    ds[t]   = sqrt(s);
    idxs[t] = j;
  }
  __syncthreads();
  if(t==0){
    unsigned used = 0;
    for(int r=0;r<KNN;r++){
      int bm=0, bi=0x7fffffff; double bd=1e300;
      for(int c=0;c<SCR;c++){
        if(used & (1u<<c)) continue;
        if(ds[c]<bd || (ds[c]==bd && idxs[c]<bi)){ bd=ds[c]; bi=idxs[c]; bm=c; }
      }
      used |= (1u<<bm);
      nidx[i*KNN+r] = bi;
    }
  }
}

// ---------- X = concat(cond[j], tens[j]) rows, bf16 ----------
__global__ void buildx_k(const float* __restrict__ condF, const float* __restrict__ tensF,
                         const int* __restrict__ nidx, u16* __restrict__ X){
  int c = blockIdx.x*256 + threadIdx.x;
  int m = c/48;
  int off = (c - m*48)*4;
  int j = nidx[m] & (NPTS-1);
  float4 v = (off < DF) ? *(const float4*)&condF[(size_t)j*DF + off]
                        : *(const float4*)&tensF[(size_t)j*DR + (off-DF)];
  ushort4 o; o.x=f2bf(v.x); o.y=f2bf(v.y); o.z=f2bf(v.z); o.w=f2bf(v.w);
  *(ushort4*)&X[(size_t)m*DIN + off] = o;
}

// ---------- GEMM: C = act(A @ Bt^T + bias), global_load_lds staging ----------
// 1-D grid, XCD-aware decode: xcd=bid&7, bm_t=xcd+8*(bid>>6), bn_t=(bid>>3)&7.
// All 8 bn-blocks of one bm are consecutive slots on ONE XCD -> A-tile enters
// exactly one L2, B (2MB) stays L2-resident.
template<int ACT>
__global__ __launch_bounds__(256,2) void gemm_bt_k(const u16* __restrict__ A,
    const u16* __restrict__ Bt, const float* __restrict__ bias, u16* __restrict__ C,
    int M, int Nc, int Kc){
  __shared__ u16 As[128*32];
  __shared__ u16 Bs[128*32];
  const int bid = blockIdx.x;
  const int bm = ((bid&7) + ((bid>>6)<<3)) * 128;
  const int bn = ((bid>>3)&7) * 128;
  const int tid = threadIdx.x, lane = tid&63, wave = tid>>6;
  const int wm = (wave&1)*64, wn = (wave>>1)*64;
  int c0 = wave*128 + lane, c1 = c0 + 64;
  int r0 = c0>>2, q0 = c0&3, r1 = c1>>2, q1 = c1&3;
  const u16* pA0 = A  + (size_t)(bm+r0)*Kc + q0*8;
  const u16* pA1 = A  + (size_t)(bm+r1)*Kc + q1*8;
  const u16* pB0 = Bt + (size_t)(bn+r0)*Kc + q0*8;
  const u16* pB1 = Bt + (size_t)(bn+r1)*Kc + q1*8;
  u16* lA0 = &As[(wave*128      )*8];
  u16* lA1 = &As[(wave*128 + 64 )*8];
  u16* lB0 = &Bs[(wave*128      )*8];
  u16* lB1 = &Bs[(wave*128 + 64 )*8];
  const int m16 = lane&15, q = lane>>4;
  v4f acc[4][4] = {};
  for(int kb=0; kb<Kc; kb+=32){
    gl2lds16(pA0 + kb, lA0);
    gl2lds16(pA1 + kb, lA1);
    gl2lds16(pB0 + kb, lB0);
    gl2lds16(pB1 + kb, lB1);
    __syncthreads();
    v8bf a[4], b[4];
    #pragma unroll
    for(int x=0;x<4;x++){
      a[x] = *(const v8bf*)&As[(wm + x*16 + m16)*32 + q*8];
      b[x] = *(const v8bf*)&Bs[(wn + x*16 + m16)*32 + q*8];
    }
    #pragma unroll
    for(int mi=0;mi<4;mi++)
      #pragma unroll
      for(int ni=0;ni<4;ni++)
        acc[mi][ni] = __builtin_amdgcn_mfma_f32_16x16x32_bf16(a[mi], b[ni], acc[mi][ni], 0,0,0);
    __syncthreads();
  }
  const int col16 = lane&15, rowq = lane>>4;
  #pragma unroll
  for(int mi=0;mi<4;mi++){
    #pragma unroll
    for(int ni=0;ni<4;ni++){
      int cn = bn + wn + ni*16 + col16;
      float bi = bias[cn];
      #pragma unroll
      for(int r=0;r<4;r++){
        int rw = bm + wm + mi*16 + rowq*4 + r;
        float v = acc[mi][ni][r] + bi;
        if(ACT) v = softplus_f(v);
        C[(size_t)rw*Nc + cn] = f2bf(v);
      }
    }
  }
}

// ---------- final layer, global_load_lds staging ----------
__global__ __launch_bounds__(256,2) void gemm_out_k(const u16* __restrict__ A,
    const u16* __restrict__ Bt, const float* __restrict__ bias,
    const float* __restrict__ tensF, const int* __restrict__ nidx,
    void* __restrict__ outv, const int* __restrict__ flag){
  __shared__ u16 As[128*32];
  __shared__ u16 Bs[64*32];
  const int fl = *flag;
  const int bm = blockIdx.x*128;
  const int tid = threadIdx.x, lane = tid&63, wave = tid>>6;
  const int wm = wave*32;
  int c0 = wave*128 + lane, c1 = c0 + 64;
  int ra0 = c0>>2, qa0 = c0&3, ra1 = c1>>2, qa1 = c1&3;
  int cb = wave*64 + lane;
  int rb = cb>>2, qb = cb&3;
  const u16* pA0 = A  + (size_t)(bm+ra0)*HID + qa0*8;
  const u16* pA1 = A  + (size_t)(bm+ra1)*HID + qa1*8;
  const u16* pB  = Bt + (size_t)rb*HID + qb*8;
  u16* lA0 = &As[(wave*128     )*8];
  u16* lA1 = &As[(wave*128 + 64)*8];
  u16* lB  = &Bs[(wave*64      )*8];
  const int m16 = lane&15, q = lane>>4;
  v4f acc[2][4] = {};
  for(int kb=0; kb<HID; kb+=32){
    gl2lds16(pA0 + kb, lA0);
    gl2lds16(pA1 + kb, lA1);
    gl2lds16(pB  + kb, lB);
    __syncthreads();
    v8bf a[2], b[4];
    a[0] = *(const v8bf*)&As[(wm + m16)*32 + q*8];
    a[1] = *(const v8bf*)&As[(wm + 16 + m16)*32 + q*8];
    #pragma unroll
    for(int x=0;x<4;x++) b[x] = *(const v8bf*)&Bs[(x*16 + m16)*32 + q*8];
    #pragma unroll
    for(int mi=0;mi<2;mi++)
      #pragma unroll
      for(int ni=0;ni<4;ni++)
        acc[mi][ni] = __builtin_amdgcn_mfma_f32_16x16x32_bf16(a[mi], b[ni], acc[mi][ni], 0,0,0);
    __syncthreads();
  }
  const int col16 = lane&15, rowq = lane>>4;
  #pragma unroll
  for(int mi=0;mi<2;mi++){
    #pragma unroll
    for(int ni=0;ni<4;ni++){
      int cn = ni*16 + col16;
      float bi = bias[cn];
      #pragma unroll
      for(int r=0;r<4;r++){
        int rw = bm + wm + mi*16 + rowq*4 + r;
        int j = nidx[rw] & (NPTS-1);
        float y = tensF[(size_t)j*DR + cn] - (acc[mi][ni][r] + bi);
        if(fl) ((u16*)outv)[(size_t)rw*DR + cn] = f2bf(y);
        else   ((float*)outv)[(size_t)rw*DR + cn] = y;
      }
    }
  }
}

// ---------- workspace layout (~178.5 MB) ----------
constexpr size_t OFF_FLAG  = 0;
constexpr size_t OFF_SQ    = 256;
constexpr size_t OFF_NIDX  = OFF_SQ    + 16384;
constexpr size_t OFF_BIAS  = OFF_NIDX  + 163840;
constexpr size_t OFF_CONDF = OFF_BIAS  + 16640;
constexpr size_t OFF_TENSF = OFF_CONDF + 2097152;
constexpr size_t OFF_WTIN  = OFF_TENSF + 1048576;
constexpr size_t OFF_WT1   = OFF_WTIN  + 393216;
constexpr size_t OFF_WT2   = OFF_WT1   + 2097152;
constexpr size_t OFF_WT3   = OFF_WT2   + 2097152;
constexpr size_t OFF_WTO   = OFF_WT3   + 2097152;
constexpr size_t OFF_RA    = OFF_WTO   + 131072;     // dist (67MB) then A0 (84MB)
constexpr size_t OFF_RB    = OFF_RA    + 83886080;   // X (15.7MB) then A1 (84MB)
constexpr size_t OFF_CAND  = OFF_RB    + 83886080;   // 256 KB

extern "C" void kernel_launch(void* const* d_in, const int* in_sizes, int n_in,
                              void* d_out, int out_size, void* d_ws, size_t ws_size,
                              hipStream_t stream){
  char* ws = (char*)d_ws;
  int*   flag  = (int*)  (ws + OFF_FLAG);
  float* sqv   = (float*)(ws + OFF_SQ);
  int*   nidx  = (int*)  (ws + OFF_NIDX);
  float* biasF = (float*)(ws + OFF_BIAS);
  float* condF = (float*)(ws + OFF_CONDF);
  float* tensF = (float*)(ws + OFF_TENSF);
  u16*   Wt_in = (u16*)  (ws + OFF_WTIN);
  u16*   Wt1   = (u16*)  (ws + OFF_WT1);
  u16*   Wt2   = (u16*)  (ws + OFF_WT2);
  u16*   Wt3   = (u16*)  (ws + OFF_WT3);
  u16*   Wt_o  = (u16*)  (ws + OFF_WTO);
  float* dist  = (float*)(ws + OFF_RA);
  u16*   A0    = (u16*)  (ws + OFF_RA);
  u16*   X     = (u16*)  (ws + OFF_RB);
  u16*   A1    = (u16*)  (ws + OFF_RB);
  int*   cand  = (int*)  (ws + OFF_CAND);

  detect_k <<<1, 256, 0, stream>>>((const u16*)d_in[0], flag);
  cvt_all_k<<<3089, 256, 0, stream>>>(d_in[0], d_in[1], d_in[3], d_in[5], d_in[7],
                                      d_in[9], d_in[11], condF, tensF, biasF, flag);
  transpose_flag_k<<<dim3(32, 6), dim3(32,8), 0, stream>>>(d_in[2],  Wt_in, 192, 1024, flag);
  transpose_flag_k<<<dim3(32,32), dim3(32,8), 0, stream>>>(d_in[4],  Wt1, 1024, 1024, flag);
  transpose_flag_k<<<dim3(32,32), dim3(32,8), 0, stream>>>(d_in[6],  Wt2, 1024, 1024, flag);
  transpose_flag_k<<<dim3(32,32), dim3(32,8), 0, stream>>>(d_in[8],  Wt3, 1024, 1024, flag);
  transpose_flag_k<<<dim3( 2,32), dim3(32,8), 0, stream>>>(d_in[10], Wt_o, 1024,  64, flag);
  sqnorm_k   <<<1024, 256, 0, stream>>>(condF, sqv);
  gram_dist_k<<<dim3(32,32), 256, 0, stream>>>(condF, sqv, dist);
  topk_scr_k <<<NPTS, 256, 0, stream>>>(dist, cand);
  refine_k   <<<NPTS, 64, 0, stream>>>(condF, cand, nidx);
  buildx_k   <<<7680, 256, 0, stream>>>(condF, tensF, nidx, X);
  gemm_bt_k<1><<<2560, 256, 0, stream>>>(X,  Wt_in, biasF,      A0, MROWS, HID, DIN);
  gemm_bt_k<1><<<2560, 256, 0, stream>>>(A0, Wt1,   biasF+1024, A1, MROWS, HID, HID);
  gemm_bt_k<1><<<2560, 256, 0, stream>>>(A1, Wt2,   biasF+2048, A0, MROWS, HID, HID);
  gemm_bt_k<1><<<2560, 256, 0, stream>>>(A0, Wt3,   biasF+3072, A1, MROWS, HID, HID);
  gemm_out_k  <<<320, 256, 0, stream>>>(A1, Wt_o, biasF+4096, tensF, nidx, d_out, flag);
}

// Round 10
// 646.660 us; speedup vs baseline: 1.8030x; 1.0136x over previous
//
// MongeGapTransport: KNN gather + 5-layer MLP pushforward, bf16 I/O (confirmed).
// R10: R9 minus the broken bf16-dist screen (bf16 ulp ~0.1 at d~13.5 creates
// mass ties at the rank-10..16 boundary -> containment failure; reverted to
// R8-proven fp32 dist + u64-key top-16). Kept: gram fast path (fl=1 skips
// zero lo-residual MFMAs, bitwise identical), fused weight transposes.
#include <hip/hip_runtime.h>
#include <stdint.h>

typedef unsigned short u16;
typedef unsigned int   u32;
typedef unsigned long long u64;
typedef short v8bf __attribute__((ext_vector_type(8)));
typedef float v4f  __attribute__((ext_vector_type(4)));

#define NPTS 4096
#define DF   128
#define DR   64
#define HID  1024
#define KNN  10
#define SCR  16
#define MROWS (NPTS*KNN)   // 40960
#define DIN  192

#define AS1 __attribute__((address_space(1)))
#define AS3 __attribute__((address_space(3)))

__device__ __forceinline__ float bf2f(u16 b){ return __uint_as_float(((unsigned)b)<<16); }
__device__ __forceinline__ u16 f2bf(float f){
  unsigned u = __float_as_uint(f);
  unsigned r = 0x7fffu + ((u>>16)&1u);
  return (u16)((u + r)>>16);
}
__device__ __forceinline__ float softplus_f(float x){
  return x>15.f ? x : __logf(1.f + __expf(x));
}
__device__ __forceinline__ float rdv(const void* p, long j, int fl){
  return fl ? bf2f(((const u16*)p)[j]) : ((const float*)p)[j];
}
__device__ __forceinline__ void gl2lds16(const u16* g, u16* l){
  __builtin_amdgcn_global_load_lds((const AS1 unsigned int*)g, (AS3 unsigned int*)l, 16, 0, 0);
}

// ---------- dtype detection (R2-proven) ----------
__global__ void detect_k(const u16* __restrict__ c, int* __restrict__ flag){
  __shared__ int cnt[256];
  int t = threadIdx.x, n = 0;
  for(int i=t; i<8192; i+=256){
    u16 v = c[2*i];
    int e = (v>>7)&0xff;
    n += (e>=96 && e<=158);
  }
  cnt[t] = n; __syncthreads();
  for(int s=128; s>0; s>>=1){ if(t<s) cnt[t]+=cnt[t+s]; __syncthreads(); }
  if(t==0) *flag = (cnt[0] > 4915) ? 1 : 0;
}

// ---------- canonicalize to fp32 (R2-proven) ----------
__global__ void cvt_all_k(const void* c, const void* t, const void* bi, const void* b1,
                          const void* b2, const void* b3, const void* bo,
                          float* __restrict__ condF, float* __restrict__ tensF,
                          float* __restrict__ biasF, const int* __restrict__ flag){
  const int fl = *flag;
  int i = blockIdx.x*256 + threadIdx.x;
  if(i < 524288){ condF[i] = rdv(c, i, fl); }
  else if(i < 786432){ tensF[i-524288] = rdv(t, i-524288, fl); }
  else{
    int j = i - 786432;
    if(j < 1024)      biasF[j] = rdv(bi, j, fl);
    else if(j < 2048) biasF[j] = rdv(b1, j-1024, fl);
    else if(j < 3072) biasF[j] = rdv(b2, j-2048, fl);
    else if(j < 4096) biasF[j] = rdv(b3, j-3072, fl);
    else if(j < 4160) biasF[j] = rdv(bo, j-4096, fl);
  }
}

// ---------- all 5 weight transposes in ONE launch (R9, math-identical) ----------
__global__ void transpose_all_k(const void* Wi, const void* W1, const void* W2,
    const void* W3, const void* Wo, u16* Oi, u16* O1, u16* O2, u16* O3, u16* Oo,
    const int* __restrict__ flag){
  __shared__ u16 tile[32][33];
  const int fl = *flag;
  int bid = blockIdx.x;
  const void* in; u16* out; int R, C, bx, by;
  if(bid < 192)      { int b=bid;      in=Wi; out=Oi; R=192;  C=1024; bx=b&31; by=b>>5; }
  else if(bid < 1216){ int b=bid-192;  in=W1; out=O1; R=1024; C=1024; bx=b&31; by=b>>5; }
  else if(bid < 2240){ int b=bid-1216; in=W2; out=O2; R=1024; C=1024; bx=b&31; by=b>>5; }
  else if(bid < 3264){ int b=bid-2240; in=W3; out=O3; R=1024; C=1024; bx=b&31; by=b>>5; }
  else               { int b=bid-3264; in=Wo; out=Oo; R=1024; C=64;   bx=b&1;  by=b>>1; }
  int gx = bx*32, gy = by*32;
  int tx = threadIdx.x, ty = threadIdx.y;
  #pragma unroll
  for(int r=ty; r<32; r+=8){
    size_t idx = (size_t)(gy+r)*C + gx + tx;
    tile[r][tx] = fl ? ((const u16*)in)[idx] : f2bf(((const float*)in)[idx]);
  }
  __syncthreads();
  #pragma unroll
  for(int r=ty; r<32; r+=8) out[(size_t)(gx+r)*R + gy + tx] = tile[tx][r];
}

// ---------- squared norms (R2-proven) ----------
__global__ void sqnorm_k(const float* __restrict__ condF, float* __restrict__ sq){
  int row  = blockIdx.x*4 + (threadIdx.x>>6);
  int lane = threadIdx.x&63;
  const float* r = condF + (size_t)row*DF;
  float a = r[lane], b = r[lane+64];
  double s = (double)a*a + (double)b*b;
  #pragma unroll
  for(int off=32; off>0; off>>=1) s += __shfl_down(s, off, 64);
  if(lane==0) sq[row] = (float)s;
}

// ---------- gram -> fp32 dist; hi/lo split only when inputs were fp32 ----------
__global__ __launch_bounds__(256) void gram_dist_k(const float* __restrict__ condF,
    const float* __restrict__ sq, float* __restrict__ dist, const int* __restrict__ flag){
  __shared__ u16 Ahi[128*40], Alo[128*40], Bhi[128*40], Blo[128*40];
  const int fl = *flag;   // 1 => bf16 inputs => lo residual is exactly zero
  const int bm = blockIdx.x*128, bn = blockIdx.y*128;
  const int tid = threadIdx.x, lane = tid&63, wave = tid>>6;
  const int wm = (wave&1)*64, wn = (wave>>1)*64;
  v4f acc[4][4] = {};
  for(int kb=0; kb<DF; kb+=32){
    #pragma unroll
    for(int t=0;t<4;t++){
      int ch = tid + t*256;
      int r = ch>>3, c = (ch&7)*4;
      float4 av = *(const float4*)&condF[(size_t)(bm+r)*DF + kb + c];
      float4 bv = *(const float4*)&condF[(size_t)(bn+r)*DF + kb + c];
      ushort4 ah, bh;
      ah.x=f2bf(av.x); ah.y=f2bf(av.y); ah.z=f2bf(av.z); ah.w=f2bf(av.w);
      bh.x=f2bf(bv.x); bh.y=f2bf(bv.y); bh.z=f2bf(bv.z); bh.w=f2bf(bv.w);
      *(ushort4*)&Ahi[r*40+c] = ah; *(ushort4*)&Bhi[r*40+c] = bh;
      if(!fl){
        ushort4 al, bl;
        al.x=f2bf(av.x-bf2f(ah.x)); al.y=f2bf(av.y-bf2f(ah.y));
        al.z=f2bf(av.z-bf2f(ah.z)); al.w=f2bf(av.w-bf2f(ah.w));
        bl.x=f2bf(bv.x-bf2f(bh.x)); bl.y=f2bf(bv.y-bf2f(bh.y));
        bl.z=f2bf(bv.z-bf2f(bh.z)); bl.w=f2bf(bv.w-bf2f(bh.w));
        *(ushort4*)&Alo[r*40+c] = al; *(ushort4*)&Blo[r*40+c] = bl;
      }
    }
    __syncthreads();
    const int m16 = lane&15, q = lane>>4;
    v8bf ahf[4], bhf[4];
    #pragma unroll
    for(int x=0;x<4;x++){
      ahf[x] = *(const v8bf*)&Ahi[(wm + x*16 + m16)*40 + q*8];
      bhf[x] = *(const v8bf*)&Bhi[(wn + x*16 + m16)*40 + q*8];
    }
    if(!fl){
      v8bf alf[4], blf[4];
      #pragma unroll
      for(int x=0;x<4;x++){
        alf[x] = *(const v8bf*)&Alo[(wm + x*16 + m16)*40 + q*8];
        blf[x] = *(const v8bf*)&Blo[(wn + x*16 + m16)*40 + q*8];
      }
      #pragma unroll
      for(int mi=0;mi<4;mi++)
        #pragma unroll
        for(int ni=0;ni<4;ni++){
          acc[mi][ni] = __builtin_amdgcn_mfma_f32_16x16x32_bf16(alf[mi], bhf[ni], acc[mi][ni], 0,0,0);
          acc[mi][ni] = __builtin_amdgcn_mfma_f32_16x16x32_bf16(ahf[mi], blf[ni], acc[mi][ni], 0,0,0);
        }
    }
    #pragma unroll
    for(int mi=0;mi<4;mi++)
      #pragma unroll
      for(int ni=0;ni<4;ni++)
        acc[mi][ni] = __builtin_amdgcn_mfma_f32_16x16x32_bf16(ahf[mi], bhf[ni], acc[mi][ni], 0,0,0);
    __syncthreads();
  }
  const int col16 = lane&15, rowq = lane>>4;
  #pragma unroll
  for(int mi=0;mi<4;mi++){
    #pragma unroll
    for(int ni=0;ni<4;ni++){
      int cj = bn + wn + ni*16 + col16;
      float sqj = sq[cj];
      #pragma unroll
      for(int r=0;r<4;r++){
        int ri = bm + wm + mi*16 + rowq*4 + r;
        float d2 = (sq[ri] + sqj) - 2.0f*acc[mi][ni][r];
        dist[(size_t)ri*NPTS + cj] = sqrtf(fmaxf(d2, 0.f));
      }
    }
  }
}

// ---------- screen: top-16 per row, fp32 dist, u64 keys (R7/R8-proven) ----------
__global__ __launch_bounds__(256) void topk_scr_k(const float* __restrict__ dist,
                                                  int* __restrict__ cand){
  const int i = blockIdx.x, tid = threadIdx.x;
  __shared__ u64 lst[256*16];
  __shared__ u64 red[256];
  u64 best[16];
  const float* drow = dist + (size_t)i*NPTS;
  #pragma unroll
  for(int t=0;t<16;t++){
    int j = tid + t*256;
    float d = drow[j];
    u64 key = ((u64)__float_as_uint(d)<<32) | (unsigned)j;
    best[t] = key;
    #pragma unroll
    for(int s=15; s>0; --s){
      if(s<=t && best[s] < best[s-1]){ u64 tmp=best[s]; best[s]=best[s-1]; best[s-1]=tmp; }
    }
  }
  #pragma unroll
  for(int t=0;t<16;t++) lst[tid*16+t] = best[t];
  __syncthreads();
  int pos = 0;
  for(int r=0;r<SCR;r++){
    u64 h = (pos<16) ? lst[tid*16+pos] : ~0ULL;
    red[tid] = h;
    __syncthreads();
    for(int s=128; s>0; s>>=1){
      if(tid<s){ u64 o = red[tid+s]; if(o<red[tid]) red[tid]=o; }
      __syncthreads();
    }
    u64 win = red[0];
    __syncthreads();
    if(h==win) pos++;
    if(tid==0) cand[i*SCR+r] = (int)(win & 0xffffffffu);
  }
}

// ---------- refine: fp64 exact distances for 16 candidates -> top-10 ----------
__global__ __launch_bounds__(64) void refine_k(const float* __restrict__ condF,
    const int* __restrict__ cand, int* __restrict__ nidx){
  const int i = blockIdx.x, t = threadIdx.x;
  __shared__ float  af[DF];
  __shared__ double ds[SCR];
  __shared__ int    idxs[SCR];
  af[t]    = condF[(size_t)i*DF + t];
  af[t+64] = condF[(size_t)i*DF + t + 64];
  __syncthreads();
  if(t < SCR){
    int j = cand[i*SCR + t] & (NPTS-1);
    const float* bp = condF + (size_t)j*DF;
    double s = 0.0;
    for(int e=0; e<DF; ++e){
      double d = (double)af[e] - (double)bp[e];
      s += d*d;
    }
    ds[t]   = sqrt(s);
    idxs[t] = j;
  }
  __syncthreads();
  if(t==0){
    unsigned used = 0;
    for(int r=0;r<KNN;r++){
      int bm=0, bi=0x7fffffff; double bd=1e300;
      for(int c=0;c<SCR;c++){
        if(used & (1u<<c)) continue;
        if(ds[c]<bd || (ds[c]==bd && idxs[c]<bi)){ bd=ds[c]; bi=idxs[c]; bm=c; }
      }
      used |= (1u<<bm);
      nidx[i*KNN+r] = bi;
    }
  }
}

// ---------- X = concat(cond[j], tens[j]) rows, bf16 ----------
__global__ void buildx_k(const float* __restrict__ condF, const float* __restrict__ tensF,
                         const int* __restrict__ nidx, u16* __restrict__ X){
  int c = blockIdx.x*256 + threadIdx.x;
  int m = c/48;
  int off = (c - m*48)*4;
  int j = nidx[m] & (NPTS-1);
  float4 v = (off < DF) ? *(const float4*)&condF[(size_t)j*DF + off]
                        : *(const float4*)&tensF[(size_t)j*DR + (off-DF)];
  ushort4 o; o.x=f2bf(v.x); o.y=f2bf(v.y); o.z=f2bf(v.z); o.w=f2bf(v.w);
  *(ushort4*)&X[(size_t)m*DIN + off] = o;
}

// ---------- GEMM (R8-proven: XCD swizzle + global_load_lds) ----------
template<int ACT>
__global__ __launch_bounds__(256,2) void gemm_bt_k(const u16* __restrict__ A,
    const u16* __restrict__ Bt, const float* __restrict__ bias, u16* __restrict__ C,
    int M, int Nc, int Kc){
  __shared__ u16 As[128*32];
  __shared__ u16 Bs[128*32];
  const int bid = blockIdx.x;
  const int bm = ((bid&7) + ((bid>>6)<<3)) * 128;
  const int bn = ((bid>>3)&7) * 128;
  const int tid = threadIdx.x, lane = tid&63, wave = tid>>6;
  const int wm = (wave&1)*64, wn = (wave>>1)*64;
  int c0 = wave*128 + lane, c1 = c0 + 64;
  int r0 = c0>>2, q0 = c0&3, r1 = c1>>2, q1 = c1&3;
  const u16* pA0 = A  + (size_t)(bm+r0)*Kc + q0*8;
  const u16* pA1 = A  + (size_t)(bm+r1)*Kc + q1*8;
  const u16* pB0 = Bt + (size_t)(bn+r0)*Kc + q0*8;
  const u16* pB1 = Bt + (size_t)(bn+r1)*Kc + q1*8;
  u16* lA0 = &As[(wave*128      )*8];
  u16* lA1 = &As[(wave*128 + 64 )*8];
  u16* lB0 = &Bs[(wave*128      )*8];
  u16* lB1 = &Bs[(wave*128 + 64 )*8];
  const int m16 = lane&15, q = lane>>4;
  v4f acc[4][4] = {};
  for(int kb=0; kb<Kc; kb+=32){
    gl2lds16(pA0 + kb, lA0);
    gl2lds16(pA1 + kb, lA1);
    gl2lds16(pB0 + kb, lB0);
    gl2lds16(pB1 + kb, lB1);
    __syncthreads();
    v8bf a[4], b[4];
    #pragma unroll
    for(int x=0;x<4;x++){
      a[x] = *(const v8bf*)&As[(wm + x*16 + m16)*32 + q*8];
      b[x] = *(const v8bf*)&Bs[(wn + x*16 + m16)*32 + q*8];
    }
    #pragma unroll
    for(int mi=0;mi<4;mi++)
      #pragma unroll
      for(int ni=0;ni<4;ni++)
        acc[mi][ni] = __builtin_amdgcn_mfma_f32_16x16x32_bf16(a[mi], b[ni], acc[mi][ni], 0,0,0);
    __syncthreads();
  }
  const int col16 = lane&15, rowq = lane>>4;
  #pragma unroll
  for(int mi=0;mi<4;mi++){
    #pragma unroll
    for(int ni=0;ni<4;ni++){
      int cn = bn + wn + ni*16 + col16;
      float bi = bias[cn];
      #pragma unroll
      for(int r=0;r<4;r++){
        int rw = bm + wm + mi*16 + rowq*4 + r;
        float v = acc[mi][ni][r] + bi;
        if(ACT) v = softplus_f(v);
        C[(size_t)rw*Nc + cn] = f2bf(v);
      }
    }
  }
}

// ---------- final layer, global_load_lds staging (R8-proven) ----------
__global__ __launch_bounds__(256,2) void gemm_out_k(const u16* __restrict__ A,
    const u16* __restrict__ Bt, const float* __restrict__ bias,
    const float* __restrict__ tensF, const int* __restrict__ nidx,
    void* __restrict__ outv, const int* __restrict__ flag){
  __shared__ u16 As[128*32];
  __shared__ u16 Bs[64*32];
  const int fl = *flag;
  const int bm = blockIdx.x*128;
  const int tid = threadIdx.x, lane = tid&63, wave = tid>>6;
  const int wm = wave*32;
  int c0 = wave*128 + lane, c1 = c0 + 64;
  int ra0 = c0>>2, qa0 = c0&3, ra1 = c1>>2, qa1 = c1&3;
  int cb = wave*64 + lane;
  int rb = cb>>2, qb = cb&3;
  const u16* pA0 = A  + (size_t)(bm+ra0)*HID + qa0*8;
  const u16* pA1 = A  + (size_t)(bm+ra1)*HID + qa1*8;
  const u16* pB  = Bt + (size_t)rb*HID + qb*8;
  u16* lA0 = &As[(wave*128     )*8];
  u16* lA1 = &As[(wave*128 + 64)*8];
  u16* lB  = &Bs[(wave*64      )*8];
  const int m16 = lane&15, q = lane>>4;
  v4f acc[2][4] = {};
  for(int kb=0; kb<HID; kb+=32){
    gl2lds16(pA0 + kb, lA0);
    gl2lds16(pA1 + kb, lA1);
    gl2lds16(pB  + kb, lB);
    __syncthreads();
    v8bf a[2], b[4];
    a[0] = *(const v8bf*)&As[(wm + m16)*32 + q*8];
    a[1] = *(const v8bf*)&As[(wm + 16 + m16)*32 + q*8];
    #pragma unroll
    for(int x=0;x<4;x++) b[x] = *(const v8bf*)&Bs[(x*16 + m16)*32 + q*8];
    #pragma unroll
    for(int mi=0;mi<2;mi++)
      #pragma unroll
      for(int ni=0;ni<4;ni++)
        acc[mi][ni] = __builtin_amdgcn_mfma_f32_16x16x32_bf16(a[mi], b[ni], acc[mi][ni], 0,0,0);
    __syncthreads();
  }
  const int col16 = lane&15, rowq = lane>>4;
  #pragma unroll
  for(int mi=0;mi<2;mi++){
    #pragma unroll
    for(int ni=0;ni<4;ni++){
      int cn = ni*16 + col16;
      float bi = bias[cn];
      #pragma unroll
      for(int r=0;r<4;r++){
        int rw = bm + wm + mi*16 + rowq*4 + r;
        int j = nidx[rw] & (NPTS-1);
        float y = tensF[(size_t)j*DR + cn] - (acc[mi][ni][r] + bi);
        if(fl) ((u16*)outv)[(size_t)rw*DR + cn] = f2bf(y);
        else   ((float*)outv)[(size_t)rw*DR + cn] = y;
      }
    }
  }
}

// ---------- workspace layout (~178.5 MB) ----------
constexpr size_t OFF_FLAG  = 0;
constexpr size_t OFF_SQ    = 256;
constexpr size_t OFF_NIDX  = OFF_SQ    + 16384;
constexpr size_t OFF_BIAS  = OFF_NIDX  + 163840;
constexpr size_t OFF_CONDF = OFF_BIAS  + 16640;
constexpr size_t OFF_TENSF = OFF_CONDF + 2097152;
constexpr size_t OFF_WTIN  = OFF_TENSF + 1048576;
constexpr size_t OFF_WT1   = OFF_WTIN  + 393216;
constexpr size_t OFF_WT2   = OFF_WT1   + 2097152;
constexpr size_t OFF_WT3   = OFF_WT2   + 2097152;
constexpr size_t OFF_WTO   = OFF_WT3   + 2097152;
constexpr size_t OFF_RA    = OFF_WTO   + 131072;     // dist (67MB) then A0 (84MB)
constexpr size_t OFF_RB    = OFF_RA    + 83886080;   // X (15.7MB) then A1 (84MB)
constexpr size_t OFF_CAND  = OFF_RB    + 83886080;   // 256 KB

extern "C" void kernel_launch(void* const* d_in, const int* in_sizes, int n_in,
                              void* d_out, int out_size, void* d_ws, size_t ws_size,
                              hipStream_t stream){
  char* ws = (char*)d_ws;
  int*   flag  = (int*)  (ws + OFF_FLAG);
  float* sqv   = (float*)(ws + OFF_SQ);
  int*   nidx  = (int*)  (ws + OFF_NIDX);
  float* biasF = (float*)(ws + OFF_BIAS);
  float* condF = (float*)(ws + OFF_CONDF);
  float* tensF = (float*)(ws + OFF_TENSF);
  u16*   Wt_in = (u16*)  (ws + OFF_WTIN);
  u16*   Wt1   = (u16*)  (ws + OFF_WT1);
  u16*   Wt2   = (u16*)  (ws + OFF_WT2);
  u16*   Wt3   = (u16*)  (ws + OFF_WT3);
  u16*   Wt_o  = (u16*)  (ws + OFF_WTO);
  float* dist  = (float*)(ws + OFF_RA);   // dead after topk -> region reused as A0
  u16*   A0    = (u16*)  (ws + OFF_RA);
  u16*   X     = (u16*)  (ws + OFF_RB);   // dead after gemm1 -> region reused as A1
  u16*   A1    = (u16*)  (ws + OFF_RB);
  int*   cand  = (int*)  (ws + OFF_CAND);

  detect_k <<<1, 256, 0, stream>>>((const u16*)d_in[0], flag);
  cvt_all_k<<<3089, 256, 0, stream>>>(d_in[0], d_in[1], d_in[3], d_in[5], d_in[7],
                                      d_in[9], d_in[11], condF, tensF, biasF, flag);
  transpose_all_k<<<3328, dim3(32,8), 0, stream>>>(d_in[2], d_in[4], d_in[6], d_in[8],
                                      d_in[10], Wt_in, Wt1, Wt2, Wt3, Wt_o, flag);
  sqnorm_k   <<<1024, 256, 0, stream>>>(condF, sqv);
  gram_dist_k<<<dim3(32,32), 256, 0, stream>>>(condF, sqv, dist, flag);
  topk_scr_k <<<NPTS, 256, 0, stream>>>(dist, cand);
  refine_k   <<<NPTS, 64, 0, stream>>>(condF, cand, nidx);
  buildx_k   <<<7680, 256, 0, stream>>>(condF, tensF, nidx, X);
  gemm_bt_k<1><<<2560, 256, 0, stream>>>(X,  Wt_in, biasF,      A0, MROWS, HID, DIN);
  gemm_bt_k<1><<<2560, 256, 0, stream>>>(A0, Wt1,   biasF+1024, A1, MROWS, HID, HID);
  gemm_bt_k<1><<<2560, 256, 0, stream>>>(A1, Wt2,   biasF+2048, A0, MROWS, HID, HID);
  gemm_bt_k<1><<<2560, 256, 0, stream>>>(A0, Wt3,   biasF+3072, A1, MROWS, HID, HID);
  gemm_out_k  <<<320, 256, 0, stream>>>(A1, Wt_o, biasF+4096, tensF, nidx, d_out, flag);
}

// Round 11
// 373.980 us; speedup vs baseline: 3.1176x; 1.7291x over previous
//
// MongeGapTransport: KNN gather + 5-layer MLP pushforward, bf16 I/O (confirmed).
// R11: ALGORITHMIC 10x — MLP input depends only on the neighbor index j, so
// the chain runs on the 4096 unique points (M=4096, 36 GFLOP) instead of the
// 40960 gathered rows (360 GFLOP); bitwise identical (deterministic GEMM +
// broadcast). Final gather out[i,k]=P[nidx[i,k]] is a 5 MB write.
// GEMM structure unchanged from R8/R10 (XCD swizzle adapted, global_load_lds).
#include <hip/hip_runtime.h>
#include <stdint.h>

typedef unsigned short u16;
typedef unsigned int   u32;
typedef unsigned long long u64;
typedef short v8bf __attribute__((ext_vector_type(8)));
typedef float v4f  __attribute__((ext_vector_type(4)));

#define NPTS 4096
#define DF   128
#define DR   64
#define HID  1024
#define KNN  10
#define SCR  16
#define MROWS (NPTS*KNN)   // 40960
#define DIN  192

#define AS1 __attribute__((address_space(1)))
#define AS3 __attribute__((address_space(3)))

__device__ __forceinline__ float bf2f(u16 b){ return __uint_as_float(((unsigned)b)<<16); }
__device__ __forceinline__ u16 f2bf(float f){
  unsigned u = __float_as_uint(f);
  unsigned r = 0x7fffu + ((u>>16)&1u);
  return (u16)((u + r)>>16);
}
__device__ __forceinline__ float softplus_f(float x){
  return x>15.f ? x : __logf(1.f + __expf(x));
}
__device__ __forceinline__ float rdv(const void* p, long j, int fl){
  return fl ? bf2f(((const u16*)p)[j]) : ((const float*)p)[j];
}
__device__ __forceinline__ void gl2lds16(const u16* g, u16* l){
  __builtin_amdgcn_global_load_lds((const AS1 unsigned int*)g, (AS3 unsigned int*)l, 16, 0, 0);
}

// ---------- dtype detection (R2-proven) ----------
__global__ void detect_k(const u16* __restrict__ c, int* __restrict__ flag){
  __shared__ int cnt[256];
  int t = threadIdx.x, n = 0;
  for(int i=t; i<8192; i+=256){
    u16 v = c[2*i];
    int e = (v>>7)&0xff;
    n += (e>=96 && e<=158);
  }
  cnt[t] = n; __syncthreads();
  for(int s=128; s>0; s>>=1){ if(t<s) cnt[t]+=cnt[t+s]; __syncthreads(); }
  if(t==0) *flag = (cnt[0] > 4915) ? 1 : 0;
}

// ---------- canonicalize to fp32 (R2-proven) ----------
__global__ void cvt_all_k(const void* c, const void* t, const void* bi, const void* b1,
                          const void* b2, const void* b3, const void* bo,
                          float* __restrict__ condF, float* __restrict__ tensF,
                          float* __restrict__ biasF, const int* __restrict__ flag){
  const int fl = *flag;
  int i = blockIdx.x*256 + threadIdx.x;
  if(i < 524288){ condF[i] = rdv(c, i, fl); }
  else if(i < 786432){ tensF[i-524288] = rdv(t, i-524288, fl); }
  else{
    int j = i - 786432;
    if(j < 1024)      biasF[j] = rdv(bi, j, fl);
    else if(j < 2048) biasF[j] = rdv(b1, j-1024, fl);
    else if(j < 3072) biasF[j] = rdv(b2, j-2048, fl);
    else if(j < 4096) biasF[j] = rdv(b3, j-3072, fl);
    else if(j < 4160) biasF[j] = rdv(bo, j-4096, fl);
  }
}

// ---------- all 5 weight transposes in ONE launch (R9-proven) ----------
__global__ void transpose_all_k(const void* Wi, const void* W1, const void* W2,
    const void* W3, const void* Wo, u16* Oi, u16* O1, u16* O2, u16* O3, u16* Oo,
    const int* __restrict__ flag){
  __shared__ u16 tile[32][33];
  const int fl = *flag;
  int bid = blockIdx.x;
  const void* in; u16* out; int R, C, bx, by;
  if(bid < 192)      { int b=bid;      in=Wi; out=Oi; R=192;  C=1024; bx=b&31; by=b>>5; }
  else if(bid < 1216){ int b=bid-192;  in=W1; out=O1; R=1024; C=1024; bx=b&31; by=b>>5; }
  else if(bid < 2240){ int b=bid-1216; in=W2; out=O2; R=1024; C=1024; bx=b&31; by=b>>5; }
  else if(bid < 3264){ int b=bid-2240; in=W3; out=O3; R=1024; C=1024; bx=b&31; by=b>>5; }
  else               { int b=bid-3264; in=Wo; out=Oo; R=1024; C=64;   bx=b&1;  by=b>>1; }
  int gx = bx*32, gy = by*32;
  int tx = threadIdx.x, ty = threadIdx.y;
  #pragma unroll
  for(int r=ty; r<32; r+=8){
    size_t idx = (size_t)(gy+r)*C + gx + tx;
    tile[r][tx] = fl ? ((const u16*)in)[idx] : f2bf(((const float*)in)[idx]);
  }
  __syncthreads();
  #pragma unroll
  for(int r=ty; r<32; r+=8) out[(size_t)(gx+r)*R + gy + tx] = tile[tx][r];
}

// ---------- squared norms (R2-proven) ----------
__global__ void sqnorm_k(const float* __restrict__ condF, float* __restrict__ sq){
  int row  = blockIdx.x*4 + (threadIdx.x>>6);
  int lane = threadIdx.x&63;
  const float* r = condF + (size_t)row*DF;
  float a = r[lane], b = r[lane+64];
  double s = (double)a*a + (double)b*b;
  #pragma unroll
  for(int off=32; off>0; off>>=1) s += __shfl_down(s, off, 64);
  if(lane==0) sq[row] = (float)s;
}

// ---------- gram -> fp32 dist; hi/lo split only when inputs were fp32 ----------
__global__ __launch_bounds__(256) void gram_dist_k(const float* __restrict__ condF,
    const float* __restrict__ sq, float* __restrict__ dist, const int* __restrict__ flag){
  __shared__ u16 Ahi[128*40], Alo[128*40], Bhi[128*40], Blo[128*40];
  const int fl = *flag;
  const int bm = blockIdx.x*128, bn = blockIdx.y*128;
  const int tid = threadIdx.x, lane = tid&63, wave = tid>>6;
  const int wm = (wave&1)*64, wn = (wave>>1)*64;
  v4f acc[4][4] = {};
  for(int kb=0; kb<DF; kb+=32){
    #pragma unroll
    for(int t=0;t<4;t++){
      int ch = tid + t*256;
      int r = ch>>3, c = (ch&7)*4;
      float4 av = *(const float4*)&condF[(size_t)(bm+r)*DF + kb + c];
      float4 bv = *(const float4*)&condF[(size_t)(bn+r)*DF + kb + c];
      ushort4 ah, bh;
      ah.x=f2bf(av.x); ah.y=f2bf(av.y); ah.z=f2bf(av.z); ah.w=f2bf(av.w);
      bh.x=f2bf(bv.x); bh.y=f2bf(bv.y); bh.z=f2bf(bv.z); bh.w=f2bf(bv.w);
      *(ushort4*)&Ahi[r*40+c] = ah; *(ushort4*)&Bhi[r*40+c] = bh;
      if(!fl){
        ushort4 al, bl;
        al.x=f2bf(av.x-bf2f(ah.x)); al.y=f2bf(av.y-bf2f(ah.y));
        al.z=f2bf(av.z-bf2f(ah.z)); al.w=f2bf(av.w-bf2f(ah.w));
        bl.x=f2bf(bv.x-bf2f(bh.x)); bl.y=f2bf(bv.y-bf2f(bh.y));
        bl.z=f2bf(bv.z-bf2f(bh.z)); bl.w=f2bf(bv.w-bf2f(bh.w));
        *(ushort4*)&Alo[r*40+c] = al; *(ushort4*)&Blo[r*40+c] = bl;
      }
    }
    __syncthreads();
    const int m16 = lane&15, q = lane>>4;
    v8bf ahf[4], bhf[4];
    #pragma unroll
    for(int x=0;x<4;x++){
      ahf[x] = *(const v8bf*)&Ahi[(wm + x*16 + m16)*40 + q*8];
      bhf[x] = *(const v8bf*)&Bhi[(wn + x*16 + m16)*40 + q*8];
    }
    if(!fl){
      v8bf alf[4], blf[4];
      #pragma unroll
      for(int x=0;x<4;x++){
        alf[x] = *(const v8bf*)&Alo[(wm + x*16 + m16)*40 + q*8];
        blf[x] = *(const v8bf*)&Blo[(wn + x*16 + m16)*40 + q*8];
      }
      #pragma unroll
      for(int mi=0;mi<4;mi++)
        #pragma unroll
        for(int ni=0;ni<4;ni++){
          acc[mi][ni] = __builtin_amdgcn_mfma_f32_16x16x32_bf16(alf[mi], bhf[ni], acc[mi][ni], 0,0,0);
          acc[mi][ni] = __builtin_amdgcn_mfma_f32_16x16x32_bf16(ahf[mi], blf[ni], acc[mi][ni], 0,0,0);
        }
    }
    #pragma unroll
    for(int mi=0;mi<4;mi++)
      #pragma unroll
      for(int ni=0;ni<4;ni++)
        acc[mi][ni] = __builtin_amdgcn_mfma_f32_16x16x32_bf16(ahf[mi], bhf[ni], acc[mi][ni], 0,0,0);
    __syncthreads();
  }
  const int col16 = lane&15, rowq = lane>>4;
  #pragma unroll
  for(int mi=0;mi<4;mi++){
    #pragma unroll
    for(int ni=0;ni<4;ni++){
      int cj = bn + wn + ni*16 + col16;
      float sqj = sq[cj];
      #pragma unroll
      for(int r=0;r<4;r++){
        int ri = bm + wm + mi*16 + rowq*4 + r;
        float d2 = (sq[ri] + sqj) - 2.0f*acc[mi][ni][r];
        dist[(size_t)ri*NPTS + cj] = sqrtf(fmaxf(d2, 0.f));
      }
    }
  }
}

// ---------- screen: top-16 per row, fp32 dist, u64 keys (R7/R8-proven) ----------
__global__ __launch_bounds__(256) void topk_scr_k(const float* __restrict__ dist,
                                                  int* __restrict__ cand){
  const int i = blockIdx.x, tid = threadIdx.x;
  __shared__ u64 lst[256*16];
  __shared__ u64 red[256];
  u64 best[16];
  const float* drow = dist + (size_t)i*NPTS;
  #pragma unroll
  for(int t=0;t<16;t++){
    int j = tid + t*256;
    float d = drow[j];
    u64 key = ((u64)__float_as_uint(d)<<32) | (unsigned)j;
    best[t] = key;
    #pragma unroll
    for(int s=15; s>0; --s){
      if(s<=t && best[s] < best[s-1]){ u64 tmp=best[s]; best[s]=best[s-1]; best[s-1]=tmp; }
    }
  }
  #pragma unroll
  for(int t=0;t<16;t++) lst[tid*16+t] = best[t];
  __syncthreads();
  int pos = 0;
  for(int r=0;r<SCR;r++){
    u64 h = (pos<16) ? lst[tid*16+pos] : ~0ULL;
    red[tid] = h;
    __syncthreads();
    for(int s=128; s>0; s>>=1){
      if(tid<s){ u64 o = red[tid+s]; if(o<red[tid]) red[tid]=o; }
      __syncthreads();
    }
    u64 win = red[0];
    __syncthreads();
    if(h==win) pos++;
    if(tid==0) cand[i*SCR+r] = (int)(win & 0xffffffffu);
  }
}

// ---------- refine: fp64 exact distances for 16 candidates -> top-10 ----------
__global__ __launch_bounds__(64) void refine_k(const float* __restrict__ condF,
    const int* __restrict__ cand, int* __restrict__ nidx){
  const int i = blockIdx.x, t = threadIdx.x;
  __shared__ float  af[DF];
  __shared__ double ds[SCR];
  __shared__ int    idxs[SCR];
  af[t]    = condF[(size_t)i*DF + t];
  af[t+64] = condF[(size_t)i*DF + t + 64];
  __syncthreads();
  if(t < SCR){
    int j = cand[i*SCR + t] & (NPTS-1);
    const float* bp = condF + (size_t)j*DF;
    double s = 0.0;
    for(int e=0; e<DF; ++e){
      double d = (double)af[e] - (double)bp[e];
      s += d*d;
    }
    ds[t]   = sqrt(s);
    idxs[t] = j;
  }
  __syncthreads();
  if(t==0){
    unsigned used = 0;
    for(int r=0;r<KNN;r++){
      int bm=0, bi=0x7fffffff; double bd=1e300;
      for(int c=0;c<SCR;c++){
        if(used & (1u<<c)) continue;
        if(ds[c]<bd || (ds[c]==bd && idxs[c]<bi)){ bd=ds[c]; bi=idxs[c]; bm=c; }
      }
      used |= (1u<<bm);
      nidx[i*KNN+r] = bi;
    }
  }
}

// ---------- X = [cond | tens] per UNIQUE point (no gather), bf16 ----------
__global__ void buildx_unique_k(const float* __restrict__ condF,
    const float* __restrict__ tensF, u16* __restrict__ X){
  int c = blockIdx.x*256 + threadIdx.x;   // 4096*48 = 196608 chunks of 4
  int j = c/48;
  int off = (c - j*48)*4;
  float4 v = (off < DF) ? *(const float4*)&condF[(size_t)j*DF + off]
                        : *(const float4*)&tensF[(size_t)j*DR + (off-DF)];
  ushort4 o; o.x=f2bf(v.x); o.y=f2bf(v.y); o.z=f2bf(v.z); o.w=f2bf(v.w);
  *(ushort4*)&X[(size_t)j*DIN + off] = o;
}

// ---------- GEMM, M=4096 (32 bm-tiles): 4 bm/XCD x 8 bn, L2-resident ----------
template<int ACT>
__global__ __launch_bounds__(256,2) void gemm_bt_k(const u16* __restrict__ A,
    const u16* __restrict__ Bt, const float* __restrict__ bias, u16* __restrict__ C,
    int Nc, int Kc){
  __shared__ u16 As[128*32];
  __shared__ u16 Bs[128*32];
  const int bid = blockIdx.x;               // 256 blocks
  const int xcd = bid&7, slot = bid>>3;     // slot 0..31
  const int bm = (xcd*4 + (slot>>3)) * 128;
  const int bn = (slot&7) * 128;
  const int tid = threadIdx.x, lane = tid&63, wave = tid>>6;
  const int wm = (wave&1)*64, wn = (wave>>1)*64;
  int c0 = wave*128 + lane, c1 = c0 + 64;
  int r0 = c0>>2, q0 = c0&3, r1 = c1>>2, q1 = c1&3;
  const u16* pA0 = A  + (size_t)(bm+r0)*Kc + q0*8;
  const u16* pA1 = A  + (size_t)(bm+r1)*Kc + q1*8;
  const u16* pB0 = Bt + (size_t)(bn+r0)*Kc + q0*8;
  const u16* pB1 = Bt + (size_t)(bn+r1)*Kc + q1*8;
  u16* lA0 = &As[(wave*128      )*8];
  u16* lA1 = &As[(wave*128 + 64 )*8];
  u16* lB0 = &Bs[(wave*128      )*8];
  u16* lB1 = &Bs[(wave*128 + 64 )*8];
  const int m16 = lane&15, q = lane>>4;
  v4f acc[4][4] = {};
  for(int kb=0; kb<Kc; kb+=32){
    gl2lds16(pA0 + kb, lA0);
    gl2lds16(pA1 + kb, lA1);
    gl2lds16(pB0 + kb, lB0);
    gl2lds16(pB1 + kb, lB1);
    __syncthreads();
    v8bf a[4], b[4];
    #pragma unroll
    for(int x=0;x<4;x++){
      a[x] = *(const v8bf*)&As[(wm + x*16 + m16)*32 + q*8];
      b[x] = *(const v8bf*)&Bs[(wn + x*16 + m16)*32 + q*8];
    }
    #pragma unroll
    for(int mi=0;mi<4;mi++)
      #pragma unroll
      for(int ni=0;ni<4;ni++)
        acc[mi][ni] = __builtin_amdgcn_mfma_f32_16x16x32_bf16(a[mi], b[ni], acc[mi][ni], 0,0,0);
    __syncthreads();
  }
  const int col16 = lane&15, rowq = lane>>4;
  #pragma unroll
  for(int mi=0;mi<4;mi++){
    #pragma unroll
    for(int ni=0;ni<4;ni++){
      int cn = bn + wn + ni*16 + col16;
      float bi = bias[cn];
      #pragma unroll
      for(int r=0;r<4;r++){
        int rw = bm + wm + mi*16 + rowq*4 + r;
        float v = acc[mi][ni][r] + bi;
        if(ACT) v = softplus_f(v);
        C[(size_t)rw*Nc + cn] = f2bf(v);
      }
    }
  }
}

// ---------- final layer, M=4096: P[j] = tens[j] - (A@Wout^T + b), fp32 ----------
__global__ __launch_bounds__(256,2) void gemm_out_k(const u16* __restrict__ A,
    const u16* __restrict__ Bt, const float* __restrict__ bias,
    const float* __restrict__ tensF, float* __restrict__ P){
  __shared__ u16 As[128*32];
  __shared__ u16 Bs[64*32];
  const int bm = blockIdx.x*128;            // 32 blocks
  const int tid = threadIdx.x, lane = tid&63, wave = tid>>6;
  const int wm = wave*32;
  int c0 = wave*128 + lane, c1 = c0 + 64;
  int ra0 = c0>>2, qa0 = c0&3, ra1 = c1>>2, qa1 = c1&3;
  int cb = wave*64 + lane;
  int rb = cb>>2, qb = cb&3;
  const u16* pA0 = A  + (size_t)(bm+ra0)*HID + qa0*8;
  const u16* pA1 = A  + (size_t)(bm+ra1)*HID + qa1*8;
  const u16* pB  = Bt + (size_t)rb*HID + qb*8;
  u16* lA0 = &As[(wave*128     )*8];
  u16* lA1 = &As[(wave*128 + 64)*8];
  u16* lB  = &Bs[(wave*64      )*8];
  const int m16 = lane&15, q = lane>>4;
  v4f acc[2][4] = {};
  for(int kb=0; kb<HID; kb+=32){
    gl2lds16(pA0 + kb, lA0);
    gl2lds16(pA1 + kb, lA1);
    gl2lds16(pB  + kb, lB);
    __syncthreads();
    v8bf a[2], b[4];
    a[0] = *(const v8bf*)&As[(wm + m16)*32 + q*8];
    a[1] = *(const v8bf*)&As[(wm + 16 + m16)*32 + q*8];
    #pragma unroll
    for(int x=0;x<4;x++) b[x] = *(const v8bf*)&Bs[(x*16 + m16)*32 + q*8];
    #pragma unroll
    for(int mi=0;mi<2;mi++)
      #pragma unroll
      for(int ni=0;ni<4;ni++)
        acc[mi][ni] = __builtin_amdgcn_mfma_f32_16x16x32_bf16(a[mi], b[ni], acc[mi][ni], 0,0,0);
    __syncthreads();
  }
  const int col16 = lane&15, rowq = lane>>4;
  #pragma unroll
  for(int mi=0;mi<2;mi++){
    #pragma unroll
    for(int ni=0;ni<4;ni++){
      int cn = ni*16 + col16;
      float bi = bias[cn];
      #pragma unroll
      for(int r=0;r<4;r++){
        int rw = bm + wm + mi*16 + rowq*4 + r;
        P[(size_t)rw*DR + cn] = tensF[(size_t)rw*DR + cn] - (acc[mi][ni][r] + bi);
      }
    }
  }
}

// ---------- gather: out[i,k,:] = P[nidx[i,k],:], dual dtype ----------
__global__ void gather_k(const float* __restrict__ P, const int* __restrict__ nidx,
                         void* __restrict__ outv, const int* __restrict__ flag){
  const int fl = *flag;
  int e = blockIdx.x*256 + threadIdx.x;     // 40960*16 = 655360 vec4 groups
  int m = e>>4;
  int c = (e&15)*4;
  int j = nidx[m] & (NPTS-1);
  float4 v = *(const float4*)&P[(size_t)j*DR + c];
  if(fl){
    ushort4 o; o.x=f2bf(v.x); o.y=f2bf(v.y); o.z=f2bf(v.z); o.w=f2bf(v.w);
    *(ushort4*)&((u16*)outv)[(size_t)m*DR + c] = o;
  }else{
    *(float4*)&((float*)outv)[(size_t)m*DR + c] = v;
  }
}

// ---------- workspace layout (~170 MB) ----------
constexpr size_t OFF_FLAG  = 0;
constexpr size_t OFF_SQ    = 256;
constexpr size_t OFF_NIDX  = OFF_SQ    + 16384;
constexpr size_t OFF_BIAS  = OFF_NIDX  + 163840;
constexpr size_t OFF_CONDF = OFF_BIAS  + 16640;
constexpr size_t OFF_TENSF = OFF_CONDF + 2097152;
constexpr size_t OFF_WTIN  = OFF_TENSF + 1048576;
constexpr size_t OFF_WT1   = OFF_WTIN  + 393216;
constexpr size_t OFF_WT2   = OFF_WT1   + 2097152;
constexpr size_t OFF_WT3   = OFF_WT2   + 2097152;
constexpr size_t OFF_WTO   = OFF_WT3   + 2097152;
constexpr size_t OFF_RA    = OFF_WTO   + 131072;     // dist (67MB) then A0 (8MB)
constexpr size_t OFF_RB    = OFF_RA    + 83886080;   // X (1.5MB) then A1 (8MB)
constexpr size_t OFF_CAND  = OFF_RB    + 83886080;   // 256 KB
constexpr size_t OFF_P     = OFF_CAND  + 262144;     // 1 MB

extern "C" void kernel_launch(void* const* d_in, const int* in_sizes, int n_in,
                              void* d_out, int out_size, void* d_ws, size_t ws_size,
                              hipStream_t stream){
  char* ws = (char*)d_ws;
  int*   flag  = (int*)  (ws + OFF_FLAG);
  float* sqv   = (float*)(ws + OFF_SQ);
  int*   nidx  = (int*)  (ws + OFF_NIDX);
  float* biasF = (float*)(ws + OFF_BIAS);
  float* condF = (float*)(ws + OFF_CONDF);
  float* tensF = (float*)(ws + OFF_TENSF);
  u16*   Wt_in = (u16*)  (ws + OFF_WTIN);
  u16*   Wt1   = (u16*)  (ws + OFF_WT1);
  u16*   Wt2   = (u16*)  (ws + OFF_WT2);
  u16*   Wt3   = (u16*)  (ws + OFF_WT3);
  u16*   Wt_o  = (u16*)  (ws + OFF_WTO);
  float* dist  = (float*)(ws + OFF_RA);   // dead after topk -> region reused as A0
  u16*   A0    = (u16*)  (ws + OFF_RA);
  u16*   X     = (u16*)  (ws + OFF_RB);   // dead after gemm1 -> region reused as A1
  u16*   A1    = (u16*)  (ws + OFF_RB);
  int*   cand  = (int*)  (ws + OFF_CAND);
  float* P     = (float*)(ws + OFF_P);

  detect_k <<<1, 256, 0, stream>>>((const u16*)d_in[0], flag);
  cvt_all_k<<<3089, 256, 0, stream>>>(d_in[0], d_in[1], d_in[3], d_in[5], d_in[7],
                                      d_in[9], d_in[11], condF, tensF, biasF, flag);
  transpose_all_k<<<3328, dim3(32,8), 0, stream>>>(d_in[2], d_in[4], d_in[6], d_in[8],
                                      d_in[10], Wt_in, Wt1, Wt2, Wt3, Wt_o, flag);
  sqnorm_k   <<<1024, 256, 0, stream>>>(condF, sqv);
  gram_dist_k<<<dim3(32,32), 256, 0, stream>>>(condF, sqv, dist, flag);
  topk_scr_k <<<NPTS, 256, 0, stream>>>(dist, cand);
  refine_k   <<<NPTS, 64, 0, stream>>>(condF, cand, nidx);
  buildx_unique_k<<<768, 256, 0, stream>>>(condF, tensF, X);
  gemm_bt_k<1><<<256, 256, 0, stream>>>(X,  Wt_in, biasF,      A0, HID, DIN);
  gemm_bt_k<1><<<256, 256, 0, stream>>>(A0, Wt1,   biasF+1024, A1, HID, HID);
  gemm_bt_k<1><<<256, 256, 0, stream>>>(A1, Wt2,   biasF+2048, A0, HID, HID);
  gemm_bt_k<1><<<256, 256, 0, stream>>>(A0, Wt3,   biasF+3072, A1, HID, HID);
  gemm_out_k  <<<32, 256, 0, stream>>>(A1, Wt_o, biasF+4096, tensF, P);
  gather_k    <<<2560, 256, 0, stream>>>(P, nidx, d_out, flag);
}

// Round 12
// 279.739 us; speedup vs baseline: 4.1679x; 1.3369x over previous
//
// MongeGapTransport: KNN gather + 5-layer MLP pushforward, bf16 I/O (confirmed).
// R12: R11 (374us) + two fixes from counters:
//  - knn_k: histogram-select top-candidates + inline fp64 refine + counting
//    rank (replaces topk_scr_k 109us: bank-0 u64 layout 32-way conflicts,
//    16 rounds x 8-barrier trees) -> single pass near HBM floor.
//  - gemm_bt_k: 512 blocks (128x64 tiles) = 2 blocks/CU (m97 structure needs
//    inter-block overlap; 256 blocks was 1/CU).
#include <hip/hip_runtime.h>
#include <stdint.h>

typedef unsigned short u16;
typedef unsigned int   u32;
typedef unsigned long long u64;
typedef short v8bf __attribute__((ext_vector_type(8)));
typedef float v4f  __attribute__((ext_vector_type(4)));

#define NPTS 4096
#define DF   128
#define DR   64
#define HID  1024
#define KNN  10
#define CAP  256
#define MROWS (NPTS*KNN)   // 40960
#define DIN  192

#define AS1 __attribute__((address_space(1)))
#define AS3 __attribute__((address_space(3)))

__device__ __forceinline__ float bf2f(u16 b){ return __uint_as_float(((unsigned)b)<<16); }
__device__ __forceinline__ u16 f2bf(float f){
  unsigned u = __float_as_uint(f);
  unsigned r = 0x7fffu + ((u>>16)&1u);
  return (u16)((u + r)>>16);
}
__device__ __forceinline__ float softplus_f(float x){
  return x>15.f ? x : __logf(1.f + __expf(x));
}
__device__ __forceinline__ float rdv(const void* p, long j, int fl){
  return fl ? bf2f(((const u16*)p)[j]) : ((const float*)p)[j];
}
__device__ __forceinline__ void gl2lds16(const u16* g, u16* l){
  __builtin_amdgcn_global_load_lds((const AS1 unsigned int*)g, (AS3 unsigned int*)l, 16, 0, 0);
}

// ---------- dtype detection (R2-proven) ----------
__global__ void detect_k(const u16* __restrict__ c, int* __restrict__ flag){
  __shared__ int cnt[256];
  int t = threadIdx.x, n = 0;
  for(int i=t; i<8192; i+=256){
    u16 v = c[2*i];
    int e = (v>>7)&0xff;
    n += (e>=96 && e<=158);
  }
  cnt[t] = n; __syncthreads();
  for(int s=128; s>0; s>>=1){ if(t<s) cnt[t]+=cnt[t+s]; __syncthreads(); }
  if(t==0) *flag = (cnt[0] > 4915) ? 1 : 0;
}

// ---------- canonicalize to fp32 (R2-proven) ----------
__global__ void cvt_all_k(const void* c, const void* t, const void* bi, const void* b1,
                          const void* b2, const void* b3, const void* bo,
                          float* __restrict__ condF, float* __restrict__ tensF,
                          float* __restrict__ biasF, const int* __restrict__ flag){
  const int fl = *flag;
  int i = blockIdx.x*256 + threadIdx.x;
  if(i < 524288){ condF[i] = rdv(c, i, fl); }
  else if(i < 786432){ tensF[i-524288] = rdv(t, i-524288, fl); }
  else{
    int j = i - 786432;
    if(j < 1024)      biasF[j] = rdv(bi, j, fl);
    else if(j < 2048) biasF[j] = rdv(b1, j-1024, fl);
    else if(j < 3072) biasF[j] = rdv(b2, j-2048, fl);
    else if(j < 4096) biasF[j] = rdv(b3, j-3072, fl);
    else if(j < 4160) biasF[j] = rdv(bo, j-4096, fl);
  }
}

// ---------- all 5 weight transposes in ONE launch (R9-proven) ----------
__global__ void transpose_all_k(const void* Wi, const void* W1, const void* W2,
    const void* W3, const void* Wo, u16* Oi, u16* O1, u16* O2, u16* O3, u16* Oo,
    const int* __restrict__ flag){
  __shared__ u16 tile[32][33];
  const int fl = *flag;
  int bid = blockIdx.x;
  const void* in; u16* out; int R, C, bx, by;
  if(bid < 192)      { int b=bid;      in=Wi; out=Oi; R=192;  C=1024; bx=b&31; by=b>>5; }
  else if(bid < 1216){ int b=bid-192;  in=W1; out=O1; R=1024; C=1024; bx=b&31; by=b>>5; }
  else if(bid < 2240){ int b=bid-1216; in=W2; out=O2; R=1024; C=1024; bx=b&31; by=b>>5; }
  else if(bid < 3264){ int b=bid-2240; in=W3; out=O3; R=1024; C=1024; bx=b&31; by=b>>5; }
  else               { int b=bid-3264; in=Wo; out=Oo; R=1024; C=64;   bx=b&1;  by=b>>1; }
  int gx = bx*32, gy = by*32;
  int tx = threadIdx.x, ty = threadIdx.y;
  #pragma unroll
  for(int r=ty; r<32; r+=8){
    size_t idx = (size_t)(gy+r)*C + gx + tx;
    tile[r][tx] = fl ? ((const u16*)in)[idx] : f2bf(((const float*)in)[idx]);
  }
  __syncthreads();
  #pragma unroll
  for(int r=ty; r<32; r+=8) out[(size_t)(gx+r)*R + gy + tx] = tile[tx][r];
}

// ---------- squared norms (R2-proven) ----------
__global__ void sqnorm_k(const float* __restrict__ condF, float* __restrict__ sq){
  int row  = blockIdx.x*4 + (threadIdx.x>>6);
  int lane = threadIdx.x&63;
  const float* r = condF + (size_t)row*DF;
  float a = r[lane], b = r[lane+64];
  double s = (double)a*a + (double)b*b;
  #pragma unroll
  for(int off=32; off>0; off>>=1) s += __shfl_down(s, off, 64);
  if(lane==0) sq[row] = (float)s;
}

// ---------- gram -> fp32 dist; hi/lo split only when inputs were fp32 ----------
__global__ __launch_bounds__(256) void gram_dist_k(const float* __restrict__ condF,
    const float* __restrict__ sq, float* __restrict__ dist, const int* __restrict__ flag){
  __shared__ u16 Ahi[128*40], Alo[128*40], Bhi[128*40], Blo[128*40];
  const int fl = *flag;
  const int bm = blockIdx.x*128, bn = blockIdx.y*128;
  const int tid = threadIdx.x, lane = tid&63, wave = tid>>6;
  const int wm = (wave&1)*64, wn = (wave>>1)*64;
  v4f acc[4][4] = {};
  for(int kb=0; kb<DF; kb+=32){
    #pragma unroll
    for(int t=0;t<4;t++){
      int ch = tid + t*256;
      int r = ch>>3, c = (ch&7)*4;
      float4 av = *(const float4*)&condF[(size_t)(bm+r)*DF + kb + c];
      float4 bv = *(const float4*)&condF[(size_t)(bn+r)*DF + kb + c];
      ushort4 ah, bh;
      ah.x=f2bf(av.x); ah.y=f2bf(av.y); ah.z=f2bf(av.z); ah.w=f2bf(av.w);
      bh.x=f2bf(bv.x); bh.y=f2bf(bv.y); bh.z=f2bf(bv.z); bh.w=f2bf(bv.w);
      *(ushort4*)&Ahi[r*40+c] = ah; *(ushort4*)&Bhi[r*40+c] = bh;
      if(!fl){
        ushort4 al, bl;
        al.x=f2bf(av.x-bf2f(ah.x)); al.y=f2bf(av.y-bf2f(ah.y));
        al.z=f2bf(av.z-bf2f(ah.z)); al.w=f2bf(av.w-bf2f(ah.w));
        bl.x=f2bf(bv.x-bf2f(bh.x)); bl.y=f2bf(bv.y-bf2f(bh.y));
        bl.z=f2bf(bv.z-bf2f(bh.z)); bl.w=f2bf(bv.w-bf2f(bh.w));
        *(ushort4*)&Alo[r*40+c] = al; *(ushort4*)&Blo[r*40+c] = bl;
      }
    }
    __syncthreads();
    const int m16 = lane&15, q = lane>>4;
    v8bf ahf[4], bhf[4];
    #pragma unroll
    for(int x=0;x<4;x++){
      ahf[x] = *(const v8bf*)&Ahi[(wm + x*16 + m16)*40 + q*8];
      bhf[x] = *(const v8bf*)&Bhi[(wn + x*16 + m16)*40 + q*8];
    }
    if(!fl){
      v8bf alf[4], blf[4];
      #pragma unroll
      for(int x=0;x<4;x++){
        alf[x] = *(const v8bf*)&Alo[(wm + x*16 + m16)*40 + q*8];
        blf[x] = *(const v8bf*)&Blo[(wn + x*16 + m16)*40 + q*8];
      }
      #pragma unroll
      for(int mi=0;mi<4;mi++)
        #pragma unroll
        for(int ni=0;ni<4;ni++){
          acc[mi][ni] = __builtin_amdgcn_mfma_f32_16x16x32_bf16(alf[mi], bhf[ni], acc[mi][ni], 0,0,0);
          acc[mi][ni] = __builtin_amdgcn_mfma_f32_16x16x32_bf16(ahf[mi], blf[ni], acc[mi][ni], 0,0,0);
        }
    }
    #pragma unroll
    for(int mi=0;mi<4;mi++)
      #pragma unroll
      for(int ni=0;ni<4;ni++)
        acc[mi][ni] = __builtin_amdgcn_mfma_f32_16x16x32_bf16(ahf[mi], bhf[ni], acc[mi][ni], 0,0,0);
    __syncthreads();
  }
  const int col16 = lane&15, rowq = lane>>4;
  #pragma unroll
  for(int mi=0;mi<4;mi++){
    #pragma unroll
    for(int ni=0;ni<4;ni++){
      int cj = bn + wn + ni*16 + col16;
      float sqj = sq[cj];
      #pragma unroll
      for(int r=0;r<4;r++){
        int ri = bm + wm + mi*16 + rowq*4 + r;
        float d2 = (sq[ri] + sqj) - 2.0f*acc[mi][ni][r];
        dist[(size_t)ri*NPTS + cj] = sqrtf(fmaxf(d2, 0.f));
      }
    }
  }
}

// ---------- knn: histogram select + inline fp64 refine + counting rank ----------
// bin = clamp((float_bits>>19)-2064, 0, 63): 0.5-wide buckets over d in [4,16),
// 1.0-wide over [16,32); monotone in d. T = first bin with cumsum>=16.
// Candidates = ALL points in bins<=T (>=16, typ ~50). fp64 dist is EXACT for
// bf16 inputs (products/sums representable), rank by (dbits&~0xFFF)|j.
__global__ __launch_bounds__(256) void knn_k(const float* __restrict__ dist,
    const float* __restrict__ condF, int* __restrict__ nidx){
  const int i = blockIdx.x, tid = threadIdx.x;
  __shared__ u32 hist[64];
  __shared__ int scnt, sT;
  __shared__ int candj[CAP];
  __shared__ u64 keys[CAP];
  __shared__ float af[DF];
  if(tid < DF) af[tid] = condF[(size_t)i*DF + tid];
  if(tid < 64) hist[tid] = 0;
  if(tid == 0) scnt = 0;
  __syncthreads();
  const float4* drow4 = (const float4*)(dist + (size_t)i*NPTS);
  #pragma unroll
  for(int k=0;k<4;k++){
    float4 x = drow4[tid + k*256];
    float v[4] = {x.x, x.y, x.z, x.w};
    #pragma unroll
    for(int e=0;e<4;e++){
      int b = (int)(__float_as_uint(v[e])>>19) - 2064;
      b = b < 0 ? 0 : (b > 63 ? 63 : b);
      atomicAdd(&hist[b], 1u);
    }
  }
  __syncthreads();
  if(tid == 0){
    int c = 0, T = 63;
    for(int b=0;b<64;b++){ c += (int)hist[b]; if(c >= 16){ T = b; break; } }
    sT = T;
  }
  __syncthreads();
  const int T = sT;
  #pragma unroll
  for(int k=0;k<4;k++){
    float4 x = drow4[tid + k*256];
    float v[4] = {x.x, x.y, x.z, x.w};
    #pragma unroll
    for(int e=0;e<4;e++){
      int b = (int)(__float_as_uint(v[e])>>19) - 2064;
      b = b < 0 ? 0 : (b > 63 ? 63 : b);
      if(b <= T){
        int s = atomicAdd(&scnt, 1);
        if(s < CAP) candj[s] = (tid + k*256)*4 + e;
      }
    }
  }
  __syncthreads();
  const int cnt = scnt < CAP ? scnt : CAP;
  u64 mykey = ~0ULL; int myj = -1;
  if(tid < cnt){
    int j = candj[tid];
    const float* bp = condF + (size_t)j*DF;
    double s = 0.0;
    for(int e=0;e<DF;e++){
      double d = (double)af[e] - (double)bp[e];
      s += d*d;
    }
    u64 bits = (u64)__double_as_longlong(sqrt(s));
    mykey = (bits & ~0xFFFULL) | (u32)j;
    myj = j;
  }
  if(tid < CAP) keys[tid] = mykey;
  __syncthreads();
  if(tid < cnt){
    int rank = 0;
    for(int c=0;c<cnt;c++) rank += (keys[c] < mykey);
    if(rank < KNN) nidx[i*KNN + rank] = myj;
  }
}

// ---------- X = [cond | tens] per UNIQUE point (no gather), bf16 ----------
__global__ void buildx_unique_k(const float* __restrict__ condF,
    const float* __restrict__ tensF, u16* __restrict__ X){
  int c = blockIdx.x*256 + threadIdx.x;
  int j = c/48;
  int off = (c - j*48)*4;
  float4 v = (off < DF) ? *(const float4*)&condF[(size_t)j*DF + off]
                        : *(const float4*)&tensF[(size_t)j*DR + (off-DF)];
  ushort4 o; o.x=f2bf(v.x); o.y=f2bf(v.y); o.z=f2bf(v.z); o.w=f2bf(v.w);
  *(ushort4*)&X[(size_t)j*DIN + off] = o;
}

// ---------- GEMM, M=4096: 512 blocks, 128x64 tiles, 2 blocks/CU ----------
template<int ACT>
__global__ __launch_bounds__(256,2) void gemm_bt_k(const u16* __restrict__ A,
    const u16* __restrict__ Bt, const float* __restrict__ bias, u16* __restrict__ C,
    int Nc, int Kc){
  __shared__ u16 As[128*32];
  __shared__ u16 Bs[64*32];
  const int bid = blockIdx.x;               // 512 blocks
  const int xcd = bid&7, slot = bid>>3;     // slot 0..63
  const int bm = (xcd*4 + (slot>>4)) * 128; // 32 bm-tiles, 4 per XCD
  const int bn = (slot&15) * 64;            // 16 bn-tiles
  const int tid = threadIdx.x, lane = tid&63, wave = tid>>6;
  const int wm = (wave&1)*64, wn = (wave>>1)*32;
  int c0 = wave*128 + lane, c1 = c0 + 64;
  int r0 = c0>>2, q0 = c0&3, r1 = c1>>2, q1 = c1&3;
  int cb = wave*64 + lane, rb = cb>>2, qb = cb&3;
  const u16* pA0 = A  + (size_t)(bm+r0)*Kc + q0*8;
  const u16* pA1 = A  + (size_t)(bm+r1)*Kc + q1*8;
  const u16* pB  = Bt + (size_t)(bn+rb)*Kc + qb*8;
  u16* lA0 = &As[(wave*128      )*8];
  u16* lA1 = &As[(wave*128 + 64 )*8];
  u16* lB  = &Bs[(wave*64       )*8];
  const int m16 = lane&15, q = lane>>4;
  v4f acc[4][2] = {};
  for(int kb=0; kb<Kc; kb+=32){
    gl2lds16(pA0 + kb, lA0);
    gl2lds16(pA1 + kb, lA1);
    gl2lds16(pB  + kb, lB);
    __syncthreads();
    v8bf a[4], b[2];
    #pragma unroll
    for(int x=0;x<4;x++) a[x] = *(const v8bf*)&As[(wm + x*16 + m16)*32 + q*8];
    #pragma unroll
    for(int x=0;x<2;x++) b[x] = *(const v8bf*)&Bs[(wn + x*16 + m16)*32 + q*8];
    #pragma unroll
    for(int mi=0;mi<4;mi++)
      #pragma unroll
      for(int ni=0;ni<2;ni++)
        acc[mi][ni] = __builtin_amdgcn_mfma_f32_16x16x32_bf16(a[mi], b[ni], acc[mi][ni], 0,0,0);
    __syncthreads();
  }
  const int col16 = lane&15, rowq = lane>>4;
  #pragma unroll
  for(int mi=0;mi<4;mi++){
    #pragma unroll
    for(int ni=0;ni<2;ni++){
      int cn = bn + wn + ni*16 + col16;
      float bi = bias[cn];
      #pragma unroll
      for(int r=0;r<4;r++){
        int rw = bm + wm + mi*16 + rowq*4 + r;
        float v = acc[mi][ni][r] + bi;
        if(ACT) v = softplus_f(v);
        C[(size_t)rw*Nc + cn] = f2bf(v);
      }
    }
  }
}

// ---------- final layer, M=4096: P[j] = tens[j] - (A@Wout^T + b), fp32 ----------
__global__ __launch_bounds__(256,2) void gemm_out_k(const u16* __restrict__ A,
    const u16* __restrict__ Bt, const float* __restrict__ bias,
    const float* __restrict__ tensF, float* __restrict__ P){
  __shared__ u16 As[128*32];
  __shared__ u16 Bs[64*32];
  const int bm = blockIdx.x*128;            // 32 blocks
  const int tid = threadIdx.x, lane = tid&63, wave = tid>>6;
  const int wm = wave*32;
  int c0 = wave*128 + lane, c1 = c0 + 64;
  int ra0 = c0>>2, qa0 = c0&3, ra1 = c1>>2, qa1 = c1&3;
  int cb = wave*64 + lane;
  int rb = cb>>2, qb = cb&3;
  const u16* pA0 = A  + (size_t)(bm+ra0)*HID + qa0*8;
  const u16* pA1 = A  + (size_t)(bm+ra1)*HID + qa1*8;
  const u16* pB  = Bt + (size_t)rb*HID + qb*8;
  u16* lA0 = &As[(wave*128     )*8];
  u16* lA1 = &As[(wave*128 + 64)*8];
  u16* lB  = &Bs[(wave*64      )*8];
  const int m16 = lane&15, q = lane>>4;
  v4f acc[2][4] = {};
  for(int kb=0; kb<HID; kb+=32){
    gl2lds16(pA0 + kb, lA0);
    gl2lds16(pA1 + kb, lA1);
    gl2lds16(pB  + kb, lB);
    __syncthreads();
    v8bf a[2], b[4];
    a[0] = *(const v8bf*)&As[(wm + m16)*32 + q*8];
    a[1] = *(const v8bf*)&As[(wm + 16 + m16)*32 + q*8];
    #pragma unroll
    for(int x=0;x<4;x++) b[x] = *(const v8bf*)&Bs[(x*16 + m16)*32 + q*8];
    #pragma unroll
    for(int mi=0;mi<2;mi++)
      #pragma unroll
      for(int ni=0;ni<4;ni++)
        acc[mi][ni] = __builtin_amdgcn_mfma_f32_16x16x32_bf16(a[mi], b[ni], acc[mi][ni], 0,0,0);
    __syncthreads();
  }
  const int col16 = lane&15, rowq = lane>>4;
  #pragma unroll
  for(int mi=0;mi<2;mi++){
    #pragma unroll
    for(int ni=0;ni<4;ni++){
      int cn = ni*16 + col16;
      float bi = bias[cn];
      #pragma unroll
      for(int r=0;r<4;r++){
        int rw = bm + wm + mi*16 + rowq*4 + r;
        P[(size_t)rw*DR + cn] = tensF[(size_t)rw*DR + cn] - (acc[mi][ni][r] + bi);
      }
    }
  }
}

// ---------- gather: out[i,k,:] = P[nidx[i,k],:], dual dtype ----------
__global__ void gather_k(const float* __restrict__ P, const int* __restrict__ nidx,
                         void* __restrict__ outv, const int* __restrict__ flag){
  const int fl = *flag;
  int e = blockIdx.x*256 + threadIdx.x;
  int m = e>>4;
  int c = (e&15)*4;
  int j = nidx[m] & (NPTS-1);
  float4 v = *(const float4*)&P[(size_t)j*DR + c];
  if(fl){
    ushort4 o; o.x=f2bf(v.x); o.y=f2bf(v.y); o.z=f2bf(v.z); o.w=f2bf(v.w);
    *(ushort4*)&((u16*)outv)[(size_t)m*DR + c] = o;
  }else{
    *(float4*)&((float*)outv)[(size_t)m*DR + c] = v;
  }
}

// ---------- workspace layout (~170 MB) ----------
constexpr size_t OFF_FLAG  = 0;
constexpr size_t OFF_SQ    = 256;
constexpr size_t OFF_NIDX  = OFF_SQ    + 16384;
constexpr size_t OFF_BIAS  = OFF_NIDX  + 163840;
constexpr size_t OFF_CONDF = OFF_BIAS  + 16640;
constexpr size_t OFF_TENSF = OFF_CONDF + 2097152;
constexpr size_t OFF_WTIN  = OFF_TENSF + 1048576;
constexpr size_t OFF_WT1   = OFF_WTIN  + 393216;
constexpr size_t OFF_WT2   = OFF_WT1   + 2097152;
constexpr size_t OFF_WT3   = OFF_WT2   + 2097152;
constexpr size_t OFF_WTO   = OFF_WT3   + 2097152;
constexpr size_t OFF_RA    = OFF_WTO   + 131072;     // dist (67MB) then A0 (8MB)
constexpr size_t OFF_RB    = OFF_RA    + 83886080;   // X (1.5MB) then A1 (8MB)
constexpr size_t OFF_P     = OFF_RB    + 83886080;   // 1 MB

extern "C" void kernel_launch(void* const* d_in, const int* in_sizes, int n_in,
                              void* d_out, int out_size, void* d_ws, size_t ws_size,
                              hipStream_t stream){
  char* ws = (char*)d_ws;
  int*   flag  = (int*)  (ws + OFF_FLAG);
  float* sqv   = (float*)(ws + OFF_SQ);
  int*   nidx  = (int*)  (ws + OFF_NIDX);
  float* biasF = (float*)(ws + OFF_BIAS);
  float* condF = (float*)(ws + OFF_CONDF);
  float* tensF = (float*)(ws + OFF_TENSF);
  u16*   Wt_in = (u16*)  (ws + OFF_WTIN);
  u16*   Wt1   = (u16*)  (ws + OFF_WT1);
  u16*   Wt2   = (u16*)  (ws + OFF_WT2);
  u16*   Wt3   = (u16*)  (ws + OFF_WT3);
  u16*   Wt_o  = (u16*)  (ws + OFF_WTO);
  float* dist  = (float*)(ws + OFF_RA);   // dead after knn -> region reused as A0
  u16*   A0    = (u16*)  (ws + OFF_RA);
  u16*   X     = (u16*)  (ws + OFF_RB);   // dead after gemm1 -> region reused as A1
  u16*   A1    = (u16*)  (ws + OFF_RB);
  float* P     = (float*)(ws + OFF_P);

  detect_k <<<1, 256, 0, stream>>>((const u16*)d_in[0], flag);
  cvt_all_k<<<3089, 256, 0, stream>>>(d_in[0], d_in[1], d_in[3], d_in[5], d_in[7],
                                      d_in[9], d_in[11], condF, tensF, biasF, flag);
  transpose_all_k<<<3328, dim3(32,8), 0, stream>>>(d_in[2], d_in[4], d_in[6], d_in[8],
                                      d_in[10], Wt_in, Wt1, Wt2, Wt3, Wt_o, flag);
  sqnorm_k   <<<1024, 256, 0, stream>>>(condF, sqv);
  gram_dist_k<<<dim3(32,32), 256, 0, stream>>>(condF, sqv, dist, flag);
  knn_k      <<<NPTS, 256, 0, stream>>>(dist, condF, nidx);
  buildx_unique_k<<<768, 256, 0, stream>>>(condF, tensF, X);
  gemm_bt_k<1><<<512, 256, 0, stream>>>(X,  Wt_in, biasF,      A0, HID, DIN);
  gemm_bt_k<1><<<512, 256, 0, stream>>>(A0, Wt1,   biasF+1024, A1, HID, HID);
  gemm_bt_k<1><<<512, 256, 0, stream>>>(A1, Wt2,   biasF+2048, A0, HID, HID);
  gemm_bt_k<1><<<512, 256, 0, stream>>>(A0, Wt3,   biasF+3072, A1, HID, HID);
  gemm_out_k  <<<32, 256, 0, stream>>>(A1, Wt_o, biasF+4096, tensF, P);
  gather_k    <<<2560, 256, 0, stream>>>(P, nidx, d_out, flag);
}

// Round 13
// 279.535 us; speedup vs baseline: 4.1710x; 1.0007x over previous
//
// MongeGapTransport: KNN gather + 5-layer MLP pushforward, bf16 I/O (confirmed).
// R13: R12 (280us) + knn refine de-latencied (counters: HBM 12%, VALU 20% =>
// latency-bound; 1 wave doing 128 dependent scalar L2 loads). Now 4 lanes per
// candidate x float4 loads, fp64 partials via LDS. dist holds d^2 (sqrt
// dropped; fmaxf kept so self stays bin 0); refine ranks EXACT fp64 d^2.
#include <hip/hip_runtime.h>
#include <stdint.h>

typedef unsigned short u16;
typedef unsigned int   u32;
typedef unsigned long long u64;
typedef short v8bf __attribute__((ext_vector_type(8)));
typedef float v4f  __attribute__((ext_vector_type(4)));

#define NPTS 4096
#define DF   128
#define DR   64
#define HID  1024
#define KNN  10
#define CAP  256
#define MROWS (NPTS*KNN)   // 40960
#define DIN  192

#define AS1 __attribute__((address_space(1)))
#define AS3 __attribute__((address_space(3)))

__device__ __forceinline__ float bf2f(u16 b){ return __uint_as_float(((unsigned)b)<<16); }
__device__ __forceinline__ u16 f2bf(float f){
  unsigned u = __float_as_uint(f);
  unsigned r = 0x7fffu + ((u>>16)&1u);
  return (u16)((u + r)>>16);
}
__device__ __forceinline__ float softplus_f(float x){
  return x>15.f ? x : __logf(1.f + __expf(x));
}
__device__ __forceinline__ float rdv(const void* p, long j, int fl){
  return fl ? bf2f(((const u16*)p)[j]) : ((const float*)p)[j];
}
__device__ __forceinline__ void gl2lds16(const u16* g, u16* l){
  __builtin_amdgcn_global_load_lds((const AS1 unsigned int*)g, (AS3 unsigned int*)l, 16, 0, 0);
}
// d^2 -> bin: exponent + top-3 mantissa bits; monotone; [8,2048) -> 0..63
__device__ __forceinline__ int d2bin(float d2){
  int b = (int)(__float_as_uint(d2)>>20) - 1040;
  return b < 0 ? 0 : (b > 63 ? 63 : b);
}

// ---------- dtype detection (R2-proven) ----------
__global__ void detect_k(const u16* __restrict__ c, int* __restrict__ flag){
  __shared__ int cnt[256];
  int t = threadIdx.x, n = 0;
  for(int i=t; i<8192; i+=256){
    u16 v = c[2*i];
    int e = (v>>7)&0xff;
    n += (e>=96 && e<=158);
  }
  cnt[t] = n; __syncthreads();
  for(int s=128; s>0; s>>=1){ if(t<s) cnt[t]+=cnt[t+s]; __syncthreads(); }
  if(t==0) *flag = (cnt[0] > 4915) ? 1 : 0;
}

// ---------- canonicalize to fp32 (R2-proven) ----------
__global__ void cvt_all_k(const void* c, const void* t, const void* bi, const void* b1,
                          const void* b2, const void* b3, const void* bo,
                          float* __restrict__ condF, float* __restrict__ tensF,
                          float* __restrict__ biasF, const int* __restrict__ flag){
  const int fl = *flag;
  int i = blockIdx.x*256 + threadIdx.x;
  if(i < 524288){ condF[i] = rdv(c, i, fl); }
  else if(i < 786432){ tensF[i-524288] = rdv(t, i-524288, fl); }
  else{
    int j = i - 786432;
    if(j < 1024)      biasF[j] = rdv(bi, j, fl);
    else if(j < 2048) biasF[j] = rdv(b1, j-1024, fl);
    else if(j < 3072) biasF[j] = rdv(b2, j-2048, fl);
    else if(j < 4096) biasF[j] = rdv(b3, j-3072, fl);
    else if(j < 4160) biasF[j] = rdv(bo, j-4096, fl);
  }
}

// ---------- all 5 weight transposes in ONE launch (R9-proven) ----------
__global__ void transpose_all_k(const void* Wi, const void* W1, const void* W2,
    const void* W3, const void* Wo, u16* Oi, u16* O1, u16* O2, u16* O3, u16* Oo,
    const int* __restrict__ flag){
  __shared__ u16 tile[32][33];
  const int fl = *flag;
  int bid = blockIdx.x;
  const void* in; u16* out; int R, C, bx, by;
  if(bid < 192)      { int b=bid;      in=Wi; out=Oi; R=192;  C=1024; bx=b&31; by=b>>5; }
  else if(bid < 1216){ int b=bid-192;  in=W1; out=O1; R=1024; C=1024; bx=b&31; by=b>>5; }
  else if(bid < 2240){ int b=bid-1216; in=W2; out=O2; R=1024; C=1024; bx=b&31; by=b>>5; }
  else if(bid < 3264){ int b=bid-2240; in=W3; out=O3; R=1024; C=1024; bx=b&31; by=b>>5; }
  else               { int b=bid-3264; in=Wo; out=Oo; R=1024; C=64;   bx=b&1;  by=b>>1; }
  int gx = bx*32, gy = by*32;
  int tx = threadIdx.x, ty = threadIdx.y;
  #pragma unroll
  for(int r=ty; r<32; r+=8){
    size_t idx = (size_t)(gy+r)*C + gx + tx;
    tile[r][tx] = fl ? ((const u16*)in)[idx] : f2bf(((const float*)in)[idx]);
  }
  __syncthreads();
  #pragma unroll
  for(int r=ty; r<32; r+=8) out[(size_t)(gx+r)*R + gy + tx] = tile[tx][r];
}

// ---------- squared norms (R2-proven) ----------
__global__ void sqnorm_k(const float* __restrict__ condF, float* __restrict__ sq){
  int row  = blockIdx.x*4 + (threadIdx.x>>6);
  int lane = threadIdx.x&63;
  const float* r = condF + (size_t)row*DF;
  float a = r[lane], b = r[lane+64];
  double s = (double)a*a + (double)b*b;
  #pragma unroll
  for(int off=32; off>0; off>>=1) s += __shfl_down(s, off, 64);
  if(lane==0) sq[row] = (float)s;
}

// ---------- gram -> fp32 d^2; hi/lo split only when inputs were fp32 ----------
__global__ __launch_bounds__(256) void gram_dist_k(const float* __restrict__ condF,
    const float* __restrict__ sq, float* __restrict__ dist, const int* __restrict__ flag){
  __shared__ u16 Ahi[128*40], Alo[128*40], Bhi[128*40], Blo[128*40];
  const int fl = *flag;
  const int bm = blockIdx.x*128, bn = blockIdx.y*128;
  const int tid = threadIdx.x, lane = tid&63, wave = tid>>6;
  const int wm = (wave&1)*64, wn = (wave>>1)*64;
  v4f acc[4][4] = {};
  for(int kb=0; kb<DF; kb+=32){
    #pragma unroll
    for(int t=0;t<4;t++){
      int ch = tid + t*256;
      int r = ch>>3, c = (ch&7)*4;
      float4 av = *(const float4*)&condF[(size_t)(bm+r)*DF + kb + c];
      float4 bv = *(const float4*)&condF[(size_t)(bn+r)*DF + kb + c];
      ushort4 ah, bh;
      ah.x=f2bf(av.x); ah.y=f2bf(av.y); ah.z=f2bf(av.z); ah.w=f2bf(av.w);
      bh.x=f2bf(bv.x); bh.y=f2bf(bv.y); bh.z=f2bf(bv.z); bh.w=f2bf(bv.w);
      *(ushort4*)&Ahi[r*40+c] = ah; *(ushort4*)&Bhi[r*40+c] = bh;
      if(!fl){
        ushort4 al, bl;
        al.x=f2bf(av.x-bf2f(ah.x)); al.y=f2bf(av.y-bf2f(ah.y));
        al.z=f2bf(av.z-bf2f(ah.z)); al.w=f2bf(av.w-bf2f(ah.w));
        bl.x=f2bf(bv.x-bf2f(bh.x)); bl.y=f2bf(bv.y-bf2f(bh.y));
        bl.z=f2bf(bv.z-bf2f(bh.z)); bl.w=f2bf(bv.w-bf2f(bh.w));
        *(ushort4*)&Alo[r*40+c] = al; *(ushort4*)&Blo[r*40+c] = bl;
      }
    }
    __syncthreads();
    const int m16 = lane&15, q = lane>>4;
    v8bf ahf[4], bhf[4];
    #pragma unroll
    for(int x=0;x<4;x++){
      ahf[x] = *(const v8bf*)&Ahi[(wm + x*16 + m16)*40 + q*8];
      bhf[x] = *(const v8bf*)&Bhi[(wn + x*16 + m16)*40 + q*8];
    }
    if(!fl){
      v8bf alf[4], blf[4];
      #pragma unroll
      for(int x=0;x<4;x++){
        alf[x] = *(const v8bf*)&Alo[(wm + x*16 + m16)*40 + q*8];
        blf[x] = *(const v8bf*)&Blo[(wn + x*16 + m16)*40 + q*8];
      }
      #pragma unroll
      for(int mi=0;mi<4;mi++)
        #pragma unroll
        for(int ni=0;ni<4;ni++){
          acc[mi][ni] = __builtin_amdgcn_mfma_f32_16x16x32_bf16(alf[mi], bhf[ni], acc[mi][ni], 0,0,0);
          acc[mi][ni] = __builtin_amdgcn_mfma_f32_16x16x32_bf16(ahf[mi], blf[ni], acc[mi][ni], 0,0,0);
        }
    }
    #pragma unroll
    for(int mi=0;mi<4;mi++)
      #pragma unroll
      for(int ni=0;ni<4;ni++)
        acc[mi][ni] = __builtin_amdgcn_mfma_f32_16x16x32_bf16(ahf[mi], bhf[ni], acc[mi][ni], 0,0,0);
    __syncthreads();
  }
  const int col16 = lane&15, rowq = lane>>4;
  #pragma unroll
  for(int mi=0;mi<4;mi++){
    #pragma unroll
    for(int ni=0;ni<4;ni++){
      int cj = bn + wn + ni*16 + col16;
      float sqj = sq[cj];
      #pragma unroll
      for(int r=0;r<4;r++){
        int ri = bm + wm + mi*16 + rowq*4 + r;
        float d2 = (sq[ri] + sqj) - 2.0f*acc[mi][ni][r];
        dist[(size_t)ri*NPTS + cj] = fmaxf(d2, 0.f);   // d^2 (no sqrt); >=0 keeps self in bin 0
      }
    }
  }
}

// ---------- knn: histogram select on d^2 + parallel fp64 refine + rank ----------
__global__ __launch_bounds__(256) void knn_k(const float* __restrict__ dist,
    const float* __restrict__ condF, int* __restrict__ nidx){
  const int i = blockIdx.x, tid = threadIdx.x;
  __shared__ u32 hist[64];
  __shared__ int scnt, sT;
  __shared__ int candj[CAP];
  __shared__ u64 keys[CAP];
  __shared__ float af[DF];
  __shared__ double psum[64][4];
  if(tid < DF) af[tid] = condF[(size_t)i*DF + tid];
  if(tid < 64) hist[tid] = 0;
  if(tid == 0) scnt = 0;
  __syncthreads();
  const float4* drow4 = (const float4*)(dist + (size_t)i*NPTS);
  #pragma unroll
  for(int k=0;k<4;k++){
    float4 x = drow4[tid + k*256];
    float v[4] = {x.x, x.y, x.z, x.w};
    #pragma unroll
    for(int e=0;e<4;e++) atomicAdd(&hist[d2bin(v[e])], 1u);
  }
  __syncthreads();
  if(tid == 0){
    int c = 0, T = 63;
    for(int b=0;b<64;b++){ c += (int)hist[b]; if(c >= 16){ T = b; break; } }
    sT = T;
  }
  __syncthreads();
  const int T = sT;
  #pragma unroll
  for(int k=0;k<4;k++){
    float4 x = drow4[tid + k*256];
    float v[4] = {x.x, x.y, x.z, x.w};
    #pragma unroll
    for(int e=0;e<4;e++){
      if(d2bin(v[e]) <= T){
        int s = atomicAdd(&scnt, 1);
        if(s < CAP) candj[s] = (tid + k*256)*4 + e;
      }
    }
  }
  __syncthreads();
  const int cnt = scnt < CAP ? scnt : CAP;
  // exact fp64 d^2 per candidate: 4 lanes/candidate, each sums 32 dims (8 float4)
  for(int base=0; base<cnt; base+=64){
    int c = base + (tid>>2);
    int p = tid&3;
    if(c < cnt){
      int j = candj[c];
      const float4* bp4 = (const float4*)(condF + (size_t)j*DF + p*32);
      const float*  ap  = af + p*32;
      double s = 0.0;
      #pragma unroll
      for(int v4i=0; v4i<8; v4i++){
        float4 bv = bp4[v4i];
        s += ((double)ap[v4i*4+0]-(double)bv.x)*((double)ap[v4i*4+0]-(double)bv.x);
        s += ((double)ap[v4i*4+1]-(double)bv.y)*((double)ap[v4i*4+1]-(double)bv.y);
        s += ((double)ap[v4i*4+2]-(double)bv.z)*((double)ap[v4i*4+2]-(double)bv.z);
        s += ((double)ap[v4i*4+3]-(double)bv.w)*((double)ap[v4i*4+3]-(double)bv.w);
      }
      psum[c-base][p] = s;
    }
    __syncthreads();
    if(tid < 64 && base + tid < cnt){
      int c2 = base + tid;
      double s = psum[tid][0] + psum[tid][1] + psum[tid][2] + psum[tid][3];
      u64 bits = (u64)__double_as_longlong(s);     // exact d^2, monotone for >=0
      keys[c2] = (bits & ~0xFFFULL) | (u32)candj[c2];
    }
    __syncthreads();
  }
  if(tid < cnt){
    u64 mykey = keys[tid];
    int rank = 0;
    for(int c=0;c<cnt;c++) rank += (keys[c] < mykey);
    if(rank < KNN) nidx[i*KNN + rank] = candj[tid];
  }
}

// ---------- X = [cond | tens] per UNIQUE point (no gather), bf16 ----------
__global__ void buildx_unique_k(const float* __restrict__ condF,
    const float* __restrict__ tensF, u16* __restrict__ X){
  int c = blockIdx.x*256 + threadIdx.x;
  int j = c/48;
  int off = (c - j*48)*4;
  float4 v = (off < DF) ? *(const float4*)&condF[(size_t)j*DF + off]
                        : *(const float4*)&tensF[(size_t)j*DR + (off-DF)];
  ushort4 o; o.x=f2bf(v.x); o.y=f2bf(v.y); o.z=f2bf(v.z); o.w=f2bf(v.w);
  *(ushort4*)&X[(size_t)j*DIN + off] = o;
}

// ---------- GEMM, M=4096: 512 blocks, 128x64 tiles, 2 blocks/CU (R12) ----------
template<int ACT>
__global__ __launch_bounds__(256,2) void gemm_bt_k(const u16* __restrict__ A,
    const u16* __restrict__ Bt, const float* __restrict__ bias, u16* __restrict__ C,
    int Nc, int Kc){
  __shared__ u16 As[128*32];
  __shared__ u16 Bs[64*32];
  const int bid = blockIdx.x;
  const int xcd = bid&7, slot = bid>>3;
  const int bm = (xcd*4 + (slot>>4)) * 128;
  const int bn = (slot&15) * 64;
  const int tid = threadIdx.x, lane = tid&63, wave = tid>>6;
  const int wm = (wave&1)*64, wn = (wave>>1)*32;
  int c0 = wave*128 + lane, c1 = c0 + 64;
  int r0 = c0>>2, q0 = c0&3, r1 = c1>>2, q1 = c1&3;
  int cb = wave*64 + lane, rb = cb>>2, qb = cb&3;
  const u16* pA0 = A  + (size_t)(bm+r0)*Kc + q0*8;
  const u16* pA1 = A  + (size_t)(bm+r1)*Kc + q1*8;
  const u16* pB  = Bt + (size_t)(bn+rb)*Kc + qb*8;
  u16* lA0 = &As[(wave*128      )*8];
  u16* lA1 = &As[(wave*128 + 64 )*8];
  u16* lB  = &Bs[(wave*64       )*8];
  const int m16 = lane&15, q = lane>>4;
  v4f acc[4][2] = {};
  for(int kb=0; kb<Kc; kb+=32){
    gl2lds16(pA0 + kb, lA0);
    gl2lds16(pA1 + kb, lA1);
    gl2lds16(pB  + kb, lB);
    __syncthreads();
    v8bf a[4], b[2];
    #pragma unroll
    for(int x=0;x<4;x++) a[x] = *(const v8bf*)&As[(wm + x*16 + m16)*32 + q*8];
    #pragma unroll
    for(int x=0;x<2;x++) b[x] = *(const v8bf*)&Bs[(wn + x*16 + m16)*32 + q*8];
    #pragma unroll
    for(int mi=0;mi<4;mi++)
      #pragma unroll
      for(int ni=0;ni<2;ni++)
        acc[mi][ni] = __builtin_amdgcn_mfma_f32_16x16x32_bf16(a[mi], b[ni], acc[mi][ni], 0,0,0);
    __syncthreads();
  }
  const int col16 = lane&15, rowq = lane>>4;
  #pragma unroll
  for(int mi=0;mi<4;mi++){
    #pragma unroll
    for(int ni=0;ni<2;ni++){
      int cn = bn + wn + ni*16 + col16;
      float bi = bias[cn];
      #pragma unroll
      for(int r=0;r<4;r++){
        int rw = bm + wm + mi*16 + rowq*4 + r;
        float v = acc[mi][ni][r] + bi;
        if(ACT) v = softplus_f(v);
        C[(size_t)rw*Nc + cn] = f2bf(v);
      }
    }
  }
}

// ---------- final layer, M=4096: P[j] = tens[j] - (A@Wout^T + b), fp32 ----------
__global__ __launch_bounds__(256,2) void gemm_out_k(const u16* __restrict__ A,
    const u16* __restrict__ Bt, const float* __restrict__ bias,
    const float* __restrict__ tensF, float* __restrict__ P){
  __shared__ u16 As[128*32];
  __shared__ u16 Bs[64*32];
  const int bm = blockIdx.x*128;
  const int tid = threadIdx.x, lane = tid&63, wave = tid>>6;
  const int wm = wave*32;
  int c0 = wave*128 + lane, c1 = c0 + 64;
  int ra0 = c0>>2, qa0 = c0&3, ra1 = c1>>2, qa1 = c1&3;
  int cb = wave*64 + lane;
  int rb = cb>>2, qb = cb&3;
  const u16* pA0 = A  + (size_t)(bm+ra0)*HID + qa0*8;
  const u16* pA1 = A  + (size_t)(bm+ra1)*HID + qa1*8;
  const u16* pB  = Bt + (size_t)rb*HID + qb*8;
  u16* lA0 = &As[(wave*128     )*8];
  u16* lA1 = &As[(wave*128 + 64)*8];
  u16* lB  = &Bs[(wave*64      )*8];
  const int m16 = lane&15, q = lane>>4;
  v4f acc[2][4] = {};
  for(int kb=0; kb<HID; kb+=32){
    gl2lds16(pA0 + kb, lA0);
    gl2lds16(pA1 + kb, lA1);
    gl2lds16(pB  + kb, lB);
    __syncthreads();
    v8bf a[2], b[4];
    a[0] = *(const v8bf*)&As[(wm + m16)*32 + q*8];
    a[1] = *(const v8bf*)&As[(wm + 16 + m16)*32 + q*8];
    #pragma unroll
    for(int x=0;x<4;x++) b[x] = *(const v8bf*)&Bs[(x*16 + m16)*32 + q*8];
    #pragma unroll
    for(int mi=0;mi<2;mi++)
      #pragma unroll
      for(int ni=0;ni<4;ni++)
        acc[mi][ni] = __builtin_amdgcn_mfma_f32_16x16x32_bf16(a[mi], b[ni], acc[mi][ni], 0,0,0);
    __syncthreads();
  }
  const int col16 = lane&15, rowq = lane>>4;
  #pragma unroll
  for(int mi=0;mi<2;mi++){
    #pragma unroll
    for(int ni=0;ni<4;ni++){
      int cn = ni*16 + col16;
      float bi = bias[cn];
      #pragma unroll
      for(int r=0;r<4;r++){
        int rw = bm + wm + mi*16 + rowq*4 + r;
        P[(size_t)rw*DR + cn] = tensF[(size_t)rw*DR + cn] - (acc[mi][ni][r] + bi);
      }
    }
  }
}

// ---------- gather: out[i,k,:] = P[nidx[i,k],:], dual dtype ----------
__global__ void gather_k(const float* __restrict__ P, const int* __restrict__ nidx,
                         void* __restrict__ outv, const int* __restrict__ flag){
  const int fl = *flag;
  int e = blockIdx.x*256 + threadIdx.x;
  int m = e>>4;
  int c = (e&15)*4;
  int j = nidx[m] & (NPTS-1);
  float4 v = *(const float4*)&P[(size_t)j*DR + c];
  if(fl){
    ushort4 o; o.x=f2bf(v.x); o.y=f2bf(v.y); o.z=f2bf(v.z); o.w=f2bf(v.w);
    *(ushort4*)&((u16*)outv)[(size_t)m*DR + c] = o;
  }else{
    *(float4*)&((float*)outv)[(size_t)m*DR + c] = v;
  }
}

// ---------- workspace layout (~170 MB) ----------
constexpr size_t OFF_FLAG  = 0;
constexpr size_t OFF_SQ    = 256;
constexpr size_t OFF_NIDX  = OFF_SQ    + 16384;
constexpr size_t OFF_BIAS  = OFF_NIDX  + 163840;
constexpr size_t OFF_CONDF = OFF_BIAS  + 16640;
constexpr size_t OFF_TENSF = OFF_CONDF + 2097152;
constexpr size_t OFF_WTIN  = OFF_TENSF + 1048576;
constexpr size_t OFF_WT1   = OFF_WTIN  + 393216;
constexpr size_t OFF_WT2   = OFF_WT1   + 2097152;
constexpr size_t OFF_WT3   = OFF_WT2   + 2097152;
constexpr size_t OFF_WTO   = OFF_WT3   + 2097152;
constexpr size_t OFF_RA    = OFF_WTO   + 131072;     // dist (67MB) then A0 (8MB)
constexpr size_t OFF_RB    = OFF_RA    + 83886080;   // X (1.5MB) then A1 (8MB)
constexpr size_t OFF_P     = OFF_RB    + 83886080;   // 1 MB

extern "C" void kernel_launch(void* const* d_in, const int* in_sizes, int n_in,
                              void* d_out, int out_size, void* d_ws, size_t ws_size,
                              hipStream_t stream){
  char* ws = (char*)d_ws;
  int*   flag  = (int*)  (ws + OFF_FLAG);
  float* sqv   = (float*)(ws + OFF_SQ);
  int*   nidx  = (int*)  (ws + OFF_NIDX);
  float* biasF = (float*)(ws + OFF_BIAS);
  float* condF = (float*)(ws + OFF_CONDF);
  float* tensF = (float*)(ws + OFF_TENSF);
  u16*   Wt_in = (u16*)  (ws + OFF_WTIN);
  u16*   Wt1   = (u16*)  (ws + OFF_WT1);
  u16*   Wt2   = (u16*)  (ws + OFF_WT2);
  u16*   Wt3   = (u16*)  (ws + OFF_WT3);
  u16*   Wt_o  = (u16*)  (ws + OFF_WTO);
  float* dist  = (float*)(ws + OFF_RA);   // dead after knn -> region reused as A0
  u16*   A0    = (u16*)  (ws + OFF_RA);
  u16*   X     = (u16*)  (ws + OFF_RB);   // dead after gemm1 -> region reused as A1
  u16*   A1    = (u16*)  (ws + OFF_RB);
  float* P     = (float*)(ws + OFF_P);

  detect_k <<<1, 256, 0, stream>>>((const u16*)d_in[0], flag);
  cvt_all_k<<<3089, 256, 0, stream>>>(d_in[0], d_in[1], d_in[3], d_in[5], d_in[7],
                                      d_in[9], d_in[11], condF, tensF, biasF, flag);
  transpose_all_k<<<3328, dim3(32,8), 0, stream>>>(d_in[2], d_in[4], d_in[6], d_in[8],
                                      d_in[10], Wt_in, Wt1, Wt2, Wt3, Wt_o, flag);
  sqnorm_k   <<<1024, 256, 0, stream>>>(condF, sqv);
  gram_dist_k<<<dim3(32,32), 256, 0, stream>>>(condF, sqv, dist, flag);
  knn_k      <<<NPTS, 256, 0, stream>>>(dist, condF, nidx);
  buildx_unique_k<<<768, 256, 0, stream>>>(condF, tensF, X);
  gemm_bt_k<1><<<512, 256, 0, stream>>>(X,  Wt_in, biasF,      A0, HID, DIN);
  gemm_bt_k<1><<<512, 256, 0, stream>>>(A0, Wt1,   biasF+1024, A1, HID, HID);
  gemm_bt_k<1><<<512, 256, 0, stream>>>(A1, Wt2,   biasF+2048, A0, HID, HID);
  gemm_bt_k<1><<<512, 256, 0, stream>>>(A0, Wt3,   biasF+3072, A1, HID, HID);
  gemm_out_k  <<<32, 256, 0, stream>>>(A1, Wt_o, biasF+4096, tensF, P);
  gather_k    <<<2560, 256, 0, stream>>>(P, nidx, d_out, flag);
}

// Round 14
// 266.784 us; speedup vs baseline: 4.3703x; 1.0478x over previous
//
// MongeGapTransport: KNN gather + 5-layer MLP pushforward, bf16 I/O (confirmed).
// R14: R13 (280us) with knn histogram REMOVED (R12/R13 counters: 6e6 LDS bank
// conflicts = concentrated-bin atomic serialization). New knn: row in registers,
// binary-search threshold via shfl-counted predicates (no atomics), compact
// ~16-20 candidates, R13-proven parallel fp64 refine + counting rank.
// gram_dist fl=1 now stages raw bf16 (R1-proven uint4 path, no f2bf).
#include <hip/hip_runtime.h>
#include <stdint.h>

typedef unsigned short u16;
typedef unsigned int   u32;
typedef unsigned long long u64;
typedef short v8bf __attribute__((ext_vector_type(8)));
typedef float v4f  __attribute__((ext_vector_type(4)));

#define NPTS 4096
#define DF   128
#define DR   64
#define HID  1024
#define KNN  10
#define CAP  256
#define MROWS (NPTS*KNN)   // 40960
#define DIN  192

#define AS1 __attribute__((address_space(1)))
#define AS3 __attribute__((address_space(3)))

__device__ __forceinline__ float bf2f(u16 b){ return __uint_as_float(((unsigned)b)<<16); }
__device__ __forceinline__ u16 f2bf(float f){
  unsigned u = __float_as_uint(f);
  unsigned r = 0x7fffu + ((u>>16)&1u);
  return (u16)((u + r)>>16);
}
__device__ __forceinline__ float softplus_f(float x){
  return x>15.f ? x : __logf(1.f + __expf(x));
}
__device__ __forceinline__ float rdv(const void* p, long j, int fl){
  return fl ? bf2f(((const u16*)p)[j]) : ((const float*)p)[j];
}
__device__ __forceinline__ void gl2lds16(const u16* g, u16* l){
  __builtin_amdgcn_global_load_lds((const AS1 unsigned int*)g, (AS3 unsigned int*)l, 16, 0, 0);
}

// ---------- dtype detection (R2-proven) ----------
__global__ void detect_k(const u16* __restrict__ c, int* __restrict__ flag){
  __shared__ int cnt[256];
  int t = threadIdx.x, n = 0;
  for(int i=t; i<8192; i+=256){
    u16 v = c[2*i];
    int e = (v>>7)&0xff;
    n += (e>=96 && e<=158);
  }
  cnt[t] = n; __syncthreads();
  for(int s=128; s>0; s>>=1){ if(t<s) cnt[t]+=cnt[t+s]; __syncthreads(); }
  if(t==0) *flag = (cnt[0] > 4915) ? 1 : 0;
}

// ---------- canonicalize to fp32 (R2-proven) ----------
__global__ void cvt_all_k(const void* c, const void* t, const void* bi, const void* b1,
                          const void* b2, const void* b3, const void* bo,
                          float* __restrict__ condF, float* __restrict__ tensF,
                          float* __restrict__ biasF, const int* __restrict__ flag){
  const int fl = *flag;
  int i = blockIdx.x*256 + threadIdx.x;
  if(i < 524288){ condF[i] = rdv(c, i, fl); }
  else if(i < 786432){ tensF[i-524288] = rdv(t, i-524288, fl); }
  else{
    int j = i - 786432;
    if(j < 1024)      biasF[j] = rdv(bi, j, fl);
    else if(j < 2048) biasF[j] = rdv(b1, j-1024, fl);
    else if(j < 3072) biasF[j] = rdv(b2, j-2048, fl);
    else if(j < 4096) biasF[j] = rdv(b3, j-3072, fl);
    else if(j < 4160) biasF[j] = rdv(bo, j-4096, fl);
  }
}

// ---------- all 5 weight transposes in ONE launch (R9-proven) ----------
__global__ void transpose_all_k(const void* Wi, const void* W1, const void* W2,
    const void* W3, const void* Wo, u16* Oi, u16* O1, u16* O2, u16* O3, u16* Oo,
    const int* __restrict__ flag){
  __shared__ u16 tile[32][33];
  const int fl = *flag;
  int bid = blockIdx.x;
  const void* in; u16* out; int R, C, bx, by;
  if(bid < 192)      { int b=bid;      in=Wi; out=Oi; R=192;  C=1024; bx=b&31; by=b>>5; }
  else if(bid < 1216){ int b=bid-192;  in=W1; out=O1; R=1024; C=1024; bx=b&31; by=b>>5; }
  else if(bid < 2240){ int b=bid-1216; in=W2; out=O2; R=1024; C=1024; bx=b&31; by=b>>5; }
  else if(bid < 3264){ int b=bid-2240; in=W3; out=O3; R=1024; C=1024; bx=b&31; by=b>>5; }
  else               { int b=bid-3264; in=Wo; out=Oo; R=1024; C=64;   bx=b&1;  by=b>>1; }
  int gx = bx*32, gy = by*32;
  int tx = threadIdx.x, ty = threadIdx.y;
  #pragma unroll
  for(int r=ty; r<32; r+=8){
    size_t idx = (size_t)(gy+r)*C + gx + tx;
    tile[r][tx] = fl ? ((const u16*)in)[idx] : f2bf(((const float*)in)[idx]);
  }
  __syncthreads();
  #pragma unroll
  for(int r=ty; r<32; r+=8) out[(size_t)(gx+r)*R + gy + tx] = tile[tx][r];
}

// ---------- squared norms (R2-proven) ----------
__global__ void sqnorm_k(const float* __restrict__ condF, float* __restrict__ sq){
  int row  = blockIdx.x*4 + (threadIdx.x>>6);
  int lane = threadIdx.x&63;
  const float* r = condF + (size_t)row*DF;
  float a = r[lane], b = r[lane+64];
  double s = (double)a*a + (double)b*b;
  #pragma unroll
  for(int off=32; off>0; off>>=1) s += __shfl_down(s, off, 64);
  if(lane==0) sq[row] = (float)s;
}

// ---------- gram -> fp32 d^2; fl=1: raw bf16 staging (R1-proven path) ----------
__global__ __launch_bounds__(256) void gram_dist_k(const u16* __restrict__ condB,
    const float* __restrict__ condF, const float* __restrict__ sq,
    float* __restrict__ dist, const int* __restrict__ flag){
  __shared__ u16 Ahi[128*40], Alo[128*40], Bhi[128*40], Blo[128*40];
  const int fl = *flag;
  const int bm = blockIdx.x*128, bn = blockIdx.y*128;
  const int tid = threadIdx.x, lane = tid&63, wave = tid>>6;
  const int wm = (wave&1)*64, wn = (wave>>1)*64;
  v4f acc[4][4] = {};
  for(int kb=0; kb<DF; kb+=32){
    if(fl){
      #pragma unroll
      for(int t=0;t<2;t++){
        int c2 = tid + t*256;
        int r = c2>>2, col = (c2&3)*8;
        *(uint4*)&Ahi[r*40+col] = *(const uint4*)&condB[(size_t)(bm+r)*DF + kb + col];
        *(uint4*)&Bhi[r*40+col] = *(const uint4*)&condB[(size_t)(bn+r)*DF + kb + col];
      }
    }else{
      #pragma unroll
      for(int t=0;t<4;t++){
        int ch = tid + t*256;
        int r = ch>>3, c = (ch&7)*4;
        float4 av = *(const float4*)&condF[(size_t)(bm+r)*DF + kb + c];
        float4 bv = *(const float4*)&condF[(size_t)(bn+r)*DF + kb + c];
        ushort4 ah, bh, al, bl;
        ah.x=f2bf(av.x); ah.y=f2bf(av.y); ah.z=f2bf(av.z); ah.w=f2bf(av.w);
        bh.x=f2bf(bv.x); bh.y=f2bf(bv.y); bh.z=f2bf(bv.z); bh.w=f2bf(bv.w);
        al.x=f2bf(av.x-bf2f(ah.x)); al.y=f2bf(av.y-bf2f(ah.y));
        al.z=f2bf(av.z-bf2f(ah.z)); al.w=f2bf(av.w-bf2f(ah.w));
        bl.x=f2bf(bv.x-bf2f(bh.x)); bl.y=f2bf(bv.y-bf2f(bh.y));
        bl.z=f2bf(bv.z-bf2f(bh.z)); bl.w=f2bf(bv.w-bf2f(bh.w));
        *(ushort4*)&Ahi[r*40+c] = ah; *(ushort4*)&Bhi[r*40+c] = bh;
        *(ushort4*)&Alo[r*40+c] = al; *(ushort4*)&Blo[r*40+c] = bl;
      }
    }
    __syncthreads();
    const int m16 = lane&15, q = lane>>4;
    v8bf ahf[4], bhf[4];
    #pragma unroll
    for(int x=0;x<4;x++){
      ahf[x] = *(const v8bf*)&Ahi[(wm + x*16 + m16)*40 + q*8];
      bhf[x] = *(const v8bf*)&Bhi[(wn + x*16 + m16)*40 + q*8];
    }
    if(!fl){
      v8bf alf[4], blf[4];
      #pragma unroll
      for(int x=0;x<4;x++){
        alf[x] = *(const v8bf*)&Alo[(wm + x*16 + m16)*40 + q*8];
        blf[x] = *(const v8bf*)&Blo[(wn + x*16 + m16)*40 + q*8];
      }
      #pragma unroll
      for(int mi=0;mi<4;mi++)
        #pragma unroll
        for(int ni=0;ni<4;ni++){
          acc[mi][ni] = __builtin_amdgcn_mfma_f32_16x16x32_bf16(alf[mi], bhf[ni], acc[mi][ni], 0,0,0);
          acc[mi][ni] = __builtin_amdgcn_mfma_f32_16x16x32_bf16(ahf[mi], blf[ni], acc[mi][ni], 0,0,0);
        }
    }
    #pragma unroll
    for(int mi=0;mi<4;mi++)
      #pragma unroll
      for(int ni=0;ni<4;ni++)
        acc[mi][ni] = __builtin_amdgcn_mfma_f32_16x16x32_bf16(ahf[mi], bhf[ni], acc[mi][ni], 0,0,0);
    __syncthreads();
  }
  const int col16 = lane&15, rowq = lane>>4;
  #pragma unroll
  for(int mi=0;mi<4;mi++){
    #pragma unroll
    for(int ni=0;ni<4;ni++){
      int cj = bn + wn + ni*16 + col16;
      float sqj = sq[cj];
      #pragma unroll
      for(int r=0;r<4;r++){
        int ri = bm + wm + mi*16 + rowq*4 + r;
        float d2 = (sq[ri] + sqj) - 2.0f*acc[mi][ni][r];
        dist[(size_t)ri*NPTS + cj] = fmaxf(d2, 0.f);
      }
    }
  }
}

// ---------- knn: register row + binary-search threshold + fp64 refine ----------
__global__ __launch_bounds__(256) void knn_k(const float* __restrict__ dist,
    const float* __restrict__ condF, int* __restrict__ nidx){
  const int i = blockIdx.x, tid = threadIdx.x, lane = tid&63, wv = tid>>6;
  __shared__ float wmaxf[4];
  __shared__ int   wcnt[4];
  __shared__ int   scnt;
  __shared__ int   candj[CAP];
  __shared__ u64   keys[CAP];
  __shared__ float af[DF];
  __shared__ double psum[64][4];
  if(tid < DF) af[tid] = condF[(size_t)i*DF + tid];
  if(tid == 0) scnt = 0;
  const float4* drow4 = (const float4*)(dist + (size_t)i*NPTS);
  float4 vals[4];
  #pragma unroll
  for(int k=0;k<4;k++) vals[k] = drow4[tid + k*256];
  // block max -> initial hi
  float mx = 0.f;
  #pragma unroll
  for(int k=0;k<4;k++)
    mx = fmaxf(mx, fmaxf(fmaxf(vals[k].x, vals[k].y), fmaxf(vals[k].z, vals[k].w)));
  #pragma unroll
  for(int off=32; off>0; off>>=1) mx = fmaxf(mx, __shfl_down(mx, off, 64));
  if(lane==0) wmaxf[wv] = mx;
  __syncthreads();
  float hi = fmaxf(fmaxf(wmaxf[0],wmaxf[1]), fmaxf(wmaxf[2],wmaxf[3]))*1.000001f + 1e-6f;
  float lo = 0.f;
  // bisect: maintain count(<hi) >= 16
  for(int it=0; it<16; ++it){
    float mid = 0.5f*(lo + hi);
    int c = 0;
    #pragma unroll
    for(int k=0;k<4;k++)
      c += (vals[k].x<mid) + (vals[k].y<mid) + (vals[k].z<mid) + (vals[k].w<mid);
    #pragma unroll
    for(int off=32; off>0; off>>=1) c += __shfl_down(c, off, 64);
    if(lane==0) wcnt[wv] = c;
    __syncthreads();
    int tot = wcnt[0]+wcnt[1]+wcnt[2]+wcnt[3];
    if(tot >= 16) hi = mid; else lo = mid;
    __syncthreads();
  }
  const float t = hi;
  #pragma unroll
  for(int k=0;k<4;k++){
    float v[4] = {vals[k].x, vals[k].y, vals[k].z, vals[k].w};
    #pragma unroll
    for(int e=0;e<4;e++){
      if(v[e] < t){
        int s = atomicAdd(&scnt, 1);
        if(s < CAP) candj[s] = (tid + k*256)*4 + e;
      }
    }
  }
  __syncthreads();
  const int cnt = scnt < CAP ? scnt : CAP;
  // exact fp64 d^2: 4 lanes/candidate, each sums 32 dims (R13-proven)
  for(int base=0; base<cnt; base+=64){
    int c = base + (tid>>2);
    int p = tid&3;
    if(c < cnt){
      int j = candj[c];
      const float4* bp4 = (const float4*)(condF + (size_t)j*DF + p*32);
      const float*  ap  = af + p*32;
      double s = 0.0;
      #pragma unroll
      for(int v4i=0; v4i<8; v4i++){
        float4 bv = bp4[v4i];
        s += ((double)ap[v4i*4+0]-(double)bv.x)*((double)ap[v4i*4+0]-(double)bv.x);
        s += ((double)ap[v4i*4+1]-(double)bv.y)*((double)ap[v4i*4+1]-(double)bv.y);
        s += ((double)ap[v4i*4+2]-(double)bv.z)*((double)ap[v4i*4+2]-(double)bv.z);
        s += ((double)ap[v4i*4+3]-(double)bv.w)*((double)ap[v4i*4+3]-(double)bv.w);
      }
      psum[c-base][p] = s;
    }
    __syncthreads();
    if(tid < 64 && base + tid < cnt){
      int c2 = base + tid;
      double s = psum[tid][0] + psum[tid][1] + psum[tid][2] + psum[tid][3];
      u64 bits = (u64)__double_as_longlong(s);
      keys[c2] = (bits & ~0xFFFULL) | (u32)candj[c2];
    }
    __syncthreads();
  }
  if(tid < cnt){
    u64 mykey = keys[tid];
    int rank = 0;
    for(int c=0;c<cnt;c++) rank += (keys[c] < mykey);
    if(rank < KNN) nidx[i*KNN + rank] = candj[tid];
  }
}

// ---------- X = [cond | tens] per UNIQUE point (no gather), bf16 ----------
__global__ void buildx_unique_k(const float* __restrict__ condF,
    const float* __restrict__ tensF, u16* __restrict__ X){
  int c = blockIdx.x*256 + threadIdx.x;
  int j = c/48;
  int off = (c - j*48)*4;
  float4 v = (off < DF) ? *(const float4*)&condF[(size_t)j*DF + off]
                        : *(const float4*)&tensF[(size_t)j*DR + (off-DF)];
  ushort4 o; o.x=f2bf(v.x); o.y=f2bf(v.y); o.z=f2bf(v.z); o.w=f2bf(v.w);
  *(ushort4*)&X[(size_t)j*DIN + off] = o;
}

// ---------- GEMM, M=4096: 512 blocks, 128x64 tiles, 2 blocks/CU (R12) ----------
template<int ACT>
__global__ __launch_bounds__(256,2) void gemm_bt_k(const u16* __restrict__ A,
    const u16* __restrict__ Bt, const float* __restrict__ bias, u16* __restrict__ C,
    int Nc, int Kc){
  __shared__ u16 As[128*32];
  __shared__ u16 Bs[64*32];
  const int bid = blockIdx.x;
  const int xcd = bid&7, slot = bid>>3;
  const int bm = (xcd*4 + (slot>>4)) * 128;
  const int bn = (slot&15) * 64;
  const int tid = threadIdx.x, lane = tid&63, wave = tid>>6;
  const int wm = (wave&1)*64, wn = (wave>>1)*32;
  int c0 = wave*128 + lane, c1 = c0 + 64;
  int r0 = c0>>2, q0 = c0&3, r1 = c1>>2, q1 = c1&3;
  int cb = wave*64 + lane, rb = cb>>2, qb = cb&3;
  const u16* pA0 = A  + (size_t)(bm+r0)*Kc + q0*8;
  const u16* pA1 = A  + (size_t)(bm+r1)*Kc + q1*8;
  const u16* pB  = Bt + (size_t)(bn+rb)*Kc + qb*8;
  u16* lA0 = &As[(wave*128      )*8];
  u16* lA1 = &As[(wave*128 + 64 )*8];
  u16* lB  = &Bs[(wave*64       )*8];
  const int m16 = lane&15, q = lane>>4;
  v4f acc[4][2] = {};
  for(int kb=0; kb<Kc; kb+=32){
    gl2lds16(pA0 + kb, lA0);
    gl2lds16(pA1 + kb, lA1);
    gl2lds16(pB  + kb, lB);
    __syncthreads();
    v8bf a[4], b[2];
    #pragma unroll
    for(int x=0;x<4;x++) a[x] = *(const v8bf*)&As[(wm + x*16 + m16)*32 + q*8];
    #pragma unroll
    for(int x=0;x<2;x++) b[x] = *(const v8bf*)&Bs[(wn + x*16 + m16)*32 + q*8];
    #pragma unroll
    for(int mi=0;mi<4;mi++)
      #pragma unroll
      for(int ni=0;ni<2;ni++)
        acc[mi][ni] = __builtin_amdgcn_mfma_f32_16x16x32_bf16(a[mi], b[ni], acc[mi][ni], 0,0,0);
    __syncthreads();
  }
  const int col16 = lane&15, rowq = lane>>4;
  #pragma unroll
  for(int mi=0;mi<4;mi++){
    #pragma unroll
    for(int ni=0;ni<2;ni++){
      int cn = bn + wn + ni*16 + col16;
      float bi = bias[cn];
      #pragma unroll
      for(int r=0;r<4;r++){
        int rw = bm + wm + mi*16 + rowq*4 + r;
        float v = acc[mi][ni][r] + bi;
        if(ACT) v = softplus_f(v);
        C[(size_t)rw*Nc + cn] = f2bf(v);
      }
    }
  }
}

// ---------- final layer, M=4096: P[j] = tens[j] - (A@Wout^T + b), fp32 ----------
__global__ __launch_bounds__(256,2) void gemm_out_k(const u16* __restrict__ A,
    const u16* __restrict__ Bt, const float* __restrict__ bias,
    const float* __restrict__ tensF, float* __restrict__ P){
  __shared__ u16 As[128*32];
  __shared__ u16 Bs[64*32];
  const int bm = blockIdx.x*128;
  const int tid = threadIdx.x, lane = tid&63, wave = tid>>6;
  const int wm = wave*32;
  int c0 = wave*128 + lane, c1 = c0 + 64;
  int ra0 = c0>>2, qa0 = c0&3, ra1 = c1>>2, qa1 = c1&3;
  int cb = wave*64 + lane;
  int rb = cb>>2, qb = cb&3;
  const u16* pA0 = A  + (size_t)(bm+ra0)*HID + qa0*8;
  const u16* pA1 = A  + (size_t)(bm+ra1)*HID + qa1*8;
  const u16* pB  = Bt + (size_t)rb*HID + qb*8;
  u16* lA0 = &As[(wave*128     )*8];
  u16* lA1 = &As[(wave*128 + 64)*8];
  u16* lB  = &Bs[(wave*64      )*8];
  const int m16 = lane&15, q = lane>>4;
  v4f acc[2][4] = {};
  for(int kb=0; kb<HID; kb+=32){
    gl2lds16(pA0 + kb, lA0);
    gl2lds16(pA1 + kb, lA1);
    gl2lds16(pB  + kb, lB);
    __syncthreads();
    v8bf a[2], b[4];
    a[0] = *(const v8bf*)&As[(wm + m16)*32 + q*8];
    a[1] = *(const v8bf*)&As[(wm + 16 + m16)*32 + q*8];
    #pragma unroll
    for(int x=0;x<4;x++) b[x] = *(const v8bf*)&Bs[(x*16 + m16)*32 + q*8];
    #pragma unroll
    for(int mi=0;mi<2;mi++)
      #pragma unroll
      for(int ni=0;ni<4;ni++)
        acc[mi][ni] = __builtin_amdgcn_mfma_f32_16x16x32_bf16(a[mi], b[ni], acc[mi][ni], 0,0,0);
    __syncthreads();
  }
  const int col16 = lane&15, rowq = lane>>4;
  #pragma unroll
  for(int mi=0;mi<2;mi++){
    #pragma unroll
    for(int ni=0;ni<4;ni++){
      int cn = ni*16 + col16;
      float bi = bias[cn];
      #pragma unroll
      for(int r=0;r<4;r++){
        int rw = bm + wm + mi*16 + rowq*4 + r;
        P[(size_t)rw*DR + cn] = tensF[(size_t)rw*DR + cn] - (acc[mi][ni][r] + bi);
      }
    }
  }
}

// ---------- gather: out[i,k,:] = P[nidx[i,k],:], dual dtype ----------
__global__ void gather_k(const float* __restrict__ P, const int* __restrict__ nidx,
                         void* __restrict__ outv, const int* __restrict__ flag){
  const int fl = *flag;
  int e = blockIdx.x*256 + threadIdx.x;
  int m = e>>4;
  int c = (e&15)*4;
  int j = nidx[m] & (NPTS-1);
  float4 v = *(const float4*)&P[(size_t)j*DR + c];
  if(fl){
    ushort4 o; o.x=f2bf(v.x); o.y=f2bf(v.y); o.z=f2bf(v.z); o.w=f2bf(v.w);
    *(ushort4*)&((u16*)outv)[(size_t)m*DR + c] = o;
  }else{
    *(float4*)&((float*)outv)[(size_t)m*DR + c] = v;
  }
}

// ---------- workspace layout (~170 MB) ----------
constexpr size_t OFF_FLAG  = 0;
constexpr size_t OFF_SQ    = 256;
constexpr size_t OFF_NIDX  = OFF_SQ    + 16384;
constexpr size_t OFF_BIAS  = OFF_NIDX  + 163840;
constexpr size_t OFF_CONDF = OFF_BIAS  + 16640;
constexpr size_t OFF_TENSF = OFF_CONDF + 2097152;
constexpr size_t OFF_WTIN  = OFF_TENSF + 1048576;
constexpr size_t OFF_WT1   = OFF_WTIN  + 393216;
constexpr size_t OFF_WT2   = OFF_WT1   + 2097152;
constexpr size_t OFF_WT3   = OFF_WT2   + 2097152;
constexpr size_t OFF_WTO   = OFF_WT3   + 2097152;
constexpr size_t OFF_RA    = OFF_WTO   + 131072;     // dist (67MB) then A0 (8MB)
constexpr size_t OFF_RB    = OFF_RA    + 83886080;   // X (1.5MB) then A1 (8MB)
constexpr size_t OFF_P     = OFF_RB    + 83886080;   // 1 MB

extern "C" void kernel_launch(void* const* d_in, const int* in_sizes, int n_in,
                              void* d_out, int out_size, void* d_ws, size_t ws_size,
                              hipStream_t stream){
  char* ws = (char*)d_ws;
  int*   flag  = (int*)  (ws + OFF_FLAG);
  float* sqv   = (float*)(ws + OFF_SQ);
  int*   nidx  = (int*)  (ws + OFF_NIDX);
  float* biasF = (float*)(ws + OFF_BIAS);
  float* condF = (float*)(ws + OFF_CONDF);
  float* tensF = (float*)(ws + OFF_TENSF);
  u16*   Wt_in = (u16*)  (ws + OFF_WTIN);
  u16*   Wt1   = (u16*)  (ws + OFF_WT1);
  u16*   Wt2   = (u16*)  (ws + OFF_WT2);
  u16*   Wt3   = (u16*)  (ws + OFF_WT3);
  u16*   Wt_o  = (u16*)  (ws + OFF_WTO);
  float* dist  = (float*)(ws + OFF_RA);   // dead after knn -> region reused as A0
  u16*   A0    = (u16*)  (ws + OFF_RA);
  u16*   X     = (u16*)  (ws + OFF_RB);   // dead after gemm1 -> region reused as A1
  u16*   A1    = (u16*)  (ws + OFF_RB);
  float* P     = (float*)(ws + OFF_P);

  detect_k <<<1, 256, 0, stream>>>((const u16*)d_in[0], flag);
  cvt_all_k<<<3089, 256, 0, stream>>>(d_in[0], d_in[1], d_in[3], d_in[5], d_in[7],
                                      d_in[9], d_in[11], condF, tensF, biasF, flag);
  transpose_all_k<<<3328, dim3(32,8), 0, stream>>>(d_in[2], d_in[4], d_in[6], d_in[8],
                                      d_in[10], Wt_in, Wt1, Wt2, Wt3, Wt_o, flag);
  sqnorm_k   <<<1024, 256, 0, stream>>>(condF, sqv);
  gram_dist_k<<<dim3(32,32), 256, 0, stream>>>((const u16*)d_in[0], condF, sqv, dist, flag);
  knn_k      <<<NPTS, 256, 0, stream>>>(dist, condF, nidx);
  buildx_unique_k<<<768, 256, 0, stream>>>(condF, tensF, X);
  gemm_bt_k<1><<<512, 256, 0, stream>>>(X,  Wt_in, biasF,      A0, HID, DIN);
  gemm_bt_k<1><<<512, 256, 0, stream>>>(A0, Wt1,   biasF+1024, A1, HID, HID);
  gemm_bt_k<1><<<512, 256, 0, stream>>>(A1, Wt2,   biasF+2048, A0, HID, HID);
  gemm_bt_k<1><<<512, 256, 0, stream>>>(A0, Wt3,   biasF+3072, A1, HID, HID);
  gemm_out_k  <<<32, 256, 0, stream>>>(A1, Wt_o, biasF+4096, tensF, P);
  gather_k    <<<2560, 256, 0, stream>>>(P, nidx, d_out, flag);
}

// Round 15
// 240.640 us; speedup vs baseline: 4.8452x; 1.1086x over previous
//
// MongeGapTransport: KNN gather + 5-layer MLP pushforward, bf16 I/O (confirmed).
// R15: R14 (267us) + knn restructured BARRIER-FREE (R14 counters: conflicts
// gone but 50us persists = 32 block barriers + 16x 6-deep bpermute chains).
// One wave per row: register row, intra-wave bisection w/ early exit, per-wave
// LDS compact + lane-per-candidate exact-fp64 refine + counting rank.
// Also: cvt/transpose/sqnorm/buildx fused into one prep kernel (13->10 launches).
#include <hip/hip_runtime.h>
#include <stdint.h>

typedef unsigned short u16;
typedef unsigned int   u32;
typedef unsigned long long u64;
typedef short v8bf __attribute__((ext_vector_type(8)));
typedef float v4f  __attribute__((ext_vector_type(4)));

#define NPTS 4096
#define DF   128
#define DR   64
#define HID  1024
#define KNN  10
#define MROWS (NPTS*KNN)   // 40960
#define DIN  192

#define AS1 __attribute__((address_space(1)))
#define AS3 __attribute__((address_space(3)))

__device__ __forceinline__ float bf2f(u16 b){ return __uint_as_float(((unsigned)b)<<16); }
__device__ __forceinline__ u16 f2bf(float f){
  unsigned u = __float_as_uint(f);
  unsigned r = 0x7fffu + ((u>>16)&1u);
  return (u16)((u + r)>>16);
}
__device__ __forceinline__ float softplus_f(float x){
  return x>15.f ? x : __logf(1.f + __expf(x));
}
__device__ __forceinline__ float rdv(const void* p, long j, int fl){
  return fl ? bf2f(((const u16*)p)[j]) : ((const float*)p)[j];
}
__device__ __forceinline__ void gl2lds16(const u16* g, u16* l){
  __builtin_amdgcn_global_load_lds((const AS1 unsigned int*)g, (AS3 unsigned int*)l, 16, 0, 0);
}

// ---------- dtype detection (R2-proven) ----------
__global__ void detect_k(const u16* __restrict__ c, int* __restrict__ flag){
  __shared__ int cnt[256];
  int t = threadIdx.x, n = 0;
  for(int i=t; i<8192; i+=256){
    u16 v = c[2*i];
    int e = (v>>7)&0xff;
    n += (e>=96 && e<=158);
  }
  cnt[t] = n; __syncthreads();
  for(int s=128; s>0; s>>=1){ if(t<s) cnt[t]+=cnt[t+s]; __syncthreads(); }
  if(t==0) *flag = (cnt[0] > 4915) ? 1 : 0;
}

// ---------- fused prep: cvt | weight transposes | sqnorm(raw) | buildx(raw) ----------
__global__ void prep_k(const void* cond, const void* tens,
    const void* Wi, const void* W1, const void* W2, const void* W3, const void* Wo,
    const void* bi, const void* b1, const void* b2, const void* b3, const void* bo,
    float* __restrict__ condF, float* __restrict__ tensF, float* __restrict__ biasF,
    u16* Oi, u16* O1, u16* O2, u16* O3, u16* Oo,
    float* __restrict__ sq, u16* __restrict__ X, const int* __restrict__ flag){
  __shared__ u16 tile[32][33];
  const int fl = *flag;
  const int bid = blockIdx.x, tid = threadIdx.x;
  if(bid < 3089){
    // canonicalize cond/tens/biases to fp32 (R2-proven body)
    int i = bid*256 + tid;
    if(i < 524288){ condF[i] = rdv(cond, i, fl); }
    else if(i < 786432){ tensF[i-524288] = rdv(tens, i-524288, fl); }
    else{
      int j = i - 786432;
      if(j < 1024)      biasF[j] = rdv(bi, j, fl);
      else if(j < 2048) biasF[j] = rdv(b1, j-1024, fl);
      else if(j < 3072) biasF[j] = rdv(b2, j-2048, fl);
      else if(j < 4096) biasF[j] = rdv(b3, j-3072, fl);
      else if(j < 4160) biasF[j] = rdv(bo, j-4096, fl);
    }
  } else if(bid < 6417){
    // weight transposes (R9-proven body, flat 256 threads)
    int b = bid - 3089;
    const void* in; u16* out; int R, C, bx, by;
    if(b < 192)      {              in=Wi; out=Oi; R=192;  C=1024; bx=b&31; by=b>>5; }
    else if(b < 1216){ b -= 192;    in=W1; out=O1; R=1024; C=1024; bx=b&31; by=b>>5; }
    else if(b < 2240){ b -= 1216;   in=W2; out=O2; R=1024; C=1024; bx=b&31; by=b>>5; }
    else if(b < 3264){ b -= 2240;   in=W3; out=O3; R=1024; C=1024; bx=b&31; by=b>>5; }
    else             { b -= 3264;   in=Wo; out=Oo; R=1024; C=64;   bx=b&1;  by=b>>1; }
    int gx = bx*32, gy = by*32;
    int tx = tid&31, ty = tid>>5;
    #pragma unroll
    for(int r=ty; r<32; r+=8){
      size_t idx = (size_t)(gy+r)*C + gx + tx;
      tile[r][tx] = fl ? ((const u16*)in)[idx] : f2bf(((const float*)in)[idx]);
    }
    __syncthreads();
    #pragma unroll
    for(int r=ty; r<32; r+=8) out[(size_t)(gx+r)*R + gy + tx] = tile[tx][r];
  } else if(bid < 7441){
    // squared norms from raw input (fp64 accumulate)
    int b = bid - 6417;
    int row = b*4 + (tid>>6), lane = tid&63;
    float a = rdv(cond, (long)row*DF + lane, fl);
    float c2 = rdv(cond, (long)row*DF + lane + 64, fl);
    double s = (double)a*a + (double)c2*c2;
    #pragma unroll
    for(int off=32; off>0; off>>=1) s += __shfl_down(s, off, 64);
    if(lane==0) sq[row] = (float)s;
  } else {
    // X = [cond | tens] per unique point, bf16, from raw input
    int c = (bid-7441)*256 + tid;
    int j = c/48;
    int off = (c - j*48)*4;
    ushort4 o;
    if(off < DF){
      o.x = f2bf(rdv(cond, (long)j*DF + off + 0, fl));
      o.y = f2bf(rdv(cond, (long)j*DF + off + 1, fl));
      o.z = f2bf(rdv(cond, (long)j*DF + off + 2, fl));
      o.w = f2bf(rdv(cond, (long)j*DF + off + 3, fl));
    }else{
      int t2 = off - DF;
      o.x = f2bf(rdv(tens, (long)j*DR + t2 + 0, fl));
      o.y = f2bf(rdv(tens, (long)j*DR + t2 + 1, fl));
      o.z = f2bf(rdv(tens, (long)j*DR + t2 + 2, fl));
      o.w = f2bf(rdv(tens, (long)j*DR + t2 + 3, fl));
    }
    *(ushort4*)&X[(size_t)j*DIN + off] = o;
  }
}

// ---------- gram -> fp32 d^2; fl=1: raw bf16 staging (R14-proven) ----------
__global__ __launch_bounds__(256) void gram_dist_k(const u16* __restrict__ condB,
    const float* __restrict__ condF, const float* __restrict__ sq,
    float* __restrict__ dist, const int* __restrict__ flag){
  __shared__ u16 Ahi[128*40], Alo[128*40], Bhi[128*40], Blo[128*40];
  const int fl = *flag;
  const int bm = blockIdx.x*128, bn = blockIdx.y*128;
  const int tid = threadIdx.x, lane = tid&63, wave = tid>>6;
  const int wm = (wave&1)*64, wn = (wave>>1)*64;
  v4f acc[4][4] = {};
  for(int kb=0; kb<DF; kb+=32){
    if(fl){
      #pragma unroll
      for(int t=0;t<2;t++){
        int c2 = tid + t*256;
        int r = c2>>2, col = (c2&3)*8;
        *(uint4*)&Ahi[r*40+col] = *(const uint4*)&condB[(size_t)(bm+r)*DF + kb + col];
        *(uint4*)&Bhi[r*40+col] = *(const uint4*)&condB[(size_t)(bn+r)*DF + kb + col];
      }
    }else{
      #pragma unroll
      for(int t=0;t<4;t++){
        int ch = tid + t*256;
        int r = ch>>3, c = (ch&7)*4;
        float4 av = *(const float4*)&condF[(size_t)(bm+r)*DF + kb + c];
        float4 bv = *(const float4*)&condF[(size_t)(bn+r)*DF + kb + c];
        ushort4 ah, bh, al, bl;
        ah.x=f2bf(av.x); ah.y=f2bf(av.y); ah.z=f2bf(av.z); ah.w=f2bf(av.w);
        bh.x=f2bf(bv.x); bh.y=f2bf(bv.y); bh.z=f2bf(bv.z); bh.w=f2bf(bv.w);
        al.x=f2bf(av.x-bf2f(ah.x)); al.y=f2bf(av.y-bf2f(ah.y));
        al.z=f2bf(av.z-bf2f(ah.z)); al.w=f2bf(av.w-bf2f(ah.w));
        bl.x=f2bf(bv.x-bf2f(bh.x)); bl.y=f2bf(bv.y-bf2f(bh.y));
        bl.z=f2bf(bv.z-bf2f(bh.z)); bl.w=f2bf(bv.w-bf2f(bh.w));
        *(ushort4*)&Ahi[r*40+c] = ah; *(ushort4*)&Bhi[r*40+c] = bh;
        *(ushort4*)&Alo[r*40+c] = al; *(ushort4*)&Blo[r*40+c] = bl;
      }
    }
    __syncthreads();
    const int m16 = lane&15, q = lane>>4;
    v8bf ahf[4], bhf[4];
    #pragma unroll
    for(int x=0;x<4;x++){
      ahf[x] = *(const v8bf*)&Ahi[(wm + x*16 + m16)*40 + q*8];
      bhf[x] = *(const v8bf*)&Bhi[(wn + x*16 + m16)*40 + q*8];
    }
    if(!fl){
      v8bf alf[4], blf[4];
      #pragma unroll
      for(int x=0;x<4;x++){
        alf[x] = *(const v8bf*)&Alo[(wm + x*16 + m16)*40 + q*8];
        blf[x] = *(const v8bf*)&Blo[(wn + x*16 + m16)*40 + q*8];
      }
      #pragma unroll
      for(int mi=0;mi<4;mi++)
        #pragma unroll
        for(int ni=0;ni<4;ni++){
          acc[mi][ni] = __builtin_amdgcn_mfma_f32_16x16x32_bf16(alf[mi], bhf[ni], acc[mi][ni], 0,0,0);
          acc[mi][ni] = __builtin_amdgcn_mfma_f32_16x16x32_bf16(ahf[mi], blf[ni], acc[mi][ni], 0,0,0);
        }
    }
    #pragma unroll
    for(int mi=0;mi<4;mi++)
      #pragma unroll
      for(int ni=0;ni<4;ni++)
        acc[mi][ni] = __builtin_amdgcn_mfma_f32_16x16x32_bf16(ahf[mi], bhf[ni], acc[mi][ni], 0,0,0);
    __syncthreads();
  }
  const int col16 = lane&15, rowq = lane>>4;
  #pragma unroll
  for(int mi=0;mi<4;mi++){
    #pragma unroll
    for(int ni=0;ni<4;ni++){
      int cj = bn + wn + ni*16 + col16;
      float sqj = sq[cj];
      #pragma unroll
      for(int r=0;r<4;r++){
        int ri = bm + wm + mi*16 + rowq*4 + r;
        float d2 = (sq[ri] + sqj) - 2.0f*acc[mi][ni][r];
        dist[(size_t)ri*NPTS + cj] = fmaxf(d2, 0.f);
      }
    }
  }
}

// ---------- knn: one wave per row, barrier-free ----------
// Bisection invariant: count(<hi) >= 16 always => top-16 (hence top-10) < hi.
// Early exit when 16<=cnt<=48. Candidates refined with exact fp64 d^2
// (bf16 diffs/products/sums exactly representable), counting rank in LDS.
__global__ __launch_bounds__(256) void knn_k(const float* __restrict__ dist,
    const float* __restrict__ condF, int* __restrict__ nidx){
  const int tid = threadIdx.x, lane = tid&63, wv = tid>>6;
  const int row = blockIdx.x*4 + wv;
  __shared__ float af[4][DF];
  __shared__ int   scnt[4];
  __shared__ int   cand[4][64];
  __shared__ u64   keys[4][64];
  af[wv][lane]    = condF[(size_t)row*DF + lane];
  af[wv][lane+64] = condF[(size_t)row*DF + lane + 64];
  if(lane==0) scnt[wv] = 0;
  const float4* drow4 = (const float4*)(dist + (size_t)row*NPTS);
  float4 vals[16];
  #pragma unroll
  for(int k=0;k<16;k++) vals[k] = drow4[lane + k*64];
  float mx = 0.f;
  #pragma unroll
  for(int k=0;k<16;k++)
    mx = fmaxf(mx, fmaxf(fmaxf(vals[k].x,vals[k].y), fmaxf(vals[k].z,vals[k].w)));
  #pragma unroll
  for(int off=32; off>0; off>>=1) mx = fmaxf(mx, __shfl_down(mx, off, 64));
  mx = __shfl(mx, 0, 64);
  float hi = mx*1.000001f + 1e-6f, lo = 0.f;
  for(int it=0; it<18; ++it){
    float mid = 0.5f*(lo+hi);
    int c = 0;
    #pragma unroll
    for(int k=0;k<16;k++)
      c += (vals[k].x<mid) + (vals[k].y<mid) + (vals[k].z<mid) + (vals[k].w<mid);
    #pragma unroll
    for(int off=32; off>0; off>>=1) c += __shfl_down(c, off, 64);
    c = __shfl(c, 0, 64);
    if(c >= 16){ hi = mid; if(c <= 48) break; }
    else lo = mid;
  }
  const float t = hi;
  #pragma unroll
  for(int k=0;k<16;k++){
    float v[4] = {vals[k].x, vals[k].y, vals[k].z, vals[k].w};
    #pragma unroll
    for(int e=0;e<4;e++){
      if(v[e] < t){
        int s = atomicAdd(&scnt[wv], 1);
        if(s < 64) cand[wv][s] = (lane + k*64)*4 + e;
      }
    }
  }
  // same-wave LDS ordering: all atomics precede this read in the wave's
  // instruction stream; compiler inserts lgkmcnt wait.
  int cnt = scnt[wv]; if(cnt > 64) cnt = 64;
  u64 mykey = ~0ULL; int myj = -1;
  if(lane < cnt){
    int j = cand[wv][lane];
    const float4* bp4 = (const float4*)(condF + (size_t)j*DF);
    const float* ap = af[wv];
    double s = 0.0;
    #pragma unroll
    for(int v4i=0; v4i<32; v4i++){
      float4 bv = bp4[v4i];
      double d0 = (double)ap[v4i*4+0]-(double)bv.x;
      double d1 = (double)ap[v4i*4+1]-(double)bv.y;
      double d2 = (double)ap[v4i*4+2]-(double)bv.z;
      double d3 = (double)ap[v4i*4+3]-(double)bv.w;
      s += d0*d0 + d1*d1 + d2*d2 + d3*d3;
    }
    u64 bits = (u64)__double_as_longlong(s);
    mykey = (bits & ~0xFFFULL) | (u32)j;
    myj = j;
  }
  keys[wv][lane] = mykey;
  if(lane < cnt){
    int rank = 0;
    for(int c2=0;c2<cnt;c2++) rank += (keys[wv][c2] < mykey);
    if(rank < KNN) nidx[row*KNN + rank] = myj;
  }
}

// ---------- GEMM, M=4096: 512 blocks, 128x64 tiles, 2 blocks/CU (R12) ----------
template<int ACT>
__global__ __launch_bounds__(256,2) void gemm_bt_k(const u16* __restrict__ A,
    const u16* __restrict__ Bt, const float* __restrict__ bias, u16* __restrict__ C,
    int Nc, int Kc){
  __shared__ u16 As[128*32];
  __shared__ u16 Bs[64*32];
  const int bid = blockIdx.x;
  const int xcd = bid&7, slot = bid>>3;
  const int bm = (xcd*4 + (slot>>4)) * 128;
  const int bn = (slot&15) * 64;
  const int tid = threadIdx.x, lane = tid&63, wave = tid>>6;
  const int wm = (wave&1)*64, wn = (wave>>1)*32;
  int c0 = wave*128 + lane, c1 = c0 + 64;
  int r0 = c0>>2, q0 = c0&3, r1 = c1>>2, q1 = c1&3;
  int cb = wave*64 + lane, rb = cb>>2, qb = cb&3;
  const u16* pA0 = A  + (size_t)(bm+r0)*Kc + q0*8;
  const u16* pA1 = A  + (size_t)(bm+r1)*Kc + q1*8;
  const u16* pB  = Bt + (size_t)(bn+rb)*Kc + qb*8;
  u16* lA0 = &As[(wave*128      )*8];
  u16* lA1 = &As[(wave*128 + 64 )*8];
  u16* lB  = &Bs[(wave*64       )*8];
  const int m16 = lane&15, q = lane>>4;
  v4f acc[4][2] = {};
  for(int kb=0; kb<Kc; kb+=32){
    gl2lds16(pA0 + kb, lA0);
    gl2lds16(pA1 + kb, lA1);
    gl2lds16(pB  + kb, lB);
    __syncthreads();
    v8bf a[4], b[2];
    #pragma unroll
    for(int x=0;x<4;x++) a[x] = *(const v8bf*)&As[(wm + x*16 + m16)*32 + q*8];
    #pragma unroll
    for(int x=0;x<2;x++) b[x] = *(const v8bf*)&Bs[(wn + x*16 + m16)*32 + q*8];
    #pragma unroll
    for(int mi=0;mi<4;mi++)
      #pragma unroll
      for(int ni=0;ni<2;ni++)
        acc[mi][ni] = __builtin_amdgcn_mfma_f32_16x16x32_bf16(a[mi], b[ni], acc[mi][ni], 0,0,0);
    __syncthreads();
  }
  const int col16 = lane&15, rowq = lane>>4;
  #pragma unroll
  for(int mi=0;mi<4;mi++){
    #pragma unroll
    for(int ni=0;ni<2;ni++){
      int cn = bn + wn + ni*16 + col16;
      float bi = bias[cn];
      #pragma unroll
      for(int r=0;r<4;r++){
        int rw = bm + wm + mi*16 + rowq*4 + r;
        float v = acc[mi][ni][r] + bi;
        if(ACT) v = softplus_f(v);
        C[(size_t)rw*Nc + cn] = f2bf(v);
      }
    }
  }
}

// ---------- final layer, M=4096: P[j] = tens[j] - (A@Wout^T + b), fp32 ----------
__global__ __launch_bounds__(256,2) void gemm_out_k(const u16* __restrict__ A,
    const u16* __restrict__ Bt, const float* __restrict__ bias,
    const float* __restrict__ tensF, float* __restrict__ P){
  __shared__ u16 As[128*32];
  __shared__ u16 Bs[64*32];
  const int bm = blockIdx.x*128;
  const int tid = threadIdx.x, lane = tid&63, wave = tid>>6;
  const int wm = wave*32;
  int c0 = wave*128 + lane, c1 = c0 + 64;
  int ra0 = c0>>2, qa0 = c0&3, ra1 = c1>>2, qa1 = c1&3;
  int cb = wave*64 + lane;
  int rb = cb>>2, qb = cb&3;
  const u16* pA0 = A  + (size_t)(bm+ra0)*HID + qa0*8;
  const u16* pA1 = A  + (size_t)(bm+ra1)*HID + qa1*8;
  const u16* pB  = Bt + (size_t)rb*HID + qb*8;
  u16* lA0 = &As[(wave*128     )*8];
  u16* lA1 = &As[(wave*128 + 64)*8];
  u16* lB  = &Bs[(wave*64      )*8];
  const int m16 = lane&15, q = lane>>4;
  v4f acc[2][4] = {};
  for(int kb=0; kb<HID; kb+=32){
    gl2lds16(pA0 + kb, lA0);
    gl2lds16(pA1 + kb, lA1);
    gl2lds16(pB  + kb, lB);
    __syncthreads();
    v8bf a[2], b[4];
    a[0] = *(const v8bf*)&As[(wm + m16)*32 + q*8];
    a[1] = *(const v8bf*)&As[(wm + 16 + m16)*32 + q*8];
    #pragma unroll
    for(int x=0;x<4;x++) b[x] = *(const v8bf*)&Bs[(x*16 + m16)*32 + q*8];
    #pragma unroll
    for(int mi=0;mi<2;mi++)
      #pragma unroll
      for(int ni=0;ni<4;ni++)
        acc[mi][ni] = __builtin_amdgcn_mfma_f32_16x16x32_bf16(a[mi], b[ni], acc[mi][ni], 0,0,0);
    __syncthreads();
  }
  const int col16 = lane&15, rowq = lane>>4;
  #pragma unroll
  for(int mi=0;mi<2;mi++){
    #pragma unroll
    for(int ni=0;ni<4;ni++){
      int cn = ni*16 + col16;
      float bi = bias[cn];
      #pragma unroll
      for(int r=0;r<4;r++){
        int rw = bm + wm + mi*16 + rowq*4 + r;
        P[(size_t)rw*DR + cn] = tensF[(size_t)rw*DR + cn] - (acc[mi][ni][r] + bi);
      }
    }
  }
}

// ---------- gather: out[i,k,:] = P[nidx[i,k],:], dual dtype ----------
__global__ void gather_k(const float* __restrict__ P, const int* __restrict__ nidx,
                         void* __restrict__ outv, const int* __restrict__ flag){
  const int fl = *flag;
  int e = blockIdx.x*256 + threadIdx.x;
  int m = e>>4;
  int c = (e&15)*4;
  int j = nidx[m] & (NPTS-1);
  float4 v = *(const float4*)&P[(size_t)j*DR + c];
  if(fl){
    ushort4 o; o.x=f2bf(v.x); o.y=f2bf(v.y); o.z=f2bf(v.z); o.w=f2bf(v.w);
    *(ushort4*)&((u16*)outv)[(size_t)m*DR + c] = o;
  }else{
    *(float4*)&((float*)outv)[(size_t)m*DR + c] = v;
  }
}

// ---------- workspace layout (~170 MB) ----------
constexpr size_t OFF_FLAG  = 0;
constexpr size_t OFF_SQ    = 256;
constexpr size_t OFF_NIDX  = OFF_SQ    + 16384;
constexpr size_t OFF_BIAS  = OFF_NIDX  + 163840;
constexpr size_t OFF_CONDF = OFF_BIAS  + 16640;
constexpr size_t OFF_TENSF = OFF_CONDF + 2097152;
constexpr size_t OFF_WTIN  = OFF_TENSF + 1048576;
constexpr size_t OFF_WT1   = OFF_WTIN  + 393216;
constexpr size_t OFF_WT2   = OFF_WT1   + 2097152;
constexpr size_t OFF_WT3   = OFF_WT2   + 2097152;
constexpr size_t OFF_WTO   = OFF_WT3   + 2097152;
constexpr size_t OFF_RA    = OFF_WTO   + 131072;     // dist (67MB) then A0 (8MB)
constexpr size_t OFF_RB    = OFF_RA    + 83886080;   // X (1.5MB) then A1 (8MB)
constexpr size_t OFF_P     = OFF_RB    + 83886080;   // 1 MB

extern "C" void kernel_launch(void* const* d_in, const int* in_sizes, int n_in,
                              void* d_out, int out_size, void* d_ws, size_t ws_size,
                              hipStream_t stream){
  char* ws = (char*)d_ws;
  int*   flag  = (int*)  (ws + OFF_FLAG);
  float* sqv   = (float*)(ws + OFF_SQ);
  int*   nidx  = (int*)  (ws + OFF_NIDX);
  float* biasF = (float*)(ws + OFF_BIAS);
  float* condF = (float*)(ws + OFF_CONDF);
  float* tensF = (float*)(ws + OFF_TENSF);
  u16*   Wt_in = (u16*)  (ws + OFF_WTIN);
  u16*   Wt1   = (u16*)  (ws + OFF_WT1);
  u16*   Wt2   = (u16*)  (ws + OFF_WT2);
  u16*   Wt3   = (u16*)  (ws + OFF_WT3);
  u16*   Wt_o  = (u16*)  (ws + OFF_WTO);
  float* dist  = (float*)(ws + OFF_RA);   // dead after knn -> region reused as A0
  u16*   A0    = (u16*)  (ws + OFF_RA);
  u16*   X     = (u16*)  (ws + OFF_RB);   // dead after gemm1 -> region reused as A1
  u16*   A1    = (u16*)  (ws + OFF_RB);
  float* P     = (float*)(ws + OFF_P);

  detect_k <<<1, 256, 0, stream>>>((const u16*)d_in[0], flag);
  prep_k   <<<8209, 256, 0, stream>>>(d_in[0], d_in[1],
                d_in[2], d_in[4], d_in[6], d_in[8], d_in[10],
                d_in[3], d_in[5], d_in[7], d_in[9], d_in[11],
                condF, tensF, biasF, Wt_in, Wt1, Wt2, Wt3, Wt_o, sqv, X, flag);
  gram_dist_k<<<dim3(32,32), 256, 0, stream>>>((const u16*)d_in[0], condF, sqv, dist, flag);
  knn_k      <<<1024, 256, 0, stream>>>(dist, condF, nidx);
  gemm_bt_k<1><<<512, 256, 0, stream>>>(X,  Wt_in, biasF,      A0, HID, DIN);
  gemm_bt_k<1><<<512, 256, 0, stream>>>(A0, Wt1,   biasF+1024, A1, HID, HID);
  gemm_bt_k<1><<<512, 256, 0, stream>>>(A1, Wt2,   biasF+2048, A0, HID, HID);
  gemm_bt_k<1><<<512, 256, 0, stream>>>(A0, Wt3,   biasF+3072, A1, HID, HID);
  gemm_out_k  <<<32, 256, 0, stream>>>(A1, Wt_o, biasF+4096, tensF, P);
  gather_k    <<<2560, 256, 0, stream>>>(P, nidx, d_out, flag);
}